// Round 1
// baseline (531.064 us; speedup 1.0000x reference)
//
#include <hip/hip_runtime.h>
#include <cmath>

// Kalman_Smooth_Gradient: B=4096 sequences, T=128 steps, 6-state EKF + RTS
// smoother + loss sum. Round 1: correct thread-per-sequence baseline.
//
// Parallelism: only across B=4096 sequences (t-loop is a true recurrence both
// directions). One thread per sequence -> 64 waves total. Blocks of 64 so the
// 64 waves spread across ~64 CUs. Known underutilization; optimize later.
//
// History for the backward pass: only (s_f, P_f upper 21) = 27 f32/step needed
// (sp/Pp/F at n+1 are recomputed from s_f[n],P_f[n]). Stored in d_ws with
// layout [t][k][seq] so each access is a fully coalesced 256B wave access.
// ws requirement: 128*27*4096*4 = 56.6 MB.

namespace {

constexpr int B = 4096;
constexpr int T = 128;
constexpr float DTc     = 1.0f / 120.0f;
constexpr float TWO_PIc = 6.28318530717958647692f;
constexpr float PI_1_5  = 4.71238898038468985769f;  // 1.5*pi

__device__ __forceinline__ int uidx(int i, int j) {  // i<=j, upper-tri row-major
  return i * 6 - i * (i - 1) / 2 + (j - i);
}

// loss term: det(Sv) + e^T Sv e with Sv = H P H^T + R
__device__ __forceinline__ float loss_term(const float Pm[6][6], const float sv[6],
                                           float z0, float z1, float z2,
                                           float r0, float r1, float r2) {
  float a = Pm[0][0] + r0, b = Pm[0][1], c = Pm[0][4];
  float d = Pm[1][1] + r1, e = Pm[1][4], f = Pm[4][4] + r2;
  float det = a * (d * f - e * e) + b * (c * e - b * f) + c * (b * e - d * c);
  float e0 = z0 - sv[0], e1 = z1 - sv[1], aa = z2 - sv[4];
  if (aa >  PI_1_5) aa -= TWO_PIc;
  if (aa < -PI_1_5) aa += TWO_PIc;
  float quad = a * e0 * e0 + d * e1 * e1 + f * aa * aa +
               2.0f * (b * e0 * e1 + c * e0 * aa + e * e1 * aa);
  return det + quad;
}

__global__ __launch_bounds__(64, 1) void ekf_smooth_loss_kernel(
    const float* __restrict__ params, const float* __restrict__ covp,
    const float* __restrict__ init_states, const float* __restrict__ z,
    float* __restrict__ hist, float* __restrict__ out) {
  const int seq = blockIdx.x * blockDim.x + threadIdx.x;
  if (seq >= B) return;

  // ---- shared scalars (uniform across lanes, scalar-cached) ----
  const float friction = (tanhf(params[0]) + 1.0f) * 0.01f;
  const float damping  = (tanhf(params[1]) + 1.0f) * 0.01f;
  float cp[7];
#pragma unroll
  for (int i = 0; i < 7; i++) cp[i] = 1.0f / (1.0f + expf(-covp[i]));
  const float r0 = cp[0], r1 = cp[1], r2 = cp[2];
  const float q[6] = {cp[3], cp[3], cp[4], cp[4], cp[5], cp[6]};
  const float dcoef = 1.0f - DTc * damping;

  // ---- state ----
  float s[6];
#pragma unroll
  for (int i = 0; i < 6; i++) s[i] = init_states[seq * 6 + i];
  float P[6][6];
#pragma unroll
  for (int i = 0; i < 6; i++)
#pragma unroll
    for (int j = 0; j < 6; j++) P[i][j] = (i == j) ? 0.01f : 0.0f;

  const float* __restrict__ zs = z + (size_t)seq * T * 3;

  // ================= forward EKF =================
#pragma unroll 1
  for (int t = 0; t < T; t++) {
    const float tx = tanhf(100.0f * s[2]);
    const float ty = tanhf(100.0f * s[3]);
    float sp[6];
    sp[0] = s[0] + DTc * s[2];
    sp[1] = s[1] + DTc * s[3];
    sp[2] = s[2] - DTc * (damping * s[2] + friction * tx);
    sp[3] = s[3] - DTc * (damping * s[3] + friction * ty);
    sp[4] = s[4] + DTc * s[5];
    sp[5] = s[5] * dcoef;
    const float gx = 1.0f - DTc * (damping + friction * 100.0f * (1.0f - tx * tx));
    const float gy = 1.0f - DTc * (damping + friction * 100.0f * (1.0f - ty * ty));

    // A = F P  (F sparse)
    float A[6][6];
#pragma unroll
    for (int j = 0; j < 6; j++) {
      A[0][j] = P[0][j] + DTc * P[2][j];
      A[1][j] = P[1][j] + DTc * P[3][j];
      A[2][j] = gx * P[2][j];
      A[3][j] = gy * P[3][j];
      A[4][j] = P[4][j] + DTc * P[5][j];
      A[5][j] = dcoef * P[5][j];
    }
    // Pp = A F^T + Q
    float Pp[6][6];
#pragma unroll
    for (int i = 0; i < 6; i++) {
      Pp[i][0] = A[i][0] + DTc * A[i][2];
      Pp[i][1] = A[i][1] + DTc * A[i][3];
      Pp[i][2] = gx * A[i][2];
      Pp[i][3] = gy * A[i][3];
      Pp[i][4] = A[i][4] + DTc * A[i][5];
      Pp[i][5] = dcoef * A[i][5];
    }
#pragma unroll
    for (int i = 0; i < 6; i++) Pp[i][i] += q[i];

    // S = H Pp H^T + R (symmetric 3x3), invert by adjugate
    const float Sa = Pp[0][0] + r0, Sb = Pp[0][1], Sc = Pp[0][4];
    const float Sd = Pp[1][1] + r1, Se = Pp[1][4], Sf = Pp[4][4] + r2;
    const float C00 = Sd * Sf - Se * Se;
    const float C01 = Sc * Se - Sb * Sf;
    const float C02 = Sb * Se - Sd * Sc;
    const float det = Sa * C00 + Sb * C01 + Sc * C02;
    const float idet = 1.0f / det;
    const float Si00 = C00 * idet, Si01 = C01 * idet, Si02 = C02 * idet;
    const float Si11 = (Sa * Sf - Sc * Sc) * idet;
    const float Si12 = (Sb * Sc - Sa * Se) * idet;
    const float Si22 = (Sa * Sd - Sb * Sb) * idet;

    // K = Pp H^T S^{-1}  (6x3)
    float K[6][3];
#pragma unroll
    for (int i = 0; i < 6; i++) {
      const float u0 = Pp[i][0], u1 = Pp[i][1], u2 = Pp[i][4];
      K[i][0] = u0 * Si00 + u1 * Si01 + u2 * Si02;
      K[i][1] = u0 * Si01 + u1 * Si11 + u2 * Si12;
      K[i][2] = u0 * Si02 + u1 * Si12 + u2 * Si22;
    }

    const float z0 = zs[t * 3 + 0], z1 = zs[t * 3 + 1], z2 = zs[t * 3 + 2];
    const float i0 = z0 - sp[0];
    const float i1 = z1 - sp[1];
    float ia = z2 - sp[4];
    ia = ia - TWO_PIc * rintf(ia * (1.0f / TWO_PIc));  // _wrap (round-to-even)

#pragma unroll
    for (int i = 0; i < 6; i++)
      s[i] = sp[i] + K[i][0] * i0 + K[i][1] * i1 + K[i][2] * ia;

    // P = (I - K H) Pp   (compute upper, mirror; analytically symmetric)
#pragma unroll
    for (int i = 0; i < 6; i++)
#pragma unroll
      for (int j = i; j < 6; j++) {
        const float v = Pp[i][j] -
            (K[i][0] * Pp[0][j] + K[i][1] * Pp[1][j] + K[i][2] * Pp[4][j]);
        P[i][j] = v;
        P[j][i] = v;
      }

    // store history (coalesced: stride B across k)
    const size_t base = (size_t)t * 27 * B + seq;
#pragma unroll
    for (int k = 0; k < 6; k++) hist[base + (size_t)k * B] = s[k];
#pragma unroll
    for (int i = 0; i < 6; i++)
#pragma unroll
      for (int j = i; j < 6; j++)
        hist[base + (size_t)(6 + uidx(i, j)) * B] = P[i][j];
  }

  // ================= loss at t = T-1 (smoothed == filtered) =================
  float loss = loss_term(P, s, zs[(T - 1) * 3 + 0], zs[(T - 1) * 3 + 1],
                         zs[(T - 1) * 3 + 2], r0, r1, r2);

  // carry: (sn, Pn) = smoothed at n+1; currently filtered at T-1
  float sn[6];
#pragma unroll
  for (int i = 0; i < 6; i++) sn[i] = s[i];
  float Pn[6][6];
#pragma unroll
  for (int i = 0; i < 6; i++)
#pragma unroll
    for (int j = 0; j < 6; j++) Pn[i][j] = P[i][j];

  // ================= backward RTS =================
#pragma unroll 1
  for (int n = T - 2; n >= 0; n--) {
    // load filtered (s_f, P_f) at n
    const size_t base = (size_t)n * 27 * B + seq;
    float s_f[6];
#pragma unroll
    for (int k = 0; k < 6; k++) s_f[k] = hist[base + (size_t)k * B];
    float Pf[6][6];
#pragma unroll
    for (int i = 0; i < 6; i++)
#pragma unroll
      for (int j = i; j < 6; j++) {
        const float v = hist[base + (size_t)(6 + uidx(i, j)) * B];
        Pf[i][j] = v;
        Pf[j][i] = v;
      }

    // recompute sp[n+1], F[n+1], Pp[n+1] from (s_f, P_f)
    const float tx = tanhf(100.0f * s_f[2]);
    const float ty = tanhf(100.0f * s_f[3]);
    float sp[6];
    sp[0] = s_f[0] + DTc * s_f[2];
    sp[1] = s_f[1] + DTc * s_f[3];
    sp[2] = s_f[2] - DTc * (damping * s_f[2] + friction * tx);
    sp[3] = s_f[3] - DTc * (damping * s_f[3] + friction * ty);
    sp[4] = s_f[4] + DTc * s_f[5];
    sp[5] = s_f[5] * dcoef;
    const float gx = 1.0f - DTc * (damping + friction * 100.0f * (1.0f - tx * tx));
    const float gy = 1.0f - DTc * (damping + friction * 100.0f * (1.0f - ty * ty));

    // W = F P_f
    float W[6][6];
#pragma unroll
    for (int j = 0; j < 6; j++) {
      W[0][j] = Pf[0][j] + DTc * Pf[2][j];
      W[1][j] = Pf[1][j] + DTc * Pf[3][j];
      W[2][j] = gx * Pf[2][j];
      W[3][j] = gy * Pf[3][j];
      W[4][j] = Pf[4][j] + DTc * Pf[5][j];
      W[5][j] = dcoef * Pf[5][j];
    }
    // Pp = W F^T + Q
    float Pp[6][6];
#pragma unroll
    for (int i = 0; i < 6; i++) {
      Pp[i][0] = W[i][0] + DTc * W[i][2];
      Pp[i][1] = W[i][1] + DTc * W[i][3];
      Pp[i][2] = gx * W[i][2];
      Pp[i][3] = gy * W[i][3];
      Pp[i][4] = W[i][4] + DTc * W[i][5];
      Pp[i][5] = dcoef * W[i][5];
    }
#pragma unroll
    for (int i = 0; i < 6; i++) Pp[i][i] += q[i];

    // M = P_next - Pp ; ds = s_next - sp   (before Cholesky destroys Pp)
    float M[6][6];
#pragma unroll
    for (int i = 0; i < 6; i++)
#pragma unroll
      for (int j = 0; j < 6; j++) M[i][j] = Pn[i][j] - Pp[i][j];
    float ds[6];
#pragma unroll
    for (int j = 0; j < 6; j++) ds[j] = sn[j] - sp[j];

    // Cholesky of Pp in place (lower), rd = 1/diag
    float rd[6];
#pragma unroll
    for (int k = 0; k < 6; k++) {
      float dv = Pp[k][k];
#pragma unroll
      for (int m = 0; m < k; m++) dv -= Pp[k][m] * Pp[k][m];
      dv = sqrtf(fmaxf(dv, 1e-30f));
      Pp[k][k] = dv;
      rd[k] = 1.0f / dv;
#pragma unroll
      for (int i = k + 1; i < 6; i++) {
        float v = Pp[i][k];
#pragma unroll
        for (int m = 0; m < k; m++) v -= Pp[i][m] * Pp[k][m];
        Pp[i][k] = v * rd[k];
      }
    }

    // X = Pp^{-1} W, in place in W (column-wise fwd/back substitution)
#pragma unroll
    for (int c = 0; c < 6; c++) {
      float y[6];
#pragma unroll
      for (int i = 0; i < 6; i++) {
        float v = W[i][c];
#pragma unroll
        for (int m = 0; m < i; m++) v -= Pp[i][m] * y[m];
        y[i] = v * rd[i];
      }
#pragma unroll
      for (int i = 5; i >= 0; i--) {
        float v = y[i];
#pragma unroll
        for (int m = i + 1; m < 6; m++) v -= Pp[m][i] * W[m][c];
        W[i][c] = v * rd[i];
      }
    }
    // G[i][j] == W[j][i]  (G = P_f F^T Pp^{-1} = X^T)

    // s_s = s_f + G ds
    float ss[6];
#pragma unroll
    for (int i = 0; i < 6; i++) {
      float v = s_f[i];
#pragma unroll
      for (int j = 0; j < 6; j++) v += W[j][i] * ds[j];
      ss[i] = v;
    }
    // GM = G M
    float GM[6][6];
#pragma unroll
    for (int i = 0; i < 6; i++)
#pragma unroll
      for (int k = 0; k < 6; k++) {
        float v = 0.0f;
#pragma unroll
        for (int j = 0; j < 6; j++) v += W[j][i] * M[j][k];
        GM[i][k] = v;
      }
    // P_s = P_f + GM G^T  (upper, mirrored) -> new carry
#pragma unroll
    for (int i = 0; i < 6; i++)
#pragma unroll
      for (int j = i; j < 6; j++) {
        float v = Pf[i][j];
#pragma unroll
        for (int k = 0; k < 6; k++) v += GM[i][k] * W[k][j];
        Pn[i][j] = v;
        Pn[j][i] = v;
      }
#pragma unroll
    for (int i = 0; i < 6; i++) sn[i] = ss[i];

    if (n >= 2)
      loss += loss_term(Pn, sn, zs[n * 3 + 0], zs[n * 3 + 1], zs[n * 3 + 2],
                        r0, r1, r2);
  }

  // ================= reduce =================
#pragma unroll
  for (int off = 32; off > 0; off >>= 1) loss += __shfl_down(loss, off);
  if (threadIdx.x == 0) atomicAdd(out, loss);
}

}  // namespace

extern "C" void kernel_launch(void* const* d_in, const int* in_sizes, int n_in,
                              void* d_out, int out_size, void* d_ws, size_t ws_size,
                              hipStream_t stream) {
  const float* params      = (const float*)d_in[0];
  const float* covp        = (const float*)d_in[1];
  const float* init_states = (const float*)d_in[2];
  const float* z           = (const float*)d_in[3];
  float* out = (float*)d_out;
  float* hist = (float*)d_ws;  // needs 128*27*4096*4 = 56.6 MB

  hipMemsetAsync(d_out, 0, sizeof(float), stream);
  ekf_smooth_loss_kernel<<<B / 64, 64, 0, stream>>>(params, covp, init_states,
                                                    z, hist, out);
}

// Round 2
// 477.179 us; speedup vs baseline: 1.1129x; 1.1129x over previous
//
#include <hip/hip_runtime.h>
#include <cmath>

// Kalman_Smooth_Gradient: B=4096 seqs, T=128 steps, 6-state EKF + RTS + loss.
// Round 2: 3-phase split.
//   Phase 1 (fwd):  serial EKF per seq (64 waves), stores (s_f, P_f) = 27 f32/step.
//   Phase 2 (ops):  B*(T-1) = 520K parallel threads compute the affine backward
//                   operator (G, b, C) per step: ALL the Cholesky/solve work.
//   Phase 3 (bwd):  serial per seq, but each step is only "apply affine op":
//                   s = G s + b ; P = C + G P G^T ; loss.
// Fallback to the round-1 monolith if ws_size < 187 MB.

namespace {

constexpr int B = 4096;
constexpr int T = 128;
constexpr float DTc     = 1.0f / 120.0f;
constexpr float TWO_PIc = 6.28318530717958647692f;
constexpr float PI_1_5  = 4.71238898038468985769f;  // 1.5*pi

__device__ __forceinline__ float frcp(float x) { return __builtin_amdgcn_rcpf(x); }

__device__ __forceinline__ float fast_tanh(float x) {
  // 1 - 2/(e^{2x}+1): exact at +-inf (no inf/inf), ~1e-6 rel err.
  float e = __expf(2.0f * x);
  return 1.0f - 2.0f * frcp(e + 1.0f);
}
__device__ __forceinline__ float sigmoidf(float x) {
  return frcp(1.0f + __expf(-x));
}

__device__ __forceinline__ int uidx(int i, int j) {  // i<=j, upper-tri row-major
  return i * 6 - i * (i - 1) / 2 + (j - i);
}

// loss term: det(Sv) + e^T Sv e with Sv = H P H^T + R
__device__ __forceinline__ float loss_term(const float Pm[6][6], const float sv[6],
                                           float z0, float z1, float z2,
                                           float r0, float r1, float r2) {
  float a = Pm[0][0] + r0, b = Pm[0][1], c = Pm[0][4];
  float d = Pm[1][1] + r1, e = Pm[1][4], f = Pm[4][4] + r2;
  float det = a * (d * f - e * e) + b * (c * e - b * f) + c * (b * e - d * c);
  float e0 = z0 - sv[0], e1 = z1 - sv[1], aa = z2 - sv[4];
  if (aa >  PI_1_5) aa -= TWO_PIc;
  if (aa < -PI_1_5) aa += TWO_PIc;
  float quad = a * e0 * e0 + d * e1 * e1 + f * aa * aa +
               2.0f * (b * e0 * e1 + c * e0 * aa + e * e1 * aa);
  return det + quad;
}

// ---------------------------------------------------------------------------
// Phase 1: forward EKF, store (s_f, P_f upper) = 27 f32 per (t, seq).
// hist layout: hist[(t*27 + k)*B + seq]  (coalesced across seq)
// ---------------------------------------------------------------------------
__global__ __launch_bounds__(64, 1) void fwd_kernel(
    const float* __restrict__ params, const float* __restrict__ covp,
    const float* __restrict__ init_states, const float* __restrict__ z,
    float* __restrict__ hist) {
  const int seq = blockIdx.x * blockDim.x + threadIdx.x;
  if (seq >= B) return;

  const float friction = (fast_tanh(params[0]) + 1.0f) * 0.01f;
  const float damping  = (fast_tanh(params[1]) + 1.0f) * 0.01f;
  float cp[7];
#pragma unroll
  for (int i = 0; i < 7; i++) cp[i] = sigmoidf(covp[i]);
  const float r0 = cp[0], r1 = cp[1], r2 = cp[2];
  const float q[6] = {cp[3], cp[3], cp[4], cp[4], cp[5], cp[6]};
  const float dcoef = 1.0f - DTc * damping;

  float s[6];
#pragma unroll
  for (int i = 0; i < 6; i++) s[i] = init_states[seq * 6 + i];
  float P[6][6];
#pragma unroll
  for (int i = 0; i < 6; i++)
#pragma unroll
    for (int j = 0; j < 6; j++) P[i][j] = (i == j) ? 0.01f : 0.0f;

  const float* __restrict__ zs = z + (size_t)seq * T * 3;

#pragma unroll 1
  for (int t = 0; t < T; t++) {
    const float tx = fast_tanh(100.0f * s[2]);
    const float ty = fast_tanh(100.0f * s[3]);
    float sp[6];
    sp[0] = s[0] + DTc * s[2];
    sp[1] = s[1] + DTc * s[3];
    sp[2] = s[2] - DTc * (damping * s[2] + friction * tx);
    sp[3] = s[3] - DTc * (damping * s[3] + friction * ty);
    sp[4] = s[4] + DTc * s[5];
    sp[5] = s[5] * dcoef;
    const float gx = 1.0f - DTc * (damping + friction * 100.0f * (1.0f - tx * tx));
    const float gy = 1.0f - DTc * (damping + friction * 100.0f * (1.0f - ty * ty));

    float A[6][6];
#pragma unroll
    for (int j = 0; j < 6; j++) {
      A[0][j] = P[0][j] + DTc * P[2][j];
      A[1][j] = P[1][j] + DTc * P[3][j];
      A[2][j] = gx * P[2][j];
      A[3][j] = gy * P[3][j];
      A[4][j] = P[4][j] + DTc * P[5][j];
      A[5][j] = dcoef * P[5][j];
    }
    float Pp[6][6];
#pragma unroll
    for (int i = 0; i < 6; i++) {
      Pp[i][0] = A[i][0] + DTc * A[i][2];
      Pp[i][1] = A[i][1] + DTc * A[i][3];
      Pp[i][2] = gx * A[i][2];
      Pp[i][3] = gy * A[i][3];
      Pp[i][4] = A[i][4] + DTc * A[i][5];
      Pp[i][5] = dcoef * A[i][5];
    }
#pragma unroll
    for (int i = 0; i < 6; i++) Pp[i][i] += q[i];

    const float Sa = Pp[0][0] + r0, Sb = Pp[0][1], Sc = Pp[0][4];
    const float Sd = Pp[1][1] + r1, Se = Pp[1][4], Sf = Pp[4][4] + r2;
    const float C00 = Sd * Sf - Se * Se;
    const float C01 = Sc * Se - Sb * Sf;
    const float C02 = Sb * Se - Sd * Sc;
    const float det = Sa * C00 + Sb * C01 + Sc * C02;
    const float idet = frcp(det);
    const float Si00 = C00 * idet, Si01 = C01 * idet, Si02 = C02 * idet;
    const float Si11 = (Sa * Sf - Sc * Sc) * idet;
    const float Si12 = (Sb * Sc - Sa * Se) * idet;
    const float Si22 = (Sa * Sd - Sb * Sb) * idet;

    float K[6][3];
#pragma unroll
    for (int i = 0; i < 6; i++) {
      const float u0 = Pp[i][0], u1 = Pp[i][1], u2 = Pp[i][4];
      K[i][0] = u0 * Si00 + u1 * Si01 + u2 * Si02;
      K[i][1] = u0 * Si01 + u1 * Si11 + u2 * Si12;
      K[i][2] = u0 * Si02 + u1 * Si12 + u2 * Si22;
    }

    const float z0 = zs[t * 3 + 0], z1 = zs[t * 3 + 1], z2 = zs[t * 3 + 2];
    const float i0 = z0 - sp[0];
    const float i1 = z1 - sp[1];
    float ia = z2 - sp[4];
    ia = ia - TWO_PIc * rintf(ia * (1.0f / TWO_PIc));

#pragma unroll
    for (int i = 0; i < 6; i++)
      s[i] = sp[i] + K[i][0] * i0 + K[i][1] * i1 + K[i][2] * ia;

#pragma unroll
    for (int i = 0; i < 6; i++)
#pragma unroll
      for (int j = i; j < 6; j++) {
        const float v = Pp[i][j] -
            (K[i][0] * Pp[0][j] + K[i][1] * Pp[1][j] + K[i][2] * Pp[4][j]);
        P[i][j] = v;
        P[j][i] = v;
      }

    float* __restrict__ h = hist + (size_t)t * 27 * B + seq;
#pragma unroll
    for (int k = 0; k < 6; k++) h[(size_t)k * B] = s[k];
#pragma unroll
    for (int i = 0; i < 6; i++)
#pragma unroll
      for (int j = i; j < 6; j++) h[(size_t)(6 + uidx(i, j)) * B] = P[i][j];
  }
}

// ---------------------------------------------------------------------------
// Phase 2: per (seq, n) for n in [0, T-2], compute the backward affine op:
//   G = P_f F^T Pp^{-1}, b = s_f - G sp, C = P_f - G Pp G^T (= P_f - W^T X)
// ops layout: ops[(n*63 + k)*B + seq], k: 0..35 G row-major, 36..41 b, 42..62 C upper
// ---------------------------------------------------------------------------
__global__ __launch_bounds__(256, 2) void ops_kernel(
    const float* __restrict__ params, const float* __restrict__ covp,
    const float* __restrict__ hist, float* __restrict__ ops) {
  const int tid = blockIdx.x * 256 + threadIdx.x;
  const int seq = tid & (B - 1);
  const int n = tid >> 12;  // log2(B) = 12
  if (n >= T - 1) return;

  const float friction = (fast_tanh(params[0]) + 1.0f) * 0.01f;
  const float damping  = (fast_tanh(params[1]) + 1.0f) * 0.01f;
  const float cp3 = sigmoidf(covp[3]), cp4 = sigmoidf(covp[4]);
  const float cp5 = sigmoidf(covp[5]), cp6 = sigmoidf(covp[6]);
  const float q[6] = {cp3, cp3, cp4, cp4, cp5, cp6};
  const float dcoef = 1.0f - DTc * damping;

  const float* __restrict__ h = hist + (size_t)n * 27 * B + seq;
  float s_f[6];
#pragma unroll
  for (int k = 0; k < 6; k++) s_f[k] = h[(size_t)k * B];
  float Pf[6][6];
#pragma unroll
  for (int i = 0; i < 6; i++)
#pragma unroll
    for (int j = i; j < 6; j++) {
      const float v = h[(size_t)(6 + uidx(i, j)) * B];
      Pf[i][j] = v;
      Pf[j][i] = v;
    }

  const float tx = fast_tanh(100.0f * s_f[2]);
  const float ty = fast_tanh(100.0f * s_f[3]);
  float sp[6];
  sp[0] = s_f[0] + DTc * s_f[2];
  sp[1] = s_f[1] + DTc * s_f[3];
  sp[2] = s_f[2] - DTc * (damping * s_f[2] + friction * tx);
  sp[3] = s_f[3] - DTc * (damping * s_f[3] + friction * ty);
  sp[4] = s_f[4] + DTc * s_f[5];
  sp[5] = s_f[5] * dcoef;
  const float gx = 1.0f - DTc * (damping + friction * 100.0f * (1.0f - tx * tx));
  const float gy = 1.0f - DTc * (damping + friction * 100.0f * (1.0f - ty * ty));

  // W = F P_f
  float W[6][6];
#pragma unroll
  for (int j = 0; j < 6; j++) {
    W[0][j] = Pf[0][j] + DTc * Pf[2][j];
    W[1][j] = Pf[1][j] + DTc * Pf[3][j];
    W[2][j] = gx * Pf[2][j];
    W[3][j] = gy * Pf[3][j];
    W[4][j] = Pf[4][j] + DTc * Pf[5][j];
    W[5][j] = dcoef * Pf[5][j];
  }
  // Pp = W F^T + Q
  float Pp[6][6];
#pragma unroll
  for (int i = 0; i < 6; i++) {
    Pp[i][0] = W[i][0] + DTc * W[i][2];
    Pp[i][1] = W[i][1] + DTc * W[i][3];
    Pp[i][2] = gx * W[i][2];
    Pp[i][3] = gy * W[i][3];
    Pp[i][4] = W[i][4] + DTc * W[i][5];
    Pp[i][5] = dcoef * W[i][5];
  }
#pragma unroll
  for (int i = 0; i < 6; i++) Pp[i][i] += q[i];

  // Cholesky of Pp in place (lower), rd = 1/diag
  float rd[6];
#pragma unroll
  for (int k = 0; k < 6; k++) {
    float dv = Pp[k][k];
#pragma unroll
    for (int m = 0; m < k; m++) dv -= Pp[k][m] * Pp[k][m];
    dv = sqrtf(fmaxf(dv, 1e-30f));
    Pp[k][k] = dv;
    rd[k] = frcp(dv);
#pragma unroll
    for (int i = k + 1; i < 6; i++) {
      float v = Pp[i][k];
#pragma unroll
      for (int m = 0; m < k; m++) v -= Pp[i][m] * Pp[k][m];
      Pp[i][k] = v * rd[k];
    }
  }

  // X = Pp^{-1} W, in place in W
#pragma unroll
  for (int c = 0; c < 6; c++) {
    float y[6];
#pragma unroll
    for (int i = 0; i < 6; i++) {
      float v = W[i][c];
#pragma unroll
      for (int m = 0; m < i; m++) v -= Pp[i][m] * y[m];
      y[i] = v * rd[i];
    }
#pragma unroll
    for (int i = 5; i >= 0; i--) {
      float v = y[i];
#pragma unroll
      for (int m = i + 1; m < 6; m++) v -= Pp[m][i] * W[m][c];
      W[i][c] = v * rd[i];
    }
  }
  // Now W holds X; G[i][j] = X[j][i].

  float* __restrict__ o = ops + (size_t)n * 63 * B + seq;
#pragma unroll
  for (int i = 0; i < 6; i++)
#pragma unroll
    for (int j = 0; j < 6; j++) o[(size_t)(i * 6 + j) * B] = W[j][i];

  // b = s_f - G sp = s_f - X^T sp
#pragma unroll
  for (int i = 0; i < 6; i++) {
    float v = s_f[i];
#pragma unroll
    for (int j = 0; j < 6; j++) v -= W[j][i] * sp[j];
    o[(size_t)(36 + i) * B] = v;
  }

  // C = P_f - Worig^T X ; Worig column i regenerated from Pf (W = F Pf):
#pragma unroll
  for (int i = 0; i < 6; i++) {
    float w[6];
    w[0] = Pf[0][i] + DTc * Pf[2][i];
    w[1] = Pf[1][i] + DTc * Pf[3][i];
    w[2] = gx * Pf[2][i];
    w[3] = gy * Pf[3][i];
    w[4] = Pf[4][i] + DTc * Pf[5][i];
    w[5] = dcoef * Pf[5][i];
#pragma unroll
    for (int j = i; j < 6; j++) {
      float v = Pf[i][j];
#pragma unroll
      for (int k = 0; k < 6; k++) v -= w[k] * W[k][j];
      o[(size_t)(42 + uidx(i, j)) * B] = v;
    }
  }
}

// ---------------------------------------------------------------------------
// Phase 3: serial backward, applying stored affine ops + loss.
// ---------------------------------------------------------------------------
__global__ __launch_bounds__(64, 1) void bwd_kernel(
    const float* __restrict__ covp, const float* __restrict__ z,
    const float* __restrict__ hist, const float* __restrict__ ops,
    float* __restrict__ out) {
  const int seq = blockIdx.x * blockDim.x + threadIdx.x;
  if (seq >= B) return;

  const float r0 = sigmoidf(covp[0]);
  const float r1 = sigmoidf(covp[1]);
  const float r2 = sigmoidf(covp[2]);
  const float* __restrict__ zs = z + (size_t)seq * T * 3;

  // init from filtered at T-1
  const float* __restrict__ h = hist + (size_t)(T - 1) * 27 * B + seq;
  float sn[6];
#pragma unroll
  for (int k = 0; k < 6; k++) sn[k] = h[(size_t)k * B];
  float Pn[6][6];
#pragma unroll
  for (int i = 0; i < 6; i++)
#pragma unroll
    for (int j = i; j < 6; j++) {
      const float v = h[(size_t)(6 + uidx(i, j)) * B];
      Pn[i][j] = v;
      Pn[j][i] = v;
    }

  float loss = loss_term(Pn, sn, zs[(T - 1) * 3 + 0], zs[(T - 1) * 3 + 1],
                         zs[(T - 1) * 3 + 2], r0, r1, r2);

#pragma unroll 1
  for (int n = T - 2; n >= 0; n--) {
    const float* __restrict__ o = ops + (size_t)n * 63 * B + seq;
    float G[6][6];
#pragma unroll
    for (int i = 0; i < 6; i++)
#pragma unroll
      for (int j = 0; j < 6; j++) G[i][j] = o[(size_t)(i * 6 + j) * B];
    float bv[6];
#pragma unroll
    for (int i = 0; i < 6; i++) bv[i] = o[(size_t)(36 + i) * B];
    float C[21];
#pragma unroll
    for (int k = 0; k < 21; k++) C[k] = o[(size_t)(42 + k) * B];

    // s = G s + b
    float ns[6];
#pragma unroll
    for (int i = 0; i < 6; i++) {
      float v = bv[i];
#pragma unroll
      for (int j = 0; j < 6; j++) v += G[i][j] * sn[j];
      ns[i] = v;
    }
    // Y = G Pn
    float Y[6][6];
#pragma unroll
    for (int i = 0; i < 6; i++)
#pragma unroll
      for (int k = 0; k < 6; k++) {
        float v = 0.0f;
#pragma unroll
        for (int j = 0; j < 6; j++) v += G[i][j] * Pn[j][k];
        Y[i][k] = v;
      }
    // Pn = C + Y G^T  (upper, mirrored)
#pragma unroll
    for (int i = 0; i < 6; i++)
#pragma unroll
      for (int j = i; j < 6; j++) {
        float v = C[uidx(i, j)];
#pragma unroll
        for (int k = 0; k < 6; k++) v += Y[i][k] * G[j][k];
        Pn[i][j] = v;
        Pn[j][i] = v;
      }
#pragma unroll
    for (int i = 0; i < 6; i++) sn[i] = ns[i];

    if (n >= 2)
      loss += loss_term(Pn, sn, zs[n * 3 + 0], zs[n * 3 + 1], zs[n * 3 + 2],
                        r0, r1, r2);
  }

#pragma unroll
  for (int off = 32; off > 0; off >>= 1) loss += __shfl_down(loss, off);
  if (threadIdx.x == 0) atomicAdd(out, loss);
}

// ---------------------------------------------------------------------------
// Fallback monolith (round-1 structure, fast tanh) if ws is too small.
// ---------------------------------------------------------------------------
__global__ __launch_bounds__(64, 1) void mono_kernel(
    const float* __restrict__ params, const float* __restrict__ covp,
    const float* __restrict__ init_states, const float* __restrict__ z,
    float* __restrict__ hist, float* __restrict__ out) {
  const int seq = blockIdx.x * blockDim.x + threadIdx.x;
  if (seq >= B) return;

  const float friction = (fast_tanh(params[0]) + 1.0f) * 0.01f;
  const float damping  = (fast_tanh(params[1]) + 1.0f) * 0.01f;
  float cp[7];
#pragma unroll
  for (int i = 0; i < 7; i++) cp[i] = sigmoidf(covp[i]);
  const float r0 = cp[0], r1 = cp[1], r2 = cp[2];
  const float q[6] = {cp[3], cp[3], cp[4], cp[4], cp[5], cp[6]};
  const float dcoef = 1.0f - DTc * damping;

  float s[6];
#pragma unroll
  for (int i = 0; i < 6; i++) s[i] = init_states[seq * 6 + i];
  float P[6][6];
#pragma unroll
  for (int i = 0; i < 6; i++)
#pragma unroll
    for (int j = 0; j < 6; j++) P[i][j] = (i == j) ? 0.01f : 0.0f;

  const float* __restrict__ zs = z + (size_t)seq * T * 3;

#pragma unroll 1
  for (int t = 0; t < T; t++) {
    const float tx = fast_tanh(100.0f * s[2]);
    const float ty = fast_tanh(100.0f * s[3]);
    float sp[6];
    sp[0] = s[0] + DTc * s[2];
    sp[1] = s[1] + DTc * s[3];
    sp[2] = s[2] - DTc * (damping * s[2] + friction * tx);
    sp[3] = s[3] - DTc * (damping * s[3] + friction * ty);
    sp[4] = s[4] + DTc * s[5];
    sp[5] = s[5] * dcoef;
    const float gx = 1.0f - DTc * (damping + friction * 100.0f * (1.0f - tx * tx));
    const float gy = 1.0f - DTc * (damping + friction * 100.0f * (1.0f - ty * ty));

    float A[6][6];
#pragma unroll
    for (int j = 0; j < 6; j++) {
      A[0][j] = P[0][j] + DTc * P[2][j];
      A[1][j] = P[1][j] + DTc * P[3][j];
      A[2][j] = gx * P[2][j];
      A[3][j] = gy * P[3][j];
      A[4][j] = P[4][j] + DTc * P[5][j];
      A[5][j] = dcoef * P[5][j];
    }
    float Pp[6][6];
#pragma unroll
    for (int i = 0; i < 6; i++) {
      Pp[i][0] = A[i][0] + DTc * A[i][2];
      Pp[i][1] = A[i][1] + DTc * A[i][3];
      Pp[i][2] = gx * A[i][2];
      Pp[i][3] = gy * A[i][3];
      Pp[i][4] = A[i][4] + DTc * A[i][5];
      Pp[i][5] = dcoef * A[i][5];
    }
#pragma unroll
    for (int i = 0; i < 6; i++) Pp[i][i] += q[i];

    const float Sa = Pp[0][0] + r0, Sb = Pp[0][1], Sc = Pp[0][4];
    const float Sd = Pp[1][1] + r1, Se = Pp[1][4], Sf = Pp[4][4] + r2;
    const float C00 = Sd * Sf - Se * Se;
    const float C01 = Sc * Se - Sb * Sf;
    const float C02 = Sb * Se - Sd * Sc;
    const float det = Sa * C00 + Sb * C01 + Sc * C02;
    const float idet = frcp(det);
    const float Si00 = C00 * idet, Si01 = C01 * idet, Si02 = C02 * idet;
    const float Si11 = (Sa * Sf - Sc * Sc) * idet;
    const float Si12 = (Sb * Sc - Sa * Se) * idet;
    const float Si22 = (Sa * Sd - Sb * Sb) * idet;

    float K[6][3];
#pragma unroll
    for (int i = 0; i < 6; i++) {
      const float u0 = Pp[i][0], u1 = Pp[i][1], u2 = Pp[i][4];
      K[i][0] = u0 * Si00 + u1 * Si01 + u2 * Si02;
      K[i][1] = u0 * Si01 + u1 * Si11 + u2 * Si12;
      K[i][2] = u0 * Si02 + u1 * Si12 + u2 * Si22;
    }

    const float z0 = zs[t * 3 + 0], z1 = zs[t * 3 + 1], z2 = zs[t * 3 + 2];
    const float i0 = z0 - sp[0];
    const float i1 = z1 - sp[1];
    float ia = z2 - sp[4];
    ia = ia - TWO_PIc * rintf(ia * (1.0f / TWO_PIc));

#pragma unroll
    for (int i = 0; i < 6; i++)
      s[i] = sp[i] + K[i][0] * i0 + K[i][1] * i1 + K[i][2] * ia;

#pragma unroll
    for (int i = 0; i < 6; i++)
#pragma unroll
      for (int j = i; j < 6; j++) {
        const float v = Pp[i][j] -
            (K[i][0] * Pp[0][j] + K[i][1] * Pp[1][j] + K[i][2] * Pp[4][j]);
        P[i][j] = v;
        P[j][i] = v;
      }

    float* __restrict__ hh = hist + (size_t)t * 27 * B + seq;
#pragma unroll
    for (int k = 0; k < 6; k++) hh[(size_t)k * B] = s[k];
#pragma unroll
    for (int i = 0; i < 6; i++)
#pragma unroll
      for (int j = i; j < 6; j++) hh[(size_t)(6 + uidx(i, j)) * B] = P[i][j];
  }

  float loss = loss_term(P, s, zs[(T - 1) * 3 + 0], zs[(T - 1) * 3 + 1],
                         zs[(T - 1) * 3 + 2], r0, r1, r2);

  float sn[6];
#pragma unroll
  for (int i = 0; i < 6; i++) sn[i] = s[i];
  float Pn[6][6];
#pragma unroll
  for (int i = 0; i < 6; i++)
#pragma unroll
    for (int j = 0; j < 6; j++) Pn[i][j] = P[i][j];

#pragma unroll 1
  for (int n = T - 2; n >= 0; n--) {
    const size_t base = (size_t)n * 27 * B + seq;
    float s_f[6];
#pragma unroll
    for (int k = 0; k < 6; k++) s_f[k] = hist[base + (size_t)k * B];
    float Pf[6][6];
#pragma unroll
    for (int i = 0; i < 6; i++)
#pragma unroll
      for (int j = i; j < 6; j++) {
        const float v = hist[base + (size_t)(6 + uidx(i, j)) * B];
        Pf[i][j] = v;
        Pf[j][i] = v;
      }

    const float tx = fast_tanh(100.0f * s_f[2]);
    const float ty = fast_tanh(100.0f * s_f[3]);
    float sp[6];
    sp[0] = s_f[0] + DTc * s_f[2];
    sp[1] = s_f[1] + DTc * s_f[3];
    sp[2] = s_f[2] - DTc * (damping * s_f[2] + friction * tx);
    sp[3] = s_f[3] - DTc * (damping * s_f[3] + friction * ty);
    sp[4] = s_f[4] + DTc * s_f[5];
    sp[5] = s_f[5] * dcoef;
    const float gx = 1.0f - DTc * (damping + friction * 100.0f * (1.0f - tx * tx));
    const float gy = 1.0f - DTc * (damping + friction * 100.0f * (1.0f - ty * ty));

    float W[6][6];
#pragma unroll
    for (int j = 0; j < 6; j++) {
      W[0][j] = Pf[0][j] + DTc * Pf[2][j];
      W[1][j] = Pf[1][j] + DTc * Pf[3][j];
      W[2][j] = gx * Pf[2][j];
      W[3][j] = gy * Pf[3][j];
      W[4][j] = Pf[4][j] + DTc * Pf[5][j];
      W[5][j] = dcoef * Pf[5][j];
    }
    float Pp[6][6];
#pragma unroll
    for (int i = 0; i < 6; i++) {
      Pp[i][0] = W[i][0] + DTc * W[i][2];
      Pp[i][1] = W[i][1] + DTc * W[i][3];
      Pp[i][2] = gx * W[i][2];
      Pp[i][3] = gy * W[i][3];
      Pp[i][4] = W[i][4] + DTc * W[i][5];
      Pp[i][5] = dcoef * W[i][5];
    }
#pragma unroll
    for (int i = 0; i < 6; i++) Pp[i][i] += q[i];

    float M[6][6];
#pragma unroll
    for (int i = 0; i < 6; i++)
#pragma unroll
      for (int j = 0; j < 6; j++) M[i][j] = Pn[i][j] - Pp[i][j];
    float ds[6];
#pragma unroll
    for (int j = 0; j < 6; j++) ds[j] = sn[j] - sp[j];

    float rd[6];
#pragma unroll
    for (int k = 0; k < 6; k++) {
      float dv = Pp[k][k];
#pragma unroll
      for (int m = 0; m < k; m++) dv -= Pp[k][m] * Pp[k][m];
      dv = sqrtf(fmaxf(dv, 1e-30f));
      Pp[k][k] = dv;
      rd[k] = frcp(dv);
#pragma unroll
      for (int i = k + 1; i < 6; i++) {
        float v = Pp[i][k];
#pragma unroll
        for (int m = 0; m < k; m++) v -= Pp[i][m] * Pp[k][m];
        Pp[i][k] = v * rd[k];
      }
    }

#pragma unroll
    for (int c = 0; c < 6; c++) {
      float y[6];
#pragma unroll
      for (int i = 0; i < 6; i++) {
        float v = W[i][c];
#pragma unroll
        for (int m = 0; m < i; m++) v -= Pp[i][m] * y[m];
        y[i] = v * rd[i];
      }
#pragma unroll
      for (int i = 5; i >= 0; i--) {
        float v = y[i];
#pragma unroll
        for (int m = i + 1; m < 6; m++) v -= Pp[m][i] * W[m][c];
        W[i][c] = v * rd[i];
      }
    }

    float ss[6];
#pragma unroll
    for (int i = 0; i < 6; i++) {
      float v = s_f[i];
#pragma unroll
      for (int j = 0; j < 6; j++) v += W[j][i] * ds[j];
      ss[i] = v;
    }
    float GM[6][6];
#pragma unroll
    for (int i = 0; i < 6; i++)
#pragma unroll
      for (int k = 0; k < 6; k++) {
        float v = 0.0f;
#pragma unroll
        for (int j = 0; j < 6; j++) v += W[j][i] * M[j][k];
        GM[i][k] = v;
      }
#pragma unroll
    for (int i = 0; i < 6; i++)
#pragma unroll
      for (int j = i; j < 6; j++) {
        float v = Pf[i][j];
#pragma unroll
        for (int k = 0; k < 6; k++) v += GM[i][k] * W[k][j];
        Pn[i][j] = v;
        Pn[j][i] = v;
      }
#pragma unroll
    for (int i = 0; i < 6; i++) sn[i] = ss[i];

    if (n >= 2)
      loss += loss_term(Pn, sn, zs[n * 3 + 0], zs[n * 3 + 1], zs[n * 3 + 2],
                        r0, r1, r2);
  }

#pragma unroll
  for (int off = 32; off > 0; off >>= 1) loss += __shfl_down(loss, off);
  if (threadIdx.x == 0) atomicAdd(out, loss);
}

}  // namespace

extern "C" void kernel_launch(void* const* d_in, const int* in_sizes, int n_in,
                              void* d_out, int out_size, void* d_ws, size_t ws_size,
                              hipStream_t stream) {
  const float* params      = (const float*)d_in[0];
  const float* covp        = (const float*)d_in[1];
  const float* init_states = (const float*)d_in[2];
  const float* z           = (const float*)d_in[3];
  float* out = (float*)d_out;

  const size_t histBytes = (size_t)T * 27 * B * sizeof(float);      // 56.6 MB
  const size_t opsBytes  = (size_t)(T - 1) * 63 * B * sizeof(float); // 130.5 MB

  hipMemsetAsync(d_out, 0, sizeof(float), stream);

  if (ws_size >= histBytes + opsBytes) {
    float* hist = (float*)d_ws;
    float* ops  = (float*)((char*)d_ws + histBytes);
    fwd_kernel<<<B / 64, 64, 0, stream>>>(params, covp, init_states, z, hist);
    ops_kernel<<<(T - 1) * B / 256, 256, 0, stream>>>(params, covp, hist, ops);
    bwd_kernel<<<B / 64, 64, 0, stream>>>(covp, z, hist, ops, out);
  } else {
    float* hist = (float*)d_ws;  // 56.6 MB fallback path
    mono_kernel<<<B / 64, 64, 0, stream>>>(params, covp, init_states, z, hist, out);
  }
}

// Round 3
// 304.208 us; speedup vs baseline: 1.7457x; 1.5686x over previous
//
#include <hip/hip_runtime.h>
#include <cmath>

// Kalman_Smooth_Gradient: B=4096 seqs, T=128 steps, 6-state EKF + RTS + loss.
// Round 3: backward pass as a two-level chunked associative scan.
//   ztrans: z [seq][t][3] -> zT [t][3][B]   (coalesced loads everywhere)
//   fwd:    serial EKF per seq (64 waves), stores (s_f, P_f) = 27 f32/step
//   A (chunkops): B*NC threads; compose 8 per-step affine ops -> 1 chunk op
//   B (chunkscan): 64 waves, only NC=16 serial steps; stores chunk-entry states
//   C (applyloss): B*NC threads; redo 8 RTS steps from chunk entry + loss
// The per-step backward op (G,b,C) is recomputed from hist in A and C (ALU is
// free at 1024 waves; avoids a 130 MB op buffer).

namespace {

constexpr int B = 4096;
constexpr int T = 128;
constexpr int NC = 16;   // chunks over n = 0..126 (last chunk has 7 steps)
constexpr float DTc     = 1.0f / 120.0f;
constexpr float TWO_PIc = 6.28318530717958647692f;
constexpr float PI_1_5  = 4.71238898038468985769f;  // 1.5*pi

__device__ __forceinline__ float frcp(float x) { return __builtin_amdgcn_rcpf(x); }

__device__ __forceinline__ float fast_tanh(float x) {
  float e = __expf(2.0f * x);
  return 1.0f - 2.0f * frcp(e + 1.0f);
}
__device__ __forceinline__ float sigmoidf(float x) {
  return frcp(1.0f + __expf(-x));
}

__device__ __forceinline__ int uidx(int i, int j) {  // i<=j, upper-tri row-major
  return i * 6 - i * (i - 1) / 2 + (j - i);
}

// loss term: det(Sv) + e^T Sv e with Sv = H P H^T + R
__device__ __forceinline__ float loss_term(const float Pm[6][6], const float sv[6],
                                           float z0, float z1, float z2,
                                           float r0, float r1, float r2) {
  float a = Pm[0][0] + r0, b = Pm[0][1], c = Pm[0][4];
  float d = Pm[1][1] + r1, e = Pm[1][4], f = Pm[4][4] + r2;
  float det = a * (d * f - e * e) + b * (c * e - b * f) + c * (b * e - d * c);
  float e0 = z0 - sv[0], e1 = z1 - sv[1], aa = z2 - sv[4];
  if (aa >  PI_1_5) aa -= TWO_PIc;
  if (aa < -PI_1_5) aa += TWO_PIc;
  float quad = a * e0 * e0 + d * e1 * e1 + f * aa * aa +
               2.0f * (b * e0 * e1 + c * e0 * aa + e * e1 * aa);
  return det + quad;
}

// Core of one backward RTS step, from filtered (s_f, Pf) at n:
//   sp = f(s_f); W := X = Pp^{-1} (F Pf); Pp holds chol'd lower+diag with the
//   ORIGINAL strict upper intact; diag[] holds the original diagonal.
__device__ __forceinline__ void rts_core(
    const float s_f[6], const float Pf[6][6],
    float friction, float damping, float dcoef, const float* __restrict__ q,
    float sp[6], float W[6][6], float Pp[6][6], float diag[6],
    float& gxo, float& gyo) {
  const float tx = fast_tanh(100.0f * s_f[2]);
  const float ty = fast_tanh(100.0f * s_f[3]);
  sp[0] = s_f[0] + DTc * s_f[2];
  sp[1] = s_f[1] + DTc * s_f[3];
  sp[2] = s_f[2] - DTc * (damping * s_f[2] + friction * tx);
  sp[3] = s_f[3] - DTc * (damping * s_f[3] + friction * ty);
  sp[4] = s_f[4] + DTc * s_f[5];
  sp[5] = s_f[5] * dcoef;
  const float gx = 1.0f - DTc * (damping + friction * 100.0f * (1.0f - tx * tx));
  const float gy = 1.0f - DTc * (damping + friction * 100.0f * (1.0f - ty * ty));
  gxo = gx; gyo = gy;

  // W = F Pf
#pragma unroll
  for (int j = 0; j < 6; j++) {
    W[0][j] = Pf[0][j] + DTc * Pf[2][j];
    W[1][j] = Pf[1][j] + DTc * Pf[3][j];
    W[2][j] = gx * Pf[2][j];
    W[3][j] = gy * Pf[3][j];
    W[4][j] = Pf[4][j] + DTc * Pf[5][j];
    W[5][j] = dcoef * Pf[5][j];
  }
  // Pp = W F^T + Q
#pragma unroll
  for (int i = 0; i < 6; i++) {
    Pp[i][0] = W[i][0] + DTc * W[i][2];
    Pp[i][1] = W[i][1] + DTc * W[i][3];
    Pp[i][2] = gx * W[i][2];
    Pp[i][3] = gy * W[i][3];
    Pp[i][4] = W[i][4] + DTc * W[i][5];
    Pp[i][5] = dcoef * W[i][5];
  }
#pragma unroll
  for (int i = 0; i < 6; i++) { Pp[i][i] += q[i]; diag[i] = Pp[i][i]; }

  // Cholesky in place (writes strictly-lower + diagonal; strict upper intact)
  float rd[6];
#pragma unroll
  for (int k = 0; k < 6; k++) {
    float dv = Pp[k][k];
#pragma unroll
    for (int m = 0; m < k; m++) dv -= Pp[k][m] * Pp[k][m];
    dv = sqrtf(fmaxf(dv, 1e-30f));
    Pp[k][k] = dv;
    rd[k] = frcp(dv);
#pragma unroll
    for (int i = k + 1; i < 6; i++) {
      float v = Pp[i][k];
#pragma unroll
      for (int m = 0; m < k; m++) v -= Pp[i][m] * Pp[k][m];
      Pp[i][k] = v * rd[k];
    }
  }
  // X = Pp^{-1} W in place in W
#pragma unroll
  for (int c = 0; c < 6; c++) {
    float y[6];
#pragma unroll
    for (int i = 0; i < 6; i++) {
      float v = W[i][c];
#pragma unroll
      for (int m = 0; m < i; m++) v -= Pp[i][m] * y[m];
      y[i] = v * rd[i];
    }
#pragma unroll
    for (int i = 5; i >= 0; i--) {
      float v = y[i];
#pragma unroll
      for (int m = i + 1; m < 6; m++) v -= Pp[m][i] * W[m][c];
      W[i][c] = v * rd[i];
    }
  }
}

// ---------------------------------------------------------------------------
// z transpose: z[seq][t][3] -> zT[(t*3+k)*B + seq]
// ---------------------------------------------------------------------------
__global__ __launch_bounds__(256, 1) void ztrans_kernel(
    const float* __restrict__ z, float* __restrict__ zT) {
  const int tid = blockIdx.x * 256 + threadIdx.x;
  const int seq = tid & (B - 1);
  const int t = tid >> 12;
  const float a = z[(size_t)seq * (T * 3) + t * 3 + 0];
  const float b = z[(size_t)seq * (T * 3) + t * 3 + 1];
  const float c = z[(size_t)seq * (T * 3) + t * 3 + 2];
  zT[(size_t)(t * 3 + 0) * B + seq] = a;
  zT[(size_t)(t * 3 + 1) * B + seq] = b;
  zT[(size_t)(t * 3 + 2) * B + seq] = c;
}

// ---------------------------------------------------------------------------
// Phase 1: forward EKF, store (s_f, P_f upper) = 27 f32 per (t, seq).
// ---------------------------------------------------------------------------
__global__ __launch_bounds__(64, 1) void fwd_kernel(
    const float* __restrict__ params, const float* __restrict__ covp,
    const float* __restrict__ init_states, const float* __restrict__ zT,
    float* __restrict__ hist) {
  const int seq = blockIdx.x * blockDim.x + threadIdx.x;

  const float friction = (fast_tanh(params[0]) + 1.0f) * 0.01f;
  const float damping  = (fast_tanh(params[1]) + 1.0f) * 0.01f;
  float cp[7];
#pragma unroll
  for (int i = 0; i < 7; i++) cp[i] = sigmoidf(covp[i]);
  const float r0 = cp[0], r1 = cp[1], r2 = cp[2];
  const float q[6] = {cp[3], cp[3], cp[4], cp[4], cp[5], cp[6]};
  const float dcoef = 1.0f - DTc * damping;

  float s[6];
#pragma unroll
  for (int i = 0; i < 6; i++) s[i] = init_states[seq * 6 + i];
  float P[6][6];
#pragma unroll
  for (int i = 0; i < 6; i++)
#pragma unroll
    for (int j = 0; j < 6; j++) P[i][j] = (i == j) ? 0.01f : 0.0f;

  // software-pipelined coalesced z loads
  float z0n = zT[(size_t)0 * B + seq];
  float z1n = zT[(size_t)1 * B + seq];
  float z2n = zT[(size_t)2 * B + seq];

#pragma unroll 1
  for (int t = 0; t < T; t++) {
    const float z0 = z0n, z1 = z1n, z2 = z2n;
    if (t < T - 1) {
      z0n = zT[(size_t)((t + 1) * 3 + 0) * B + seq];
      z1n = zT[(size_t)((t + 1) * 3 + 1) * B + seq];
      z2n = zT[(size_t)((t + 1) * 3 + 2) * B + seq];
    }
    const float tx = fast_tanh(100.0f * s[2]);
    const float ty = fast_tanh(100.0f * s[3]);
    float sp[6];
    sp[0] = s[0] + DTc * s[2];
    sp[1] = s[1] + DTc * s[3];
    sp[2] = s[2] - DTc * (damping * s[2] + friction * tx);
    sp[3] = s[3] - DTc * (damping * s[3] + friction * ty);
    sp[4] = s[4] + DTc * s[5];
    sp[5] = s[5] * dcoef;
    const float gx = 1.0f - DTc * (damping + friction * 100.0f * (1.0f - tx * tx));
    const float gy = 1.0f - DTc * (damping + friction * 100.0f * (1.0f - ty * ty));

    float A[6][6];
#pragma unroll
    for (int j = 0; j < 6; j++) {
      A[0][j] = P[0][j] + DTc * P[2][j];
      A[1][j] = P[1][j] + DTc * P[3][j];
      A[2][j] = gx * P[2][j];
      A[3][j] = gy * P[3][j];
      A[4][j] = P[4][j] + DTc * P[5][j];
      A[5][j] = dcoef * P[5][j];
    }
    float Pp[6][6];
#pragma unroll
    for (int i = 0; i < 6; i++) {
      Pp[i][0] = A[i][0] + DTc * A[i][2];
      Pp[i][1] = A[i][1] + DTc * A[i][3];
      Pp[i][2] = gx * A[i][2];
      Pp[i][3] = gy * A[i][3];
      Pp[i][4] = A[i][4] + DTc * A[i][5];
      Pp[i][5] = dcoef * A[i][5];
    }
#pragma unroll
    for (int i = 0; i < 6; i++) Pp[i][i] += q[i];

    const float Sa = Pp[0][0] + r0, Sb = Pp[0][1], Sc = Pp[0][4];
    const float Sd = Pp[1][1] + r1, Se = Pp[1][4], Sf = Pp[4][4] + r2;
    const float C00 = Sd * Sf - Se * Se;
    const float C01 = Sc * Se - Sb * Sf;
    const float C02 = Sb * Se - Sd * Sc;
    const float det = Sa * C00 + Sb * C01 + Sc * C02;
    const float idet = frcp(det);
    const float Si00 = C00 * idet, Si01 = C01 * idet, Si02 = C02 * idet;
    const float Si11 = (Sa * Sf - Sc * Sc) * idet;
    const float Si12 = (Sb * Sc - Sa * Se) * idet;
    const float Si22 = (Sa * Sd - Sb * Sb) * idet;

    float K[6][3];
#pragma unroll
    for (int i = 0; i < 6; i++) {
      const float u0 = Pp[i][0], u1 = Pp[i][1], u2 = Pp[i][4];
      K[i][0] = u0 * Si00 + u1 * Si01 + u2 * Si02;
      K[i][1] = u0 * Si01 + u1 * Si11 + u2 * Si12;
      K[i][2] = u0 * Si02 + u1 * Si12 + u2 * Si22;
    }

    const float i0 = z0 - sp[0];
    const float i1 = z1 - sp[1];
    float ia = z2 - sp[4];
    ia = ia - TWO_PIc * rintf(ia * (1.0f / TWO_PIc));

#pragma unroll
    for (int i = 0; i < 6; i++)
      s[i] = sp[i] + K[i][0] * i0 + K[i][1] * i1 + K[i][2] * ia;

#pragma unroll
    for (int i = 0; i < 6; i++)
#pragma unroll
      for (int j = i; j < 6; j++) {
        const float v = Pp[i][j] -
            (K[i][0] * Pp[0][j] + K[i][1] * Pp[1][j] + K[i][2] * Pp[4][j]);
        P[i][j] = v;
        P[j][i] = v;
      }

    float* __restrict__ h = hist + (size_t)t * 27 * B + seq;
#pragma unroll
    for (int k = 0; k < 6; k++) h[(size_t)k * B] = s[k];
#pragma unroll
    for (int i = 0; i < 6; i++)
#pragma unroll
      for (int j = i; j < 6; j++) h[(size_t)(6 + uidx(i, j)) * B] = P[i][j];
  }
}

// ---------------------------------------------------------------------------
// Phase A: per (seq, chunk): compose the chunk's backward affine ops.
// chunkops layout: [(c*63 + k)*B + seq]; k: 0..35 G row-major, 36..41 b, 42..62 C upper
// ---------------------------------------------------------------------------
__global__ __launch_bounds__(256, 1) void chunkops_kernel(
    const float* __restrict__ params, const float* __restrict__ covp,
    const float* __restrict__ hist, float* __restrict__ chunkops) {
  const int tid = blockIdx.x * 256 + threadIdx.x;
  const int seq = tid & (B - 1);
  const int c = tid >> 12;  // 0..15, uniform per block
  const int lo = c * 8;
  const int hi = (c == NC - 1) ? (T - 2) : (lo + 7);

  const float friction = (fast_tanh(params[0]) + 1.0f) * 0.01f;
  const float damping  = (fast_tanh(params[1]) + 1.0f) * 0.01f;
  const float cp3 = sigmoidf(covp[3]), cp4 = sigmoidf(covp[4]);
  const float cp5 = sigmoidf(covp[5]), cp6 = sigmoidf(covp[6]);
  const float q[6] = {cp3, cp3, cp4, cp4, cp5, cp6};
  const float dcoef = 1.0f - DTc * damping;

  float Ga[6][6], ba[6], Ca[6][6];

#pragma unroll 1
  for (int n = hi; n >= lo; --n) {
    const float* __restrict__ h = hist + (size_t)n * 27 * B + seq;
    float s_f[6];
#pragma unroll
    for (int k = 0; k < 6; k++) s_f[k] = h[(size_t)k * B];
    float Pf[6][6];
#pragma unroll
    for (int i = 0; i < 6; i++)
#pragma unroll
      for (int j = i; j < 6; j++) {
        const float v = h[(size_t)(6 + uidx(i, j)) * B];
        Pf[i][j] = v;
        Pf[j][i] = v;
      }

    float sp[6], X[6][6], Pp[6][6], dg[6], gx, gy;
    rts_core(s_f, Pf, friction, damping, dcoef, q, sp, X, Pp, dg, gx, gy);
    // G_n[i][j] = X[j][i]

    // b_n = s_f - G_n sp
    float bn[6];
#pragma unroll
    for (int i = 0; i < 6; i++) {
      float v = s_f[i];
#pragma unroll
      for (int j = 0; j < 6; j++) v -= X[j][i] * sp[j];
      bn[i] = v;
    }
    // C_n = Pf - Worig^T X  (Worig col i regenerated from Pf)
    float Cn[6][6];
#pragma unroll
    for (int i = 0; i < 6; i++) {
      float w[6];
      w[0] = Pf[0][i] + DTc * Pf[2][i];
      w[1] = Pf[1][i] + DTc * Pf[3][i];
      w[2] = gx * Pf[2][i];
      w[3] = gy * Pf[3][i];
      w[4] = Pf[4][i] + DTc * Pf[5][i];
      w[5] = dcoef * Pf[5][i];
#pragma unroll
      for (int j = i; j < 6; j++) {
        float v = Pf[i][j];
#pragma unroll
        for (int k = 0; k < 6; k++) v -= w[k] * X[k][j];
        Cn[i][j] = v;
        Cn[j][i] = v;
      }
    }

    if (n == hi) {
#pragma unroll
      for (int i = 0; i < 6; i++) {
        ba[i] = bn[i];
#pragma unroll
        for (int j = 0; j < 6; j++) { Ga[i][j] = X[j][i]; Ca[i][j] = Cn[i][j]; }
      }
    } else {
      // acc' = op_n o acc: G' = Gn Ga ; b' = Gn ba + bn ; C' = Cn + Gn Ca Gn^T
      float tG[6][6], tb[6], Y[6][6];
#pragma unroll
      for (int i = 0; i < 6; i++) {
        float bacc = bn[i];
#pragma unroll
        for (int k = 0; k < 6; k++) bacc += X[k][i] * ba[k];
        tb[i] = bacc;
#pragma unroll
        for (int j = 0; j < 6; j++) {
          float g = 0.0f, y = 0.0f;
#pragma unroll
          for (int k = 0; k < 6; k++) {
            g += X[k][i] * Ga[k][j];
            y += X[k][i] * Ca[k][j];
          }
          tG[i][j] = g;
          Y[i][j] = y;
        }
      }
      float tC[6][6];
#pragma unroll
      for (int i = 0; i < 6; i++)
#pragma unroll
        for (int j = i; j < 6; j++) {
          float v = Cn[i][j];
#pragma unroll
          for (int k = 0; k < 6; k++) v += Y[i][k] * X[k][j];  // Gn[j][k]=X[k][j]
          tC[i][j] = v;
          tC[j][i] = v;
        }
#pragma unroll
      for (int i = 0; i < 6; i++) {
        ba[i] = tb[i];
#pragma unroll
        for (int j = 0; j < 6; j++) { Ga[i][j] = tG[i][j]; Ca[i][j] = tC[i][j]; }
      }
    }
  }

  float* __restrict__ o = chunkops + (size_t)c * 63 * B + seq;
#pragma unroll
  for (int i = 0; i < 6; i++)
#pragma unroll
    for (int j = 0; j < 6; j++) o[(size_t)(i * 6 + j) * B] = Ga[i][j];
#pragma unroll
  for (int i = 0; i < 6; i++) o[(size_t)(36 + i) * B] = ba[i];
#pragma unroll
  for (int i = 0; i < 6; i++)
#pragma unroll
    for (int j = i; j < 6; j++) o[(size_t)(42 + uidx(i, j)) * B] = Ca[i][j];
}

// ---------------------------------------------------------------------------
// Phase B: serial scan over NC chunk ops; store chunk-entry states; loss@127.
// entries layout: [(c*27 + k)*B + seq]
// ---------------------------------------------------------------------------
__global__ __launch_bounds__(64, 1) void chunkscan_kernel(
    const float* __restrict__ covp, const float* __restrict__ zT,
    const float* __restrict__ hist, const float* __restrict__ chunkops,
    float* __restrict__ entries, float* __restrict__ out) {
  const int seq = blockIdx.x * blockDim.x + threadIdx.x;

  const float r0 = sigmoidf(covp[0]);
  const float r1 = sigmoidf(covp[1]);
  const float r2 = sigmoidf(covp[2]);

  // state = filtered at T-1
  const float* __restrict__ h = hist + (size_t)(T - 1) * 27 * B + seq;
  float s[6];
#pragma unroll
  for (int k = 0; k < 6; k++) s[k] = h[(size_t)k * B];
  float P[6][6];
#pragma unroll
  for (int i = 0; i < 6; i++)
#pragma unroll
    for (int j = i; j < 6; j++) {
      const float v = h[(size_t)(6 + uidx(i, j)) * B];
      P[i][j] = v;
      P[j][i] = v;
    }

  float loss = loss_term(P, s,
                         zT[(size_t)((T - 1) * 3 + 0) * B + seq],
                         zT[(size_t)((T - 1) * 3 + 1) * B + seq],
                         zT[(size_t)((T - 1) * 3 + 2) * B + seq], r0, r1, r2);

  float G[36], bv[6], Cu[21];
  {
    const float* __restrict__ o = chunkops + (size_t)(NC - 1) * 63 * B + seq;
#pragma unroll
    for (int k = 0; k < 36; k++) G[k] = o[(size_t)k * B];
#pragma unroll
    for (int k = 0; k < 6; k++) bv[k] = o[(size_t)(36 + k) * B];
#pragma unroll
    for (int k = 0; k < 21; k++) Cu[k] = o[(size_t)(42 + k) * B];
  }

#pragma unroll 1
  for (int c = NC - 1; c >= 0; --c) {
    // prefetch next chunk op (independent of the apply below)
    float G2[36], b2[6], C2[21];
    if (c > 0) {
      const float* __restrict__ o = chunkops + (size_t)(c - 1) * 63 * B + seq;
#pragma unroll
      for (int k = 0; k < 36; k++) G2[k] = o[(size_t)k * B];
#pragma unroll
      for (int k = 0; k < 6; k++) b2[k] = o[(size_t)(36 + k) * B];
#pragma unroll
      for (int k = 0; k < 21; k++) C2[k] = o[(size_t)(42 + k) * B];
    }
    // store entry state for chunk c
    float* __restrict__ e = entries + (size_t)c * 27 * B + seq;
#pragma unroll
    for (int k = 0; k < 6; k++) e[(size_t)k * B] = s[k];
#pragma unroll
    for (int i = 0; i < 6; i++)
#pragma unroll
      for (int j = i; j < 6; j++) e[(size_t)(6 + uidx(i, j)) * B] = P[i][j];

    // apply: s = G s + b ; P = C + G P G^T
    float ns[6];
#pragma unroll
    for (int i = 0; i < 6; i++) {
      float v = bv[i];
#pragma unroll
      for (int j = 0; j < 6; j++) v += G[i * 6 + j] * s[j];
      ns[i] = v;
    }
    float Y[6][6];
#pragma unroll
    for (int i = 0; i < 6; i++)
#pragma unroll
      for (int k = 0; k < 6; k++) {
        float v = 0.0f;
#pragma unroll
        for (int j = 0; j < 6; j++) v += G[i * 6 + j] * P[j][k];
        Y[i][k] = v;
      }
#pragma unroll
    for (int i = 0; i < 6; i++)
#pragma unroll
      for (int j = i; j < 6; j++) {
        float v = Cu[uidx(i, j)];
#pragma unroll
        for (int k = 0; k < 6; k++) v += Y[i][k] * G[j * 6 + k];
        P[i][j] = v;
        P[j][i] = v;
      }
#pragma unroll
    for (int i = 0; i < 6; i++) s[i] = ns[i];

    if (c > 0) {
#pragma unroll
      for (int k = 0; k < 36; k++) G[k] = G2[k];
#pragma unroll
      for (int k = 0; k < 6; k++) bv[k] = b2[k];
#pragma unroll
      for (int k = 0; k < 21; k++) Cu[k] = C2[k];
    }
  }

#pragma unroll
  for (int off = 32; off > 0; off >>= 1) loss += __shfl_down(loss, off);
  if (threadIdx.x == 0) atomicAdd(out, loss);
}

// ---------------------------------------------------------------------------
// Phase C: per (seq, chunk): redo the chunk's RTS steps from the entry state,
// accumulate loss for n >= 2.
// ---------------------------------------------------------------------------
__global__ __launch_bounds__(256, 1) void applyloss_kernel(
    const float* __restrict__ params, const float* __restrict__ covp,
    const float* __restrict__ hist, const float* __restrict__ entries,
    const float* __restrict__ zT, float* __restrict__ out) {
  const int tid = blockIdx.x * 256 + threadIdx.x;
  const int seq = tid & (B - 1);
  const int c = tid >> 12;
  const int lo = (c == 0) ? 2 : c * 8;  // loss only for n >= 2
  const int hi = (c == NC - 1) ? (T - 2) : (c * 8 + 7);

  const float friction = (fast_tanh(params[0]) + 1.0f) * 0.01f;
  const float damping  = (fast_tanh(params[1]) + 1.0f) * 0.01f;
  float cp[7];
#pragma unroll
  for (int i = 0; i < 7; i++) cp[i] = sigmoidf(covp[i]);
  const float r0 = cp[0], r1 = cp[1], r2 = cp[2];
  const float q[6] = {cp[3], cp[3], cp[4], cp[4], cp[5], cp[6]};
  const float dcoef = 1.0f - DTc * damping;

  // load entry state (smoothed at hi+1)
  const float* __restrict__ e = entries + (size_t)c * 27 * B + seq;
  float s[6];
#pragma unroll
  for (int k = 0; k < 6; k++) s[k] = e[(size_t)k * B];
  float P[6][6];
#pragma unroll
  for (int i = 0; i < 6; i++)
#pragma unroll
    for (int j = i; j < 6; j++) {
      const float v = e[(size_t)(6 + uidx(i, j)) * B];
      P[i][j] = v;
      P[j][i] = v;
    }

  float loss = 0.0f;

#pragma unroll 1
  for (int n = hi; n >= lo; --n) {
    const float* __restrict__ h = hist + (size_t)n * 27 * B + seq;
    float s_f[6];
#pragma unroll
    for (int k = 0; k < 6; k++) s_f[k] = h[(size_t)k * B];
    float Pf[6][6];
#pragma unroll
    for (int i = 0; i < 6; i++)
#pragma unroll
      for (int j = i; j < 6; j++) {
        const float v = h[(size_t)(6 + uidx(i, j)) * B];
        Pf[i][j] = v;
        Pf[j][i] = v;
      }
    const float zz0 = zT[(size_t)(n * 3 + 0) * B + seq];
    const float zz1 = zT[(size_t)(n * 3 + 1) * B + seq];
    const float zz2 = zT[(size_t)(n * 3 + 2) * B + seq];

    float sp[6], X[6][6], Pp[6][6], dg[6], gx, gy;
    rts_core(s_f, Pf, friction, damping, dcoef, q, sp, X, Pp, dg, gx, gy);

    // ds = s - sp ; M = P - Pp_orig
    float ds[6];
#pragma unroll
    for (int j = 0; j < 6; j++) ds[j] = s[j] - sp[j];
    float M[6][6];
#pragma unroll
    for (int i = 0; i < 6; i++)
#pragma unroll
      for (int j = 0; j < 6; j++) {
        const float ppo = (i == j) ? dg[i] : ((i < j) ? Pp[i][j] : Pp[j][i]);
        M[i][j] = P[i][j] - ppo;
      }

    // s = s_f + G ds   (G = X^T)
    float ns[6];
#pragma unroll
    for (int i = 0; i < 6; i++) {
      float v = s_f[i];
#pragma unroll
      for (int j = 0; j < 6; j++) v += X[j][i] * ds[j];
      ns[i] = v;
    }
    // GM = G M
    float GM[6][6];
#pragma unroll
    for (int i = 0; i < 6; i++)
#pragma unroll
      for (int k = 0; k < 6; k++) {
        float v = 0.0f;
#pragma unroll
        for (int j = 0; j < 6; j++) v += X[j][i] * M[j][k];
        GM[i][k] = v;
      }
    // P = Pf + GM G^T
#pragma unroll
    for (int i = 0; i < 6; i++)
#pragma unroll
      for (int j = i; j < 6; j++) {
        float v = Pf[i][j];
#pragma unroll
        for (int k = 0; k < 6; k++) v += GM[i][k] * X[k][j];
        P[i][j] = v;
        P[j][i] = v;
      }
#pragma unroll
    for (int i = 0; i < 6; i++) s[i] = ns[i];

    if (n >= 2)
      loss += loss_term(P, s, zz0, zz1, zz2, r0, r1, r2);
  }

#pragma unroll
  for (int off = 32; off > 0; off >>= 1) loss += __shfl_down(loss, off);
  if ((threadIdx.x & 63) == 0) atomicAdd(out, loss);
}

}  // namespace

extern "C" void kernel_launch(void* const* d_in, const int* in_sizes, int n_in,
                              void* d_out, int out_size, void* d_ws, size_t ws_size,
                              hipStream_t stream) {
  const float* params      = (const float*)d_in[0];
  const float* covp        = (const float*)d_in[1];
  const float* init_states = (const float*)d_in[2];
  const float* z           = (const float*)d_in[3];
  float* out = (float*)d_out;

  const size_t histF    = (size_t)T * 27 * B;        // 56.6 MB
  const size_t zTF      = (size_t)T * 3 * B;         //  6.3 MB
  const size_t chunkF   = (size_t)NC * 63 * B;       // 16.5 MB
  const size_t entriesF = (size_t)NC * 27 * B;       //  7.1 MB
  const size_t needBytes = (histF + zTF + chunkF + entriesF) * sizeof(float);

  hipMemsetAsync(d_out, 0, sizeof(float), stream);

  if (ws_size >= needBytes) {
    float* hist     = (float*)d_ws;
    float* zT       = hist + histF;
    float* chunkops = zT + zTF;
    float* entries  = chunkops + chunkF;

    ztrans_kernel<<<(B * T) / 256, 256, 0, stream>>>(z, zT);
    fwd_kernel<<<B / 64, 64, 0, stream>>>(params, covp, init_states, zT, hist);
    chunkops_kernel<<<(B * NC) / 256, 256, 0, stream>>>(params, covp, hist, chunkops);
    chunkscan_kernel<<<B / 64, 64, 0, stream>>>(covp, zT, hist, chunkops, entries, out);
    applyloss_kernel<<<(B * NC) / 256, 256, 0, stream>>>(params, covp, hist, entries, zT, out);
  }
  // (workspace has been >= 187 MB in prior rounds; need is 86.5 MB)
}

// Round 4
// 230.549 us; speedup vs baseline: 2.3035x; 1.3195x over previous
//
#include <hip/hip_runtime.h>
#include <cmath>

// Kalman_Smooth_Gradient: B=4096 seqs, T=128 steps, 6-state EKF + RTS + loss.
// Round 4: forward EKF parallelized 4 lanes/seq via DPP quad_perm (256 waves).
//   fwd4:      lane m of each 4-lane quad owns P rows {m, m+4}; all cross-lane
//              exchanges are quad_perm DPP (VALU, no LDS). Stores hist in
//              wave-chunked layout: hist[((t*NW+wg)*14 + c)*64 + lane].
//   chunkops:  B*NC threads compose 8 per-step backward affine ops -> chunk op
//   chunkscan: 64 waves, NC=16 serial steps over chunk ops; entry states
//   applyloss: B*NC threads redo 8 RTS steps from chunk entry + loss
// hist planes per (t,seq): c=0: s[0..3], c=1: s[4..5], c=2+j: P[0..3][j],
// c=8+j: P[4..5][j]  (m=2,3 slots of planes 1, 8+j are zero padding).

namespace {

constexpr int B = 4096;
constexpr int T = 128;
constexpr int NC = 16;                        // backward chunks
constexpr int NW = B * 4 / 64;                // 256 forward waves
constexpr size_t TS = (size_t)NW * 14 * 64;   // hist floats per t = 229376
constexpr float DTc     = 1.0f / 120.0f;
constexpr float TWO_PIc = 6.28318530717958647692f;
constexpr float PI_1_5  = 4.71238898038468985769f;  // 1.5*pi

__device__ __forceinline__ float frcp(float x) { return __builtin_amdgcn_rcpf(x); }

__device__ __forceinline__ float fast_tanh(float x) {
  float e = __expf(2.0f * x);
  return 1.0f - 2.0f * frcp(e + 1.0f);
}
__device__ __forceinline__ float sigmoidf(float x) {
  return frcp(1.0f + __expf(-x));
}

__device__ __forceinline__ int uidx(int i, int j) {  // i<=j, upper-tri row-major
  return i * 6 - i * (i - 1) / 2 + (j - i);
}

// DPP quad_perm: dest lane i (within each 4-lane quad) reads src lane perm[i].
template <int CTRL>
__device__ __forceinline__ float qp(float x) {
  return __int_as_float(__builtin_amdgcn_update_dpp(
      __float_as_int(x), __float_as_int(x), CTRL, 0xF, 0xF, false));
}
// ctrl = p0 | p1<<2 | p2<<4 | p3<<6
constexpr int QP_B0 = 0;      // bcast lane 0
constexpr int QP_B1 = 85;     // bcast lane 1
constexpr int QP_B2 = 170;    // bcast lane 2
constexpr int QP_B3 = 255;    // bcast lane 3
constexpr int QP_2323 = 238;  // perm(2,3,2,3)

// loss term: det(Sv) + e^T Sv e with Sv = H P H^T + R
__device__ __forceinline__ float loss_term(const float Pm[6][6], const float sv[6],
                                           float z0, float z1, float z2,
                                           float r0, float r1, float r2) {
  float a = Pm[0][0] + r0, b = Pm[0][1], c = Pm[0][4];
  float d = Pm[1][1] + r1, e = Pm[1][4], f = Pm[4][4] + r2;
  float det = a * (d * f - e * e) + b * (c * e - b * f) + c * (b * e - d * c);
  float e0 = z0 - sv[0], e1 = z1 - sv[1], aa = z2 - sv[4];
  if (aa >  PI_1_5) aa -= TWO_PIc;
  if (aa < -PI_1_5) aa += TWO_PIc;
  float quad = a * e0 * e0 + d * e1 * e1 + f * aa * aa +
               2.0f * (b * e0 * e1 + c * e0 * aa + e * e1 * aa);
  return det + quad;
}

// Read (s_f, Pf) for (t, seq) from the wave-chunked hist layout.
__device__ __forceinline__ void load_hist(const float* __restrict__ hist, int t,
                                          int seq, float s_f[6], float Pf[6][6]) {
  const float* hc = hist + (size_t)t * TS + (size_t)(seq >> 4) * (14 * 64) +
                    (seq & 15) * 4;
  const float4 s03 = *(const float4*)(hc);
  const float2 s45 = *(const float2*)(hc + 64);
  s_f[0] = s03.x; s_f[1] = s03.y; s_f[2] = s03.z; s_f[3] = s03.w;
  s_f[4] = s45.x; s_f[5] = s45.y;
#pragma unroll
  for (int j = 0; j < 6; j++) {
    const float4 a = *(const float4*)(hc + (size_t)(2 + j) * 64);
    const float2 b = *(const float2*)(hc + (size_t)(8 + j) * 64);
    Pf[0][j] = a.x; Pf[1][j] = a.y; Pf[2][j] = a.z; Pf[3][j] = a.w;
    Pf[4][j] = b.x; Pf[5][j] = b.y;
  }
}

// Core of one backward RTS step from filtered (s_f, Pf) at n.
__device__ __forceinline__ void rts_core(
    const float s_f[6], const float Pf[6][6],
    float friction, float damping, float dcoef, const float* __restrict__ q,
    float sp[6], float W[6][6], float Pp[6][6], float diag[6],
    float& gxo, float& gyo) {
  const float tx = fast_tanh(100.0f * s_f[2]);
  const float ty = fast_tanh(100.0f * s_f[3]);
  sp[0] = s_f[0] + DTc * s_f[2];
  sp[1] = s_f[1] + DTc * s_f[3];
  sp[2] = s_f[2] - DTc * (damping * s_f[2] + friction * tx);
  sp[3] = s_f[3] - DTc * (damping * s_f[3] + friction * ty);
  sp[4] = s_f[4] + DTc * s_f[5];
  sp[5] = s_f[5] * dcoef;
  const float gx = 1.0f - DTc * (damping + friction * 100.0f * (1.0f - tx * tx));
  const float gy = 1.0f - DTc * (damping + friction * 100.0f * (1.0f - ty * ty));
  gxo = gx; gyo = gy;

#pragma unroll
  for (int j = 0; j < 6; j++) {
    W[0][j] = Pf[0][j] + DTc * Pf[2][j];
    W[1][j] = Pf[1][j] + DTc * Pf[3][j];
    W[2][j] = gx * Pf[2][j];
    W[3][j] = gy * Pf[3][j];
    W[4][j] = Pf[4][j] + DTc * Pf[5][j];
    W[5][j] = dcoef * Pf[5][j];
  }
#pragma unroll
  for (int i = 0; i < 6; i++) {
    Pp[i][0] = W[i][0] + DTc * W[i][2];
    Pp[i][1] = W[i][1] + DTc * W[i][3];
    Pp[i][2] = gx * W[i][2];
    Pp[i][3] = gy * W[i][3];
    Pp[i][4] = W[i][4] + DTc * W[i][5];
    Pp[i][5] = dcoef * W[i][5];
  }
#pragma unroll
  for (int i = 0; i < 6; i++) { Pp[i][i] += q[i]; diag[i] = Pp[i][i]; }

  float rd[6];
#pragma unroll
  for (int k = 0; k < 6; k++) {
    float dv = Pp[k][k];
#pragma unroll
    for (int m = 0; m < k; m++) dv -= Pp[k][m] * Pp[k][m];
    dv = sqrtf(fmaxf(dv, 1e-30f));
    Pp[k][k] = dv;
    rd[k] = frcp(dv);
#pragma unroll
    for (int i = k + 1; i < 6; i++) {
      float v = Pp[i][k];
#pragma unroll
      for (int m = 0; m < k; m++) v -= Pp[i][m] * Pp[k][m];
      Pp[i][k] = v * rd[k];
    }
  }
#pragma unroll
  for (int c = 0; c < 6; c++) {
    float y[6];
#pragma unroll
    for (int i = 0; i < 6; i++) {
      float v = W[i][c];
#pragma unroll
      for (int m = 0; m < i; m++) v -= Pp[i][m] * y[m];
      y[i] = v * rd[i];
    }
#pragma unroll
    for (int i = 5; i >= 0; i--) {
      float v = y[i];
#pragma unroll
      for (int m = i + 1; m < 6; m++) v -= Pp[m][i] * W[m][c];
      W[i][c] = v * rd[i];
    }
  }
}

// ---------------------------------------------------------------------------
// Forward EKF, 4 lanes/seq. Lane m owns rows m (slot a) and m+4 (slot b;
// valid for m=0,1; zero padding for m=2,3).
// ---------------------------------------------------------------------------
__global__ __launch_bounds__(64, 1) void fwd4_kernel(
    const float* __restrict__ params, const float* __restrict__ covp,
    const float* __restrict__ init_states, const float* __restrict__ z,
    float* __restrict__ hist) {
  const int l = threadIdx.x;     // 0..63
  const int m = l & 3;           // row-lane within quad
  const int si = l >> 2;         // seq within wave (0..15)
  const int wg = blockIdx.x;     // wave id (0..NW-1)
  const int seq = wg * 16 + si;

  const float friction = (fast_tanh(params[0]) + 1.0f) * 0.01f;
  const float damping  = (fast_tanh(params[1]) + 1.0f) * 0.01f;
  float cp[7];
#pragma unroll
  for (int i = 0; i < 7; i++) cp[i] = sigmoidf(covp[i]);
  const float r0 = cp[0], r1 = cp[1], r2 = cp[2];
  const float q[6] = {cp[3], cp[3], cp[4], cp[4], cp[5], cp[6]};
  const float dcoef = 1.0f - DTc * damping;
  const float DTf = DTc * friction;
  const float f100 = friction * 100.0f;

  // per-lane constants
  const float da = (m < 2) ? DTc : 0.0f;                              // A slot a
  const float cb = (m == 0) ? 1.0f : (m == 1) ? dcoef : 0.0f;         // A slot b
  const float db = (m == 0) ? DTc : 0.0f;
  const float Aspa = (m < 2) ? 1.0f : dcoef;                          // sp slot a
  const float Bspa = (m < 2) ? DTc : 0.0f;
  const float Aspb = cb, Bspb = db;                                   // sp slot b
  float qma[6], qmb[6];
#pragma unroll
  for (int j = 0; j < 6; j++) {
    qma[j] = (j == m) ? q[j] : 0.0f;
    qmb[j] = (m == 0 && j == 4) ? q[4] : (m == 1 && j == 5) ? q[5] : 0.0f;
  }

  // state
  float sa = init_states[seq * 6 + m];
  float sb = (m < 2) ? init_states[seq * 6 + 4 + m] : 0.0f;
  float Pa[6], Pb[6];
#pragma unroll
  for (int j = 0; j < 6; j++) {
    Pa[j] = (j == m) ? 0.01f : 0.0f;
    Pb[j] = (m < 2 && j == m + 4) ? 0.01f : 0.0f;
  }

  const float* __restrict__ zp = z + (size_t)seq * (T * 3);
  float* __restrict__ hbase = hist + (size_t)wg * (14 * 64) + l;

  float z0 = zp[0], z1 = zp[1], z2 = zp[2];

#pragma unroll 1
  for (int t = 0; t < T; t++) {
    float z0n = 0.f, z1n = 0.f, z2n = 0.f;
    if (t < T - 1) {
      z0n = zp[(t + 1) * 3 + 0];
      z1n = zp[(t + 1) * 3 + 1];
      z2n = zp[(t + 1) * 3 + 2];
    }

    const float s2 = qp<QP_B2>(sa);
    const float s3 = qp<QP_B3>(sa);
    const float tx = fast_tanh(100.0f * s2);
    const float ty = fast_tanh(100.0f * s3);
    const float gx = 1.0f - DTc * (damping + f100 * (1.0f - tx * tx));
    const float gy = 1.0f - DTc * (damping + f100 * (1.0f - ty * ty));
    const float ca = (m == 2) ? gx : (m == 3) ? gy : 1.0f;

    // sp (per-lane rows m, m+4)
    const float sshf = qp<QP_2323>(sa);   // lane0<-s2, lane1<-s3
    const float s5s  = qp<QP_B1>(sb);     // lane0<-s5
    const float tsel = (m == 2) ? tx : (m == 3) ? ty : 0.0f;
    const float spa = fmaf(Bspa, sshf, fmaf(Aspa, sa, -DTf * tsel));
    const float spb = fmaf(Bspb, s5s, Aspb * sb);

    // A = F P
    float Aa[6], Ab[6];
#pragma unroll
    for (int j = 0; j < 6; j++) {
      const float t1 = qp<QP_2323>(Pa[j]);   // lane0<-P[2][j], lane1<-P[3][j]
      const float t2 = qp<QP_B1>(Pb[j]);     // lane0<-P[5][j]
      Aa[j] = fmaf(da, t1, ca * Pa[j]);
      Ab[j] = fmaf(db, t2, cb * Pb[j]);
    }
    // Pp = A F^T + Q (per-lane rows)
    float Ppa[6], Ppb[6];
    Ppa[0] = fmaf(DTc, Aa[2], Aa[0]) + qma[0];
    Ppa[1] = fmaf(DTc, Aa[3], Aa[1]) + qma[1];
    Ppa[2] = fmaf(gx, Aa[2], qma[2]);
    Ppa[3] = fmaf(gy, Aa[3], qma[3]);
    Ppa[4] = fmaf(DTc, Aa[5], Aa[4]) + qma[4];
    Ppa[5] = fmaf(dcoef, Aa[5], qma[5]);
    Ppb[0] = fmaf(DTc, Ab[2], Ab[0]) + qmb[0];
    Ppb[1] = fmaf(DTc, Ab[3], Ab[1]) + qmb[1];
    Ppb[2] = fmaf(gx, Ab[2], qmb[2]);
    Ppb[3] = fmaf(gy, Ab[3], qmb[3]);
    Ppb[4] = fmaf(DTc, Ab[5], Ab[4]) + qmb[4];
    Ppb[5] = fmaf(dcoef, Ab[5], qmb[5]);

    // S = H Pp H^T + R (broadcast to all lanes), adjugate inverse
    const float Sa = qp<QP_B0>(Ppa[0]) + r0;
    const float Sbv = qp<QP_B0>(Ppa[1]);
    const float Scv = qp<QP_B0>(Ppa[4]);
    const float Sd = qp<QP_B1>(Ppa[1]) + r1;
    const float Se = qp<QP_B1>(Ppa[4]);
    const float Sf = qp<QP_B0>(Ppb[4]) + r2;
    const float C00 = Sd * Sf - Se * Se;
    const float C01 = Scv * Se - Sbv * Sf;
    const float C02 = Sbv * Se - Sd * Scv;
    const float det = Sa * C00 + Sbv * C01 + Scv * C02;
    const float idet = frcp(det);
    const float Si00 = C00 * idet, Si01 = C01 * idet, Si02 = C02 * idet;
    const float Si11 = (Sa * Sf - Scv * Scv) * idet;
    const float Si12 = (Sbv * Scv - Sa * Se) * idet;
    const float Si22 = (Sa * Sd - Sbv * Sbv) * idet;

    // K rows m and m+4
    const float Ka0 = Ppa[0] * Si00 + Ppa[1] * Si01 + Ppa[4] * Si02;
    const float Ka1 = Ppa[0] * Si01 + Ppa[1] * Si11 + Ppa[4] * Si12;
    const float Ka2 = Ppa[0] * Si02 + Ppa[1] * Si12 + Ppa[4] * Si22;
    const float Kb0 = Ppb[0] * Si00 + Ppb[1] * Si01 + Ppb[4] * Si02;
    const float Kb1 = Ppb[0] * Si01 + Ppb[1] * Si11 + Ppb[4] * Si12;
    const float Kb2 = Ppb[0] * Si02 + Ppb[1] * Si12 + Ppb[4] * Si22;

    // innovation (all lanes)
    const float sp0 = qp<QP_B0>(spa);
    const float sp1 = qp<QP_B1>(spa);
    const float sp4 = qp<QP_B0>(spb);
    const float i0 = z0 - sp0;
    const float i1 = z1 - sp1;
    float ia = z2 - sp4;
    ia = ia - TWO_PIc * rintf(ia * (1.0f / TWO_PIc));

    sa = spa + Ka0 * i0 + Ka1 * i1 + Ka2 * ia;
    sb = spb + Kb0 * i0 + Kb1 * i1 + Kb2 * ia;

    // P = (I - K H) Pp
#pragma unroll
    for (int j = 0; j < 6; j++) {
      const float p0 = qp<QP_B0>(Ppa[j]);
      const float p1 = qp<QP_B1>(Ppa[j]);
      const float p4 = qp<QP_B0>(Ppb[j]);
      Pa[j] = Ppa[j] - (Ka0 * p0 + Ka1 * p1 + Ka2 * p4);
      Pb[j] = Ppb[j] - (Kb0 * p0 + Kb1 * p1 + Kb2 * p4);
    }

    // store (14 coalesced planes, immediate offsets)
    float* __restrict__ hc = hbase + (size_t)t * TS;
    hc[0 * 64] = sa;
    hc[1 * 64] = sb;
#pragma unroll
    for (int j = 0; j < 6; j++) {
      hc[(2 + j) * 64] = Pa[j];
      hc[(8 + j) * 64] = Pb[j];
    }

    z0 = z0n; z1 = z1n; z2 = z2n;
  }
}

// ---------------------------------------------------------------------------
// Phase A: per (seq, chunk): compose the chunk's backward affine ops.
// chunkops layout: [(c*63 + k)*B + seq]
// ---------------------------------------------------------------------------
__global__ __launch_bounds__(256, 1) void chunkops_kernel(
    const float* __restrict__ params, const float* __restrict__ covp,
    const float* __restrict__ hist, float* __restrict__ chunkops) {
  const int tid = blockIdx.x * 256 + threadIdx.x;
  const int seq = tid & (B - 1);
  const int c = tid >> 12;
  const int lo = c * 8;
  const int hi = (c == NC - 1) ? (T - 2) : (lo + 7);

  const float friction = (fast_tanh(params[0]) + 1.0f) * 0.01f;
  const float damping  = (fast_tanh(params[1]) + 1.0f) * 0.01f;
  const float cp3 = sigmoidf(covp[3]), cp4 = sigmoidf(covp[4]);
  const float cp5 = sigmoidf(covp[5]), cp6 = sigmoidf(covp[6]);
  const float q[6] = {cp3, cp3, cp4, cp4, cp5, cp6};
  const float dcoef = 1.0f - DTc * damping;

  float Ga[6][6], ba[6], Ca[6][6];

#pragma unroll 1
  for (int n = hi; n >= lo; --n) {
    float s_f[6], Pf[6][6];
    load_hist(hist, n, seq, s_f, Pf);

    float sp[6], X[6][6], Pp[6][6], dg[6], gx, gy;
    rts_core(s_f, Pf, friction, damping, dcoef, q, sp, X, Pp, dg, gx, gy);
    // G_n[i][j] = X[j][i]

    float bn[6];
#pragma unroll
    for (int i = 0; i < 6; i++) {
      float v = s_f[i];
#pragma unroll
      for (int j = 0; j < 6; j++) v -= X[j][i] * sp[j];
      bn[i] = v;
    }
    float Cn[6][6];
#pragma unroll
    for (int i = 0; i < 6; i++) {
      float w[6];
      w[0] = Pf[0][i] + DTc * Pf[2][i];
      w[1] = Pf[1][i] + DTc * Pf[3][i];
      w[2] = gx * Pf[2][i];
      w[3] = gy * Pf[3][i];
      w[4] = Pf[4][i] + DTc * Pf[5][i];
      w[5] = dcoef * Pf[5][i];
#pragma unroll
      for (int j = i; j < 6; j++) {
        float v = Pf[i][j];
#pragma unroll
        for (int k = 0; k < 6; k++) v -= w[k] * X[k][j];
        Cn[i][j] = v;
        Cn[j][i] = v;
      }
    }

    if (n == hi) {
#pragma unroll
      for (int i = 0; i < 6; i++) {
        ba[i] = bn[i];
#pragma unroll
        for (int j = 0; j < 6; j++) { Ga[i][j] = X[j][i]; Ca[i][j] = Cn[i][j]; }
      }
    } else {
      float tG[6][6], tb[6], Y[6][6];
#pragma unroll
      for (int i = 0; i < 6; i++) {
        float bacc = bn[i];
#pragma unroll
        for (int k = 0; k < 6; k++) bacc += X[k][i] * ba[k];
        tb[i] = bacc;
#pragma unroll
        for (int j = 0; j < 6; j++) {
          float g = 0.0f, y = 0.0f;
#pragma unroll
          for (int k = 0; k < 6; k++) {
            g += X[k][i] * Ga[k][j];
            y += X[k][i] * Ca[k][j];
          }
          tG[i][j] = g;
          Y[i][j] = y;
        }
      }
      float tC[6][6];
#pragma unroll
      for (int i = 0; i < 6; i++)
#pragma unroll
        for (int j = i; j < 6; j++) {
          float v = Cn[i][j];
#pragma unroll
          for (int k = 0; k < 6; k++) v += Y[i][k] * X[k][j];
          tC[i][j] = v;
          tC[j][i] = v;
        }
#pragma unroll
      for (int i = 0; i < 6; i++) {
        ba[i] = tb[i];
#pragma unroll
        for (int j = 0; j < 6; j++) { Ga[i][j] = tG[i][j]; Ca[i][j] = tC[i][j]; }
      }
    }
  }

  float* __restrict__ o = chunkops + (size_t)c * 63 * B + seq;
#pragma unroll
  for (int i = 0; i < 6; i++)
#pragma unroll
    for (int j = 0; j < 6; j++) o[(size_t)(i * 6 + j) * B] = Ga[i][j];
#pragma unroll
  for (int i = 0; i < 6; i++) o[(size_t)(36 + i) * B] = ba[i];
#pragma unroll
  for (int i = 0; i < 6; i++)
#pragma unroll
    for (int j = i; j < 6; j++) o[(size_t)(42 + uidx(i, j)) * B] = Ca[i][j];
}

// ---------------------------------------------------------------------------
// Phase B: serial scan over NC chunk ops; stores chunk-entry states; loss@T-1.
// ---------------------------------------------------------------------------
__global__ __launch_bounds__(64, 1) void chunkscan_kernel(
    const float* __restrict__ covp, const float* __restrict__ z,
    const float* __restrict__ hist, const float* __restrict__ chunkops,
    float* __restrict__ entries, float* __restrict__ out) {
  const int seq = blockIdx.x * blockDim.x + threadIdx.x;

  const float r0 = sigmoidf(covp[0]);
  const float r1 = sigmoidf(covp[1]);
  const float r2 = sigmoidf(covp[2]);
  const float* __restrict__ zs = z + (size_t)seq * T * 3;

  float s[6], P[6][6];
  load_hist(hist, T - 1, seq, s, P);

  float loss = loss_term(P, s, zs[(T - 1) * 3 + 0], zs[(T - 1) * 3 + 1],
                         zs[(T - 1) * 3 + 2], r0, r1, r2);

  float G[36], bv[6], Cu[21];
  {
    const float* __restrict__ o = chunkops + (size_t)(NC - 1) * 63 * B + seq;
#pragma unroll
    for (int k = 0; k < 36; k++) G[k] = o[(size_t)k * B];
#pragma unroll
    for (int k = 0; k < 6; k++) bv[k] = o[(size_t)(36 + k) * B];
#pragma unroll
    for (int k = 0; k < 21; k++) Cu[k] = o[(size_t)(42 + k) * B];
  }

#pragma unroll 1
  for (int c = NC - 1; c >= 0; --c) {
    float G2[36], b2[6], C2[21];
    if (c > 0) {
      const float* __restrict__ o = chunkops + (size_t)(c - 1) * 63 * B + seq;
#pragma unroll
      for (int k = 0; k < 36; k++) G2[k] = o[(size_t)k * B];
#pragma unroll
      for (int k = 0; k < 6; k++) b2[k] = o[(size_t)(36 + k) * B];
#pragma unroll
      for (int k = 0; k < 21; k++) C2[k] = o[(size_t)(42 + k) * B];
    }
    float* __restrict__ e = entries + (size_t)c * 27 * B + seq;
#pragma unroll
    for (int k = 0; k < 6; k++) e[(size_t)k * B] = s[k];
#pragma unroll
    for (int i = 0; i < 6; i++)
#pragma unroll
      for (int j = i; j < 6; j++) e[(size_t)(6 + uidx(i, j)) * B] = P[i][j];

    float ns[6];
#pragma unroll
    for (int i = 0; i < 6; i++) {
      float v = bv[i];
#pragma unroll
      for (int j = 0; j < 6; j++) v += G[i * 6 + j] * s[j];
      ns[i] = v;
    }
    float Y[6][6];
#pragma unroll
    for (int i = 0; i < 6; i++)
#pragma unroll
      for (int k = 0; k < 6; k++) {
        float v = 0.0f;
#pragma unroll
        for (int j = 0; j < 6; j++) v += G[i * 6 + j] * P[j][k];
        Y[i][k] = v;
      }
#pragma unroll
    for (int i = 0; i < 6; i++)
#pragma unroll
      for (int j = i; j < 6; j++) {
        float v = Cu[uidx(i, j)];
#pragma unroll
        for (int k = 0; k < 6; k++) v += Y[i][k] * G[j * 6 + k];
        P[i][j] = v;
        P[j][i] = v;
      }
#pragma unroll
    for (int i = 0; i < 6; i++) s[i] = ns[i];

    if (c > 0) {
#pragma unroll
      for (int k = 0; k < 36; k++) G[k] = G2[k];
#pragma unroll
      for (int k = 0; k < 6; k++) bv[k] = b2[k];
#pragma unroll
      for (int k = 0; k < 21; k++) Cu[k] = C2[k];
    }
  }

#pragma unroll
  for (int off = 32; off > 0; off >>= 1) loss += __shfl_down(loss, off);
  if (threadIdx.x == 0) atomicAdd(out, loss);
}

// ---------------------------------------------------------------------------
// Phase C: per (seq, chunk): redo RTS steps from entry state + loss (n>=2).
// ---------------------------------------------------------------------------
__global__ __launch_bounds__(256, 1) void applyloss_kernel(
    const float* __restrict__ params, const float* __restrict__ covp,
    const float* __restrict__ hist, const float* __restrict__ entries,
    const float* __restrict__ z, float* __restrict__ out) {
  const int tid = blockIdx.x * 256 + threadIdx.x;
  const int seq = tid & (B - 1);
  const int c = tid >> 12;
  const int lo = (c == 0) ? 2 : c * 8;
  const int hi = (c == NC - 1) ? (T - 2) : (c * 8 + 7);

  const float friction = (fast_tanh(params[0]) + 1.0f) * 0.01f;
  const float damping  = (fast_tanh(params[1]) + 1.0f) * 0.01f;
  float cp[7];
#pragma unroll
  for (int i = 0; i < 7; i++) cp[i] = sigmoidf(covp[i]);
  const float r0 = cp[0], r1 = cp[1], r2 = cp[2];
  const float q[6] = {cp[3], cp[3], cp[4], cp[4], cp[5], cp[6]};
  const float dcoef = 1.0f - DTc * damping;
  const float* __restrict__ zs = z + (size_t)seq * T * 3;

  const float* __restrict__ e = entries + (size_t)c * 27 * B + seq;
  float s[6];
#pragma unroll
  for (int k = 0; k < 6; k++) s[k] = e[(size_t)k * B];
  float P[6][6];
#pragma unroll
  for (int i = 0; i < 6; i++)
#pragma unroll
    for (int j = i; j < 6; j++) {
      const float v = e[(size_t)(6 + uidx(i, j)) * B];
      P[i][j] = v;
      P[j][i] = v;
    }

  float loss = 0.0f;

#pragma unroll 1
  for (int n = hi; n >= lo; --n) {
    float s_f[6], Pf[6][6];
    load_hist(hist, n, seq, s_f, Pf);
    const float zz0 = zs[n * 3 + 0];
    const float zz1 = zs[n * 3 + 1];
    const float zz2 = zs[n * 3 + 2];

    float sp[6], X[6][6], Pp[6][6], dg[6], gx, gy;
    rts_core(s_f, Pf, friction, damping, dcoef, q, sp, X, Pp, dg, gx, gy);

    float ds[6];
#pragma unroll
    for (int j = 0; j < 6; j++) ds[j] = s[j] - sp[j];
    float M[6][6];
#pragma unroll
    for (int i = 0; i < 6; i++)
#pragma unroll
      for (int j = 0; j < 6; j++) {
        const float ppo = (i == j) ? dg[i] : ((i < j) ? Pp[i][j] : Pp[j][i]);
        M[i][j] = P[i][j] - ppo;
      }

    float ns[6];
#pragma unroll
    for (int i = 0; i < 6; i++) {
      float v = s_f[i];
#pragma unroll
      for (int j = 0; j < 6; j++) v += X[j][i] * ds[j];
      ns[i] = v;
    }
    float GM[6][6];
#pragma unroll
    for (int i = 0; i < 6; i++)
#pragma unroll
      for (int k = 0; k < 6; k++) {
        float v = 0.0f;
#pragma unroll
        for (int j = 0; j < 6; j++) v += X[j][i] * M[j][k];
        GM[i][k] = v;
      }
#pragma unroll
    for (int i = 0; i < 6; i++)
#pragma unroll
      for (int j = i; j < 6; j++) {
        float v = Pf[i][j];
#pragma unroll
        for (int k = 0; k < 6; k++) v += GM[i][k] * X[k][j];
        P[i][j] = v;
        P[j][i] = v;
      }
#pragma unroll
    for (int i = 0; i < 6; i++) s[i] = ns[i];

    if (n >= 2)
      loss += loss_term(P, s, zz0, zz1, zz2, r0, r1, r2);
  }

#pragma unroll
  for (int off = 32; off > 0; off >>= 1) loss += __shfl_down(loss, off);
  if ((threadIdx.x & 63) == 0) atomicAdd(out, loss);
}

}  // namespace

extern "C" void kernel_launch(void* const* d_in, const int* in_sizes, int n_in,
                              void* d_out, int out_size, void* d_ws, size_t ws_size,
                              hipStream_t stream) {
  const float* params      = (const float*)d_in[0];
  const float* covp        = (const float*)d_in[1];
  const float* init_states = (const float*)d_in[2];
  const float* z           = (const float*)d_in[3];
  float* out = (float*)d_out;

  const size_t histF    = (size_t)T * TS;       // 29.36M floats = 117.4 MB
  const size_t chunkF   = (size_t)NC * 63 * B;  // 16.5 MB
  const size_t entriesF = (size_t)NC * 27 * B;  //  7.1 MB
  const size_t needBytes = (histF + chunkF + entriesF) * sizeof(float);

  hipMemsetAsync(d_out, 0, sizeof(float), stream);

  if (ws_size >= needBytes) {
    float* hist     = (float*)d_ws;
    float* chunkops = hist + histF;
    float* entries  = chunkops + chunkF;

    fwd4_kernel<<<NW, 64, 0, stream>>>(params, covp, init_states, z, hist);
    chunkops_kernel<<<(B * NC) / 256, 256, 0, stream>>>(params, covp, hist, chunkops);
    chunkscan_kernel<<<B / 64, 64, 0, stream>>>(covp, z, hist, chunkops, entries, out);
    applyloss_kernel<<<(B * NC) / 256, 256, 0, stream>>>(params, covp, hist, entries, z, out);
  }
}

// Round 5
// 220.195 us; speedup vs baseline: 2.4118x; 1.0470x over previous
//
#include <hip/hip_runtime.h>
#include <cmath>

// Kalman_Smooth_Gradient: B=4096 seqs, T=128 steps, 6-state EKF + RTS + loss.
// Round 5: two kernels total.
//   fwd4:     forward EKF, 4 lanes/seq via DPP quad_perm (256 waves), stores
//             hist in wave-chunked layout hist[((t*NW+wg)*14 + plane)*64 + lane].
//   bwdfused: ONE backward kernel, block = 64 thr = 4 seqs x 16 chunks.
//             Phase 1: thread (c,seq) composes its chunk's 8 backward affine
//                      ops (G,b,C) from hist.
//             Phase 2: Kogge-Stone inclusive suffix scan of the 16 chunk ops
//                      per seq in LDS (4 rounds), all threads busy.
//             Phase 3: exclusive suffix op (right neighbor) applied to the
//                      terminal state -> chunk entry state; redo 8 RTS steps
//                      with loss accumulation; wave-reduce + atomicAdd.

namespace {

constexpr int B = 4096;
constexpr int T = 128;
constexpr int NC = 16;                        // backward chunks
constexpr int NW = B * 4 / 64;                // 256 forward waves
constexpr size_t TS = (size_t)NW * 14 * 64;   // hist floats per t
constexpr int OPS = 81;                       // LDS stride per op (81%32=17, odd)
constexpr float DTc     = 1.0f / 120.0f;
constexpr float TWO_PIc = 6.28318530717958647692f;
constexpr float PI_1_5  = 4.71238898038468985769f;  // 1.5*pi

__device__ __forceinline__ float frcp(float x) { return __builtin_amdgcn_rcpf(x); }

__device__ __forceinline__ float fast_tanh(float x) {
  float e = __expf(2.0f * x);
  return 1.0f - 2.0f * frcp(e + 1.0f);
}
__device__ __forceinline__ float sigmoidf(float x) {
  return frcp(1.0f + __expf(-x));
}

// DPP quad_perm
template <int CTRL>
__device__ __forceinline__ float qp(float x) {
  return __int_as_float(__builtin_amdgcn_update_dpp(
      __float_as_int(x), __float_as_int(x), CTRL, 0xF, 0xF, false));
}
constexpr int QP_B0 = 0;
constexpr int QP_B1 = 85;
constexpr int QP_B2 = 170;
constexpr int QP_B3 = 255;
constexpr int QP_2323 = 238;

__device__ __forceinline__ float loss_term(const float Pm[6][6], const float sv[6],
                                           float z0, float z1, float z2,
                                           float r0, float r1, float r2) {
  float a = Pm[0][0] + r0, b = Pm[0][1], c = Pm[0][4];
  float d = Pm[1][1] + r1, e = Pm[1][4], f = Pm[4][4] + r2;
  float det = a * (d * f - e * e) + b * (c * e - b * f) + c * (b * e - d * c);
  float e0 = z0 - sv[0], e1 = z1 - sv[1], aa = z2 - sv[4];
  if (aa >  PI_1_5) aa -= TWO_PIc;
  if (aa < -PI_1_5) aa += TWO_PIc;
  float quad = a * e0 * e0 + d * e1 * e1 + f * aa * aa +
               2.0f * (b * e0 * e1 + c * e0 * aa + e * e1 * aa);
  return det + quad;
}

// Read (s_f, Pf) for (t, seq) from the wave-chunked hist layout.
__device__ __forceinline__ void load_hist(const float* __restrict__ hist, int t,
                                          int seq, float s_f[6], float Pf[6][6]) {
  const float* hc = hist + (size_t)t * TS + (size_t)(seq >> 4) * (14 * 64) +
                    (seq & 15) * 4;
  const float4 s03 = *(const float4*)(hc);
  const float2 s45 = *(const float2*)(hc + 64);
  s_f[0] = s03.x; s_f[1] = s03.y; s_f[2] = s03.z; s_f[3] = s03.w;
  s_f[4] = s45.x; s_f[5] = s45.y;
#pragma unroll
  for (int j = 0; j < 6; j++) {
    const float4 a = *(const float4*)(hc + (size_t)(2 + j) * 64);
    const float2 b = *(const float2*)(hc + (size_t)(8 + j) * 64);
    Pf[0][j] = a.x; Pf[1][j] = a.y; Pf[2][j] = a.z; Pf[3][j] = a.w;
    Pf[4][j] = b.x; Pf[5][j] = b.y;
  }
}

// Core of one backward RTS step from filtered (s_f, Pf) at n.
__device__ __forceinline__ void rts_core(
    const float s_f[6], const float Pf[6][6],
    float friction, float damping, float dcoef, const float* __restrict__ q,
    float sp[6], float W[6][6], float Pp[6][6], float diag[6],
    float& gxo, float& gyo) {
  const float tx = fast_tanh(100.0f * s_f[2]);
  const float ty = fast_tanh(100.0f * s_f[3]);
  sp[0] = s_f[0] + DTc * s_f[2];
  sp[1] = s_f[1] + DTc * s_f[3];
  sp[2] = s_f[2] - DTc * (damping * s_f[2] + friction * tx);
  sp[3] = s_f[3] - DTc * (damping * s_f[3] + friction * ty);
  sp[4] = s_f[4] + DTc * s_f[5];
  sp[5] = s_f[5] * dcoef;
  const float gx = 1.0f - DTc * (damping + friction * 100.0f * (1.0f - tx * tx));
  const float gy = 1.0f - DTc * (damping + friction * 100.0f * (1.0f - ty * ty));
  gxo = gx; gyo = gy;

#pragma unroll
  for (int j = 0; j < 6; j++) {
    W[0][j] = Pf[0][j] + DTc * Pf[2][j];
    W[1][j] = Pf[1][j] + DTc * Pf[3][j];
    W[2][j] = gx * Pf[2][j];
    W[3][j] = gy * Pf[3][j];
    W[4][j] = Pf[4][j] + DTc * Pf[5][j];
    W[5][j] = dcoef * Pf[5][j];
  }
#pragma unroll
  for (int i = 0; i < 6; i++) {
    Pp[i][0] = W[i][0] + DTc * W[i][2];
    Pp[i][1] = W[i][1] + DTc * W[i][3];
    Pp[i][2] = gx * W[i][2];
    Pp[i][3] = gy * W[i][3];
    Pp[i][4] = W[i][4] + DTc * W[i][5];
    Pp[i][5] = dcoef * W[i][5];
  }
#pragma unroll
  for (int i = 0; i < 6; i++) { Pp[i][i] += q[i]; diag[i] = Pp[i][i]; }

  float rd[6];
#pragma unroll
  for (int k = 0; k < 6; k++) {
    float dv = Pp[k][k];
#pragma unroll
    for (int m = 0; m < k; m++) dv -= Pp[k][m] * Pp[k][m];
    dv = sqrtf(fmaxf(dv, 1e-30f));
    Pp[k][k] = dv;
    rd[k] = frcp(dv);
#pragma unroll
    for (int i = k + 1; i < 6; i++) {
      float v = Pp[i][k];
#pragma unroll
      for (int m = 0; m < k; m++) v -= Pp[i][m] * Pp[k][m];
      Pp[i][k] = v * rd[k];
    }
  }
#pragma unroll
  for (int c = 0; c < 6; c++) {
    float y[6];
#pragma unroll
    for (int i = 0; i < 6; i++) {
      float v = W[i][c];
#pragma unroll
      for (int m = 0; m < i; m++) v -= Pp[i][m] * y[m];
      y[i] = v * rd[i];
    }
#pragma unroll
    for (int i = 5; i >= 0; i--) {
      float v = y[i];
#pragma unroll
      for (int m = i + 1; m < 6; m++) v -= Pp[m][i] * W[m][c];
      W[i][c] = v * rd[i];
    }
  }
}

// O = A o B  (apply B first, then A):
//   G = GA GB ; b = GA bB + bA ; C = CA + GA CB GA^T
// Alias-safe (temps then copy).
__device__ __forceinline__ void compose_op(
    const float AG[36], const float Ab[6], const float AC[36],
    const float BG[36], const float Bb[6], const float BC[36],
    float OG[36], float Ob[6], float OC[36]) {
  float tG[36], tb[6], Y[36], tC[36];
#pragma unroll
  for (int i = 0; i < 6; i++) {
    float bacc = Ab[i];
#pragma unroll
    for (int k = 0; k < 6; k++) bacc += AG[i * 6 + k] * Bb[k];
    tb[i] = bacc;
#pragma unroll
    for (int j = 0; j < 6; j++) {
      float g = 0.0f, y = 0.0f;
#pragma unroll
      for (int k = 0; k < 6; k++) {
        g += AG[i * 6 + k] * BG[k * 6 + j];
        y += AG[i * 6 + k] * BC[k * 6 + j];
      }
      tG[i * 6 + j] = g;
      Y[i * 6 + j] = y;
    }
  }
#pragma unroll
  for (int i = 0; i < 6; i++)
#pragma unroll
    for (int j = i; j < 6; j++) {
      float v = AC[i * 6 + j];
#pragma unroll
      for (int k = 0; k < 6; k++) v += Y[i * 6 + k] * AG[j * 6 + k];
      tC[i * 6 + j] = v;
      tC[j * 6 + i] = v;
    }
#pragma unroll
  for (int k = 0; k < 36; k++) { OG[k] = tG[k]; OC[k] = tC[k]; }
#pragma unroll
  for (int k = 0; k < 6; k++) Ob[k] = tb[k];
}

// ---------------------------------------------------------------------------
// Forward EKF, 4 lanes/seq (unchanged from round 4).
// ---------------------------------------------------------------------------
__global__ __launch_bounds__(64, 1) void fwd4_kernel(
    const float* __restrict__ params, const float* __restrict__ covp,
    const float* __restrict__ init_states, const float* __restrict__ z,
    float* __restrict__ hist) {
  const int l = threadIdx.x;
  const int m = l & 3;
  const int si = l >> 2;
  const int wg = blockIdx.x;
  const int seq = wg * 16 + si;

  const float friction = (fast_tanh(params[0]) + 1.0f) * 0.01f;
  const float damping  = (fast_tanh(params[1]) + 1.0f) * 0.01f;
  float cp[7];
#pragma unroll
  for (int i = 0; i < 7; i++) cp[i] = sigmoidf(covp[i]);
  const float r0 = cp[0], r1 = cp[1], r2 = cp[2];
  const float q[6] = {cp[3], cp[3], cp[4], cp[4], cp[5], cp[6]};
  const float dcoef = 1.0f - DTc * damping;
  const float DTf = DTc * friction;
  const float f100 = friction * 100.0f;

  const float da = (m < 2) ? DTc : 0.0f;
  const float cb = (m == 0) ? 1.0f : (m == 1) ? dcoef : 0.0f;
  const float db = (m == 0) ? DTc : 0.0f;
  const float Aspa = (m < 2) ? 1.0f : dcoef;
  const float Bspa = (m < 2) ? DTc : 0.0f;
  const float Aspb = cb, Bspb = db;
  float qma[6], qmb[6];
#pragma unroll
  for (int j = 0; j < 6; j++) {
    qma[j] = (j == m) ? q[j] : 0.0f;
    qmb[j] = (m == 0 && j == 4) ? q[4] : (m == 1 && j == 5) ? q[5] : 0.0f;
  }

  float sa = init_states[seq * 6 + m];
  float sb = (m < 2) ? init_states[seq * 6 + 4 + m] : 0.0f;
  float Pa[6], Pb[6];
#pragma unroll
  for (int j = 0; j < 6; j++) {
    Pa[j] = (j == m) ? 0.01f : 0.0f;
    Pb[j] = (m < 2 && j == m + 4) ? 0.01f : 0.0f;
  }

  const float* __restrict__ zp = z + (size_t)seq * (T * 3);
  float* __restrict__ hbase = hist + (size_t)wg * (14 * 64) + l;

  float z0 = zp[0], z1 = zp[1], z2 = zp[2];

#pragma unroll 1
  for (int t = 0; t < T; t++) {
    float z0n = 0.f, z1n = 0.f, z2n = 0.f;
    if (t < T - 1) {
      z0n = zp[(t + 1) * 3 + 0];
      z1n = zp[(t + 1) * 3 + 1];
      z2n = zp[(t + 1) * 3 + 2];
    }

    const float s2 = qp<QP_B2>(sa);
    const float s3 = qp<QP_B3>(sa);
    const float tx = fast_tanh(100.0f * s2);
    const float ty = fast_tanh(100.0f * s3);
    const float gx = 1.0f - DTc * (damping + f100 * (1.0f - tx * tx));
    const float gy = 1.0f - DTc * (damping + f100 * (1.0f - ty * ty));
    const float ca = (m == 2) ? gx : (m == 3) ? gy : 1.0f;

    const float sshf = qp<QP_2323>(sa);
    const float s5s  = qp<QP_B1>(sb);
    const float tsel = (m == 2) ? tx : (m == 3) ? ty : 0.0f;
    const float spa = fmaf(Bspa, sshf, fmaf(Aspa, sa, -DTf * tsel));
    const float spb = fmaf(Bspb, s5s, Aspb * sb);

    float Aa[6], Ab[6];
#pragma unroll
    for (int j = 0; j < 6; j++) {
      const float t1 = qp<QP_2323>(Pa[j]);
      const float t2 = qp<QP_B1>(Pb[j]);
      Aa[j] = fmaf(da, t1, ca * Pa[j]);
      Ab[j] = fmaf(db, t2, cb * Pb[j]);
    }
    float Ppa[6], Ppb[6];
    Ppa[0] = fmaf(DTc, Aa[2], Aa[0]) + qma[0];
    Ppa[1] = fmaf(DTc, Aa[3], Aa[1]) + qma[1];
    Ppa[2] = fmaf(gx, Aa[2], qma[2]);
    Ppa[3] = fmaf(gy, Aa[3], qma[3]);
    Ppa[4] = fmaf(DTc, Aa[5], Aa[4]) + qma[4];
    Ppa[5] = fmaf(dcoef, Aa[5], qma[5]);
    Ppb[0] = fmaf(DTc, Ab[2], Ab[0]) + qmb[0];
    Ppb[1] = fmaf(DTc, Ab[3], Ab[1]) + qmb[1];
    Ppb[2] = fmaf(gx, Ab[2], qmb[2]);
    Ppb[3] = fmaf(gy, Ab[3], qmb[3]);
    Ppb[4] = fmaf(DTc, Ab[5], Ab[4]) + qmb[4];
    Ppb[5] = fmaf(dcoef, Ab[5], qmb[5]);

    const float Sa = qp<QP_B0>(Ppa[0]) + r0;
    const float Sbv = qp<QP_B0>(Ppa[1]);
    const float Scv = qp<QP_B0>(Ppa[4]);
    const float Sd = qp<QP_B1>(Ppa[1]) + r1;
    const float Se = qp<QP_B1>(Ppa[4]);
    const float Sf = qp<QP_B0>(Ppb[4]) + r2;
    const float C00 = Sd * Sf - Se * Se;
    const float C01 = Scv * Se - Sbv * Sf;
    const float C02 = Sbv * Se - Sd * Scv;
    const float det = Sa * C00 + Sbv * C01 + Scv * C02;
    const float idet = frcp(det);
    const float Si00 = C00 * idet, Si01 = C01 * idet, Si02 = C02 * idet;
    const float Si11 = (Sa * Sf - Scv * Scv) * idet;
    const float Si12 = (Sbv * Scv - Sa * Se) * idet;
    const float Si22 = (Sa * Sd - Sbv * Sbv) * idet;

    const float Ka0 = Ppa[0] * Si00 + Ppa[1] * Si01 + Ppa[4] * Si02;
    const float Ka1 = Ppa[0] * Si01 + Ppa[1] * Si11 + Ppa[4] * Si12;
    const float Ka2 = Ppa[0] * Si02 + Ppa[1] * Si12 + Ppa[4] * Si22;
    const float Kb0 = Ppb[0] * Si00 + Ppb[1] * Si01 + Ppb[4] * Si02;
    const float Kb1 = Ppb[0] * Si01 + Ppb[1] * Si11 + Ppb[4] * Si12;
    const float Kb2 = Ppb[0] * Si02 + Ppb[1] * Si12 + Ppb[4] * Si22;

    const float sp0 = qp<QP_B0>(spa);
    const float sp1 = qp<QP_B1>(spa);
    const float sp4 = qp<QP_B0>(spb);
    const float i0 = z0 - sp0;
    const float i1 = z1 - sp1;
    float ia = z2 - sp4;
    ia = ia - TWO_PIc * rintf(ia * (1.0f / TWO_PIc));

    sa = spa + Ka0 * i0 + Ka1 * i1 + Ka2 * ia;
    sb = spb + Kb0 * i0 + Kb1 * i1 + Kb2 * ia;

#pragma unroll
    for (int j = 0; j < 6; j++) {
      const float p0 = qp<QP_B0>(Ppa[j]);
      const float p1 = qp<QP_B1>(Ppa[j]);
      const float p4 = qp<QP_B0>(Ppb[j]);
      Pa[j] = Ppa[j] - (Ka0 * p0 + Ka1 * p1 + Ka2 * p4);
      Pb[j] = Ppb[j] - (Kb0 * p0 + Kb1 * p1 + Kb2 * p4);
    }

    float* __restrict__ hc = hbase + (size_t)t * TS;
    hc[0 * 64] = sa;
    hc[1 * 64] = sb;
#pragma unroll
    for (int j = 0; j < 6; j++) {
      hc[(2 + j) * 64] = Pa[j];
      hc[(8 + j) * 64] = Pb[j];
    }

    z0 = z0n; z1 = z1n; z2 = z2n;
  }
}

// ---------------------------------------------------------------------------
// Fused backward: chunk-op build + LDS Kogge-Stone suffix scan + redo + loss.
// Block = 64 threads = 4 seqs x 16 chunks. Grid = B/4 = 1024 blocks.
// ---------------------------------------------------------------------------
__global__ __launch_bounds__(64, 1) void bwdfused_kernel(
    const float* __restrict__ params, const float* __restrict__ covp,
    const float* __restrict__ hist, const float* __restrict__ z,
    float* __restrict__ out) {
  const int l = threadIdx.x;
  const int c = l & (NC - 1);
  const int seq = blockIdx.x * 4 + (l >> 4);
  const int lo = c * 8;
  const int hi = (c == NC - 1) ? (T - 2) : (lo + 7);

  __shared__ float lops[64 * OPS];
  float* __restrict__ myop = &lops[l * OPS];

  const float friction = (fast_tanh(params[0]) + 1.0f) * 0.01f;
  const float damping  = (fast_tanh(params[1]) + 1.0f) * 0.01f;
  float cp[7];
#pragma unroll
  for (int i = 0; i < 7; i++) cp[i] = sigmoidf(covp[i]);
  const float r0 = cp[0], r1 = cp[1], r2 = cp[2];
  const float q[6] = {cp[3], cp[3], cp[4], cp[4], cp[5], cp[6]};
  const float dcoef = 1.0f - DTc * damping;
  const float* __restrict__ zs = z + (size_t)seq * T * 3;

  // ---- phase 1: build this chunk's composed affine op (QG, Qb, QC) ----
  float QG[36], Qb[6], QC[36];

#pragma unroll 1
  for (int n = hi; n >= lo; --n) {
    float s_f[6], Pf[6][6];
    load_hist(hist, n, seq, s_f, Pf);

    float sp[6], X[6][6], Pp[6][6], dg[6], gx, gy;
    rts_core(s_f, Pf, friction, damping, dcoef, q, sp, X, Pp, dg, gx, gy);
    // G_n[i][j] = X[j][i]

    float Gn[36], bn[6], Cn[36];
#pragma unroll
    for (int i = 0; i < 6; i++) {
      float v = s_f[i];
#pragma unroll
      for (int j = 0; j < 6; j++) {
        Gn[i * 6 + j] = X[j][i];
        v -= X[j][i] * sp[j];
      }
      bn[i] = v;
    }
#pragma unroll
    for (int i = 0; i < 6; i++) {
      float w[6];
      w[0] = Pf[0][i] + DTc * Pf[2][i];
      w[1] = Pf[1][i] + DTc * Pf[3][i];
      w[2] = gx * Pf[2][i];
      w[3] = gy * Pf[3][i];
      w[4] = Pf[4][i] + DTc * Pf[5][i];
      w[5] = dcoef * Pf[5][i];
#pragma unroll
      for (int j = i; j < 6; j++) {
        float v = Pf[i][j];
#pragma unroll
        for (int k = 0; k < 6; k++) v -= w[k] * X[k][j];
        Cn[i * 6 + j] = v;
        Cn[j * 6 + i] = v;
      }
    }

    if (n == hi) {
#pragma unroll
      for (int k = 0; k < 36; k++) { QG[k] = Gn[k]; QC[k] = Cn[k]; }
#pragma unroll
      for (int k = 0; k < 6; k++) Qb[k] = bn[k];
    } else {
      compose_op(Gn, bn, Cn, QG, Qb, QC, QG, Qb, QC);
    }
  }

  // write own op
#pragma unroll
  for (int k = 0; k < 36; k++) { myop[k] = QG[k]; myop[42 + k] = QC[k]; }
#pragma unroll
  for (int k = 0; k < 6; k++) myop[36 + k] = Qb[k];
  __syncthreads();

  // ---- phase 2: Kogge-Stone inclusive suffix scan over the 16 chunk ops ----
#pragma unroll 1
  for (int r = 1; r < NC; r <<= 1) {
    float PG[36], Pb[6], PC[36];
    const bool act = (c + r) < NC;
    if (act) {
      const float* __restrict__ p = &lops[(l + r) * OPS];
#pragma unroll
      for (int k = 0; k < 36; k++) { PG[k] = p[k]; PC[k] = p[42 + k]; }
#pragma unroll
      for (int k = 0; k < 6; k++) Pb[k] = p[36 + k];
    }
    __syncthreads();
    if (act) compose_op(QG, Qb, QC, PG, Pb, PC, QG, Qb, QC);
#pragma unroll
    for (int k = 0; k < 36; k++) { myop[k] = QG[k]; myop[42 + k] = QC[k]; }
#pragma unroll
    for (int k = 0; k < 6; k++) myop[36 + k] = Qb[k];
    __syncthreads();
  }

  // ---- phase 3: entry state = exclusive-suffix(terminal), then redo+loss ----
  float st[6], Pt[6][6];
  load_hist(hist, T - 1, seq, st, Pt);

  float s[6], P[6][6];
  float loss = 0.0f;

  if (c < NC - 1) {
    // read neighbor's inclusive suffix = my exclusive suffix
    const float* __restrict__ p = &lops[(l + 1) * OPS];
    float EG[36], Eb[6], EC[36];
#pragma unroll
    for (int k = 0; k < 36; k++) { EG[k] = p[k]; EC[k] = p[42 + k]; }
#pragma unroll
    for (int k = 0; k < 6; k++) Eb[k] = p[36 + k];

#pragma unroll
    for (int i = 0; i < 6; i++) {
      float v = Eb[i];
#pragma unroll
      for (int j = 0; j < 6; j++) v += EG[i * 6 + j] * st[j];
      s[i] = v;
    }
    float Y[6][6];
#pragma unroll
    for (int i = 0; i < 6; i++)
#pragma unroll
      for (int k = 0; k < 6; k++) {
        float v = 0.0f;
#pragma unroll
        for (int j = 0; j < 6; j++) v += EG[i * 6 + j] * Pt[j][k];
        Y[i][k] = v;
      }
#pragma unroll
    for (int i = 0; i < 6; i++)
#pragma unroll
      for (int j = i; j < 6; j++) {
        float v = EC[i * 6 + j];
#pragma unroll
        for (int k = 0; k < 6; k++) v += Y[i][k] * EG[j * 6 + k];
        P[i][j] = v;
        P[j][i] = v;
      }
  } else {
#pragma unroll
    for (int i = 0; i < 6; i++) {
      s[i] = st[i];
#pragma unroll
      for (int j = 0; j < 6; j++) P[i][j] = Pt[i][j];
    }
    // loss at t = T-1 (smoothed == filtered)
    loss = loss_term(Pt, st, zs[(T - 1) * 3 + 0], zs[(T - 1) * 3 + 1],
                     zs[(T - 1) * 3 + 2], r0, r1, r2);
  }

  const int lo2 = (c == 0) ? 2 : lo;  // loss only needed for n >= 2

#pragma unroll 1
  for (int n = hi; n >= lo2; --n) {
    float s_f[6], Pf[6][6];
    load_hist(hist, n, seq, s_f, Pf);
    const float zz0 = zs[n * 3 + 0];
    const float zz1 = zs[n * 3 + 1];
    const float zz2 = zs[n * 3 + 2];

    float sp[6], X[6][6], Pp[6][6], dg[6], gx, gy;
    rts_core(s_f, Pf, friction, damping, dcoef, q, sp, X, Pp, dg, gx, gy);

    float ds[6];
#pragma unroll
    for (int j = 0; j < 6; j++) ds[j] = s[j] - sp[j];
    float M[6][6];
#pragma unroll
    for (int i = 0; i < 6; i++)
#pragma unroll
      for (int j = 0; j < 6; j++) {
        const float ppo = (i == j) ? dg[i] : ((i < j) ? Pp[i][j] : Pp[j][i]);
        M[i][j] = P[i][j] - ppo;
      }

    float ns[6];
#pragma unroll
    for (int i = 0; i < 6; i++) {
      float v = s_f[i];
#pragma unroll
      for (int j = 0; j < 6; j++) v += X[j][i] * ds[j];
      ns[i] = v;
    }
    float GM[6][6];
#pragma unroll
    for (int i = 0; i < 6; i++)
#pragma unroll
      for (int k = 0; k < 6; k++) {
        float v = 0.0f;
#pragma unroll
        for (int j = 0; j < 6; j++) v += X[j][i] * M[j][k];
        GM[i][k] = v;
      }
#pragma unroll
    for (int i = 0; i < 6; i++)
#pragma unroll
      for (int j = i; j < 6; j++) {
        float v = Pf[i][j];
#pragma unroll
        for (int k = 0; k < 6; k++) v += GM[i][k] * X[k][j];
        P[i][j] = v;
        P[j][i] = v;
      }
#pragma unroll
    for (int i = 0; i < 6; i++) s[i] = ns[i];

    if (n >= 2)
      loss += loss_term(P, s, zz0, zz1, zz2, r0, r1, r2);
  }

  // ---- reduce + atomic ----
#pragma unroll
  for (int off = 32; off > 0; off >>= 1) loss += __shfl_down(loss, off);
  if (threadIdx.x == 0) atomicAdd(out, loss);
}

}  // namespace

extern "C" void kernel_launch(void* const* d_in, const int* in_sizes, int n_in,
                              void* d_out, int out_size, void* d_ws, size_t ws_size,
                              hipStream_t stream) {
  const float* params      = (const float*)d_in[0];
  const float* covp        = (const float*)d_in[1];
  const float* init_states = (const float*)d_in[2];
  const float* z           = (const float*)d_in[3];
  float* out = (float*)d_out;

  const size_t histBytes = (size_t)T * TS * sizeof(float);  // 117.4 MB

  hipMemsetAsync(d_out, 0, sizeof(float), stream);

  if (ws_size >= histBytes) {
    float* hist = (float*)d_ws;
    fwd4_kernel<<<NW, 64, 0, stream>>>(params, covp, init_states, z, hist);
    bwdfused_kernel<<<B / 4, 64, 0, stream>>>(params, covp, hist, z, out);
  }
}

// Round 7
// 209.909 us; speedup vs baseline: 2.5300x; 1.0490x over previous
//
#include <hip/hip_runtime.h>
#include <cmath>

// Kalman_Smooth_Gradient: B=4096 seqs, T=128 steps, 6-state EKF + RTS + loss.
// Round 7: single fused kernel, ORDINARY launch (no cooperative, no grid sync).
// Insight: backward of seq s depends only on forward of seq s, so each block
// owns 4 seqs end-to-end:
//   Section A (lanes 0..15 = 4 DPP quads): forward EKF for the block's 4 seqs,
//     compact 10-plane hist at hist[((t*NB + blk)*160) + plane*16 + col].
//   __syncthreads()  (block-local store->load visibility)
//   Section B (64 thr = 4 seqs x 16 chunks):
//     Phase 1: compose chunk's backward affine ops (G,b,C) from hist; emit the
//              27-float loss projection of the running within-chunk suffix op
//              to lane-coalesced private scratch.
//     Phase 2: Kogge-Stone inclusive suffix scan of chunk ops in LDS.
//     Phase 3: entry state from right neighbor's suffix; apply projections
//              (no Cholesky, no hist re-read) + loss; wave-reduce + atomicAdd.

namespace {

constexpr int B = 4096;
constexpr int T = 128;
constexpr int NC = 16;          // backward chunks per seq
constexpr int NB = B / 4;       // 1024 blocks
constexpr int OPS = 81;         // LDS floats per op (odd stride)
constexpr int PRJ = 27;         // proj floats per step
constexpr float DTc     = 1.0f / 120.0f;
constexpr float TWO_PIc = 6.28318530717958647692f;
constexpr float PI_1_5  = 4.71238898038468985769f;

__device__ __forceinline__ float frcp(float x) { return __builtin_amdgcn_rcpf(x); }

__device__ __forceinline__ float fast_tanh(float x) {
  float e = __expf(2.0f * x);
  return 1.0f - 2.0f * frcp(e + 1.0f);
}
__device__ __forceinline__ float sigmoidf(float x) {
  return frcp(1.0f + __expf(-x));
}

template <int CTRL>
__device__ __forceinline__ float qp(float x) {
  return __int_as_float(__builtin_amdgcn_update_dpp(
      __float_as_int(x), __float_as_int(x), CTRL, 0xF, 0xF, false));
}
constexpr int QP_B0 = 0;
constexpr int QP_B1 = 85;
constexpr int QP_B2 = 170;
constexpr int QP_B3 = 255;
constexpr int QP_2323 = 238;

__device__ __forceinline__ float loss_term(const float Pm[6][6], const float sv[6],
                                           float z0, float z1, float z2,
                                           float r0, float r1, float r2) {
  float a = Pm[0][0] + r0, b = Pm[0][1], c = Pm[0][4];
  float d = Pm[1][1] + r1, e = Pm[1][4], f = Pm[4][4] + r2;
  float det = a * (d * f - e * e) + b * (c * e - b * f) + c * (b * e - d * c);
  float e0 = z0 - sv[0], e1 = z1 - sv[1], aa = z2 - sv[4];
  if (aa >  PI_1_5) aa -= TWO_PIc;
  if (aa < -PI_1_5) aa += TWO_PIc;
  float quad = a * e0 * e0 + d * e1 * e1 + f * aa * aa +
               2.0f * (b * e0 * e1 + c * e0 * aa + e * e1 * aa);
  return det + quad;
}

// Read (s_f, Pf) for (t, block-local seq sl) from the compact 10-plane hist.
__device__ __forceinline__ void load_hist(const float* __restrict__ hist, int t,
                                          int blk, int sl,
                                          float s_f[6], float Pf[6][6]) {
  const float* hb = hist + ((size_t)t * NB + blk) * 160 + sl * 4;
  const float4 s03 = *(const float4*)(hb);
  const float2 s45 = *(const float2*)(hb + 16);
  s_f[0] = s03.x; s_f[1] = s03.y; s_f[2] = s03.z; s_f[3] = s03.w;
  s_f[4] = s45.x; s_f[5] = s45.y;
#pragma unroll
  for (int j = 0; j < 6; j++) {
    const float4 a = *(const float4*)(hb + (2 + j) * 16);
    Pf[0][j] = a.x; Pf[1][j] = a.y; Pf[2][j] = a.z; Pf[3][j] = a.w;
  }
#pragma unroll
  for (int j = 0; j < 4; j++) { Pf[4][j] = Pf[j][4]; Pf[5][j] = Pf[j][5]; }
  const float2 p4 = *(const float2*)(hb + 128);  // P44, P45(=P54)
  const float2 p5 = *(const float2*)(hb + 144);  // (dup), P55
  Pf[4][4] = p4.x; Pf[4][5] = p4.y; Pf[5][4] = p4.y; Pf[5][5] = p5.y;
}

// One backward RTS op-build core from filtered (s_f, Pf) at n.
// Returns sp, X = Pp^{-1} (F Pf) (G = X^T), gx, gy.
__device__ __forceinline__ void rts_core(
    const float s_f[6], const float Pf[6][6],
    float friction, float damping, float dcoef, const float* __restrict__ q,
    float sp[6], float W[6][6], float& gxo, float& gyo) {
  const float tx = fast_tanh(100.0f * s_f[2]);
  const float ty = fast_tanh(100.0f * s_f[3]);
  sp[0] = s_f[0] + DTc * s_f[2];
  sp[1] = s_f[1] + DTc * s_f[3];
  sp[2] = s_f[2] - DTc * (damping * s_f[2] + friction * tx);
  sp[3] = s_f[3] - DTc * (damping * s_f[3] + friction * ty);
  sp[4] = s_f[4] + DTc * s_f[5];
  sp[5] = s_f[5] * dcoef;
  const float gx = 1.0f - DTc * (damping + friction * 100.0f * (1.0f - tx * tx));
  const float gy = 1.0f - DTc * (damping + friction * 100.0f * (1.0f - ty * ty));
  gxo = gx; gyo = gy;

  float Pp[6][6];
#pragma unroll
  for (int j = 0; j < 6; j++) {
    W[0][j] = Pf[0][j] + DTc * Pf[2][j];
    W[1][j] = Pf[1][j] + DTc * Pf[3][j];
    W[2][j] = gx * Pf[2][j];
    W[3][j] = gy * Pf[3][j];
    W[4][j] = Pf[4][j] + DTc * Pf[5][j];
    W[5][j] = dcoef * Pf[5][j];
  }
#pragma unroll
  for (int i = 0; i < 6; i++) {
    Pp[i][0] = W[i][0] + DTc * W[i][2];
    Pp[i][1] = W[i][1] + DTc * W[i][3];
    Pp[i][2] = gx * W[i][2];
    Pp[i][3] = gy * W[i][3];
    Pp[i][4] = W[i][4] + DTc * W[i][5];
    Pp[i][5] = dcoef * W[i][5];
  }
#pragma unroll
  for (int i = 0; i < 6; i++) Pp[i][i] += q[i];

  float rd[6];
#pragma unroll
  for (int k = 0; k < 6; k++) {
    float dv = Pp[k][k];
#pragma unroll
    for (int m = 0; m < k; m++) dv -= Pp[k][m] * Pp[k][m];
    dv = sqrtf(fmaxf(dv, 1e-30f));
    Pp[k][k] = dv;
    rd[k] = frcp(dv);
#pragma unroll
    for (int i = k + 1; i < 6; i++) {
      float v = Pp[i][k];
#pragma unroll
      for (int m = 0; m < k; m++) v -= Pp[i][m] * Pp[k][m];
      Pp[i][k] = v * rd[k];
    }
  }
#pragma unroll
  for (int c = 0; c < 6; c++) {
    float y[6];
#pragma unroll
    for (int i = 0; i < 6; i++) {
      float v = W[i][c];
#pragma unroll
      for (int m = 0; m < i; m++) v -= Pp[i][m] * y[m];
      y[i] = v * rd[i];
    }
#pragma unroll
    for (int i = 5; i >= 0; i--) {
      float v = y[i];
#pragma unroll
      for (int m = i + 1; m < 6; m++) v -= Pp[m][i] * W[m][c];
      W[i][c] = v * rd[i];
    }
  }
}

// O = A o B (apply B first, then A). Alias-safe.
__device__ __forceinline__ void compose_op(
    const float AG[36], const float Ab[6], const float AC[36],
    const float BG[36], const float Bb[6], const float BC[36],
    float OG[36], float Ob[6], float OC[36]) {
  float tG[36], tb[6], Y[36], tC[36];
#pragma unroll
  for (int i = 0; i < 6; i++) {
    float bacc = Ab[i];
#pragma unroll
    for (int k = 0; k < 6; k++) bacc += AG[i * 6 + k] * Bb[k];
    tb[i] = bacc;
#pragma unroll
    for (int j = 0; j < 6; j++) {
      float g = 0.0f, y = 0.0f;
#pragma unroll
      for (int k = 0; k < 6; k++) {
        g += AG[i * 6 + k] * BG[k * 6 + j];
        y += AG[i * 6 + k] * BC[k * 6 + j];
      }
      tG[i * 6 + j] = g;
      Y[i * 6 + j] = y;
    }
  }
#pragma unroll
  for (int i = 0; i < 6; i++)
#pragma unroll
    for (int j = i; j < 6; j++) {
      float v = AC[i * 6 + j];
#pragma unroll
      for (int k = 0; k < 6; k++) v += Y[i * 6 + k] * AG[j * 6 + k];
      tC[i * 6 + j] = v;
      tC[j * 6 + i] = v;
    }
#pragma unroll
  for (int k = 0; k < 36; k++) { OG[k] = tG[k]; OC[k] = tC[k]; }
#pragma unroll
  for (int k = 0; k < 6; k++) Ob[k] = tb[k];
}

// ---------------------------------------------------------------------------
// Fused per-block fwd+bwd. Grid = NB = 1024 blocks x 64 threads (1 wave).
// ---------------------------------------------------------------------------
__global__ __launch_bounds__(64, 1) void fused_kernel(
    const float* __restrict__ params, const float* __restrict__ covp,
    const float* __restrict__ init_states, const float* __restrict__ z,
    float* __restrict__ hist, float* __restrict__ proj,
    float* __restrict__ out) {
  const int blk = blockIdx.x;
  const int l = threadIdx.x;

  __shared__ float lops[64 * OPS];

  // ---- shared scalars ----
  const float friction = (fast_tanh(params[0]) + 1.0f) * 0.01f;
  const float damping  = (fast_tanh(params[1]) + 1.0f) * 0.01f;
  float cp[7];
#pragma unroll
  for (int i = 0; i < 7; i++) cp[i] = sigmoidf(covp[i]);
  const float r0 = cp[0], r1 = cp[1], r2 = cp[2];
  const float q[6] = {cp[3], cp[3], cp[4], cp[4], cp[5], cp[6]};
  const float dcoef = 1.0f - DTc * damping;

  // ================= Section A: forward (lanes 0..15) =======================
  {
    const int m = l & 3;
    const int qd = l >> 2;           // quad = block-local seq; active if < 4
    if (qd < 4) {
      const int seq = blk * 4 + qd;
      const float DTf = DTc * friction;
      const float f100 = friction * 100.0f;

      const float da = (m < 2) ? DTc : 0.0f;
      const float cb = (m == 0) ? 1.0f : (m == 1) ? dcoef : 0.0f;
      const float db = (m == 0) ? DTc : 0.0f;
      const float Aspa = (m < 2) ? 1.0f : dcoef;
      const float Bspa = (m < 2) ? DTc : 0.0f;
      const float Aspb = cb, Bspb = db;
      float qma[6], qmb[6];
#pragma unroll
      for (int j = 0; j < 6; j++) {
        qma[j] = (j == m) ? q[j] : 0.0f;
        qmb[j] = (m == 0 && j == 4) ? q[4] : (m == 1 && j == 5) ? q[5] : 0.0f;
      }

      float sa = init_states[seq * 6 + m];
      float sb = (m < 2) ? init_states[seq * 6 + 4 + m] : 0.0f;
      float Pa[6], Pb[6];
#pragma unroll
      for (int j = 0; j < 6; j++) {
        Pa[j] = (j == m) ? 0.01f : 0.0f;
        Pb[j] = (m < 2 && j == m + 4) ? 0.01f : 0.0f;
      }

      const float* __restrict__ zp = z + (size_t)seq * (T * 3);
      float z0 = zp[0], z1 = zp[1], z2 = zp[2];

#pragma unroll 1
      for (int t = 0; t < T; t++) {
        float z0n = 0.f, z1n = 0.f, z2n = 0.f;
        if (t < T - 1) {
          z0n = zp[(t + 1) * 3 + 0];
          z1n = zp[(t + 1) * 3 + 1];
          z2n = zp[(t + 1) * 3 + 2];
        }

        const float s2 = qp<QP_B2>(sa);
        const float s3 = qp<QP_B3>(sa);
        const float tx = fast_tanh(100.0f * s2);
        const float ty = fast_tanh(100.0f * s3);
        const float gx = 1.0f - DTc * (damping + f100 * (1.0f - tx * tx));
        const float gy = 1.0f - DTc * (damping + f100 * (1.0f - ty * ty));
        const float ca = (m == 2) ? gx : (m == 3) ? gy : 1.0f;

        const float sshf = qp<QP_2323>(sa);
        const float s5s  = qp<QP_B1>(sb);
        const float tsel = (m == 2) ? tx : (m == 3) ? ty : 0.0f;
        const float spa = fmaf(Bspa, sshf, fmaf(Aspa, sa, -DTf * tsel));
        const float spb = fmaf(Bspb, s5s, Aspb * sb);

        float Aa[6], Ab[6];
#pragma unroll
        for (int j = 0; j < 6; j++) {
          const float t1 = qp<QP_2323>(Pa[j]);
          const float t2 = qp<QP_B1>(Pb[j]);
          Aa[j] = fmaf(da, t1, ca * Pa[j]);
          Ab[j] = fmaf(db, t2, cb * Pb[j]);
        }
        float Ppa[6], Ppb[6];
        Ppa[0] = fmaf(DTc, Aa[2], Aa[0]) + qma[0];
        Ppa[1] = fmaf(DTc, Aa[3], Aa[1]) + qma[1];
        Ppa[2] = fmaf(gx, Aa[2], qma[2]);
        Ppa[3] = fmaf(gy, Aa[3], qma[3]);
        Ppa[4] = fmaf(DTc, Aa[5], Aa[4]) + qma[4];
        Ppa[5] = fmaf(dcoef, Aa[5], qma[5]);
        Ppb[0] = fmaf(DTc, Ab[2], Ab[0]) + qmb[0];
        Ppb[1] = fmaf(DTc, Ab[3], Ab[1]) + qmb[1];
        Ppb[2] = fmaf(gx, Ab[2], qmb[2]);
        Ppb[3] = fmaf(gy, Ab[3], qmb[3]);
        Ppb[4] = fmaf(DTc, Ab[5], Ab[4]) + qmb[4];
        Ppb[5] = fmaf(dcoef, Ab[5], qmb[5]);

        const float Sa = qp<QP_B0>(Ppa[0]) + r0;
        const float Sbv = qp<QP_B0>(Ppa[1]);
        const float Scv = qp<QP_B0>(Ppa[4]);
        const float Sd = qp<QP_B1>(Ppa[1]) + r1;
        const float Se = qp<QP_B1>(Ppa[4]);
        const float Sf = qp<QP_B0>(Ppb[4]) + r2;
        const float C00 = Sd * Sf - Se * Se;
        const float C01 = Scv * Se - Sbv * Sf;
        const float C02 = Sbv * Se - Sd * Scv;
        const float det = Sa * C00 + Sbv * C01 + Scv * C02;
        const float idet = frcp(det);
        const float Si00 = C00 * idet, Si01 = C01 * idet, Si02 = C02 * idet;
        const float Si11 = (Sa * Sf - Scv * Scv) * idet;
        const float Si12 = (Sbv * Scv - Sa * Se) * idet;
        const float Si22 = (Sa * Sd - Sbv * Sbv) * idet;

        const float Ka0 = Ppa[0] * Si00 + Ppa[1] * Si01 + Ppa[4] * Si02;
        const float Ka1 = Ppa[0] * Si01 + Ppa[1] * Si11 + Ppa[4] * Si12;
        const float Ka2 = Ppa[0] * Si02 + Ppa[1] * Si12 + Ppa[4] * Si22;
        const float Kb0 = Ppb[0] * Si00 + Ppb[1] * Si01 + Ppb[4] * Si02;
        const float Kb1 = Ppb[0] * Si01 + Ppb[1] * Si11 + Ppb[4] * Si12;
        const float Kb2 = Ppb[0] * Si02 + Ppb[1] * Si12 + Ppb[4] * Si22;

        const float sp0 = qp<QP_B0>(spa);
        const float sp1 = qp<QP_B1>(spa);
        const float sp4 = qp<QP_B0>(spb);
        const float i0 = z0 - sp0;
        const float i1 = z1 - sp1;
        float ia = z2 - sp4;
        ia = ia - TWO_PIc * rintf(ia * (1.0f / TWO_PIc));

        sa = spa + Ka0 * i0 + Ka1 * i1 + Ka2 * ia;
        sb = spb + Kb0 * i0 + Kb1 * i1 + Kb2 * ia;

#pragma unroll
        for (int j = 0; j < 6; j++) {
          const float p0 = qp<QP_B0>(Ppa[j]);
          const float p1 = qp<QP_B1>(Ppa[j]);
          const float p4 = qp<QP_B0>(Ppb[j]);
          Pa[j] = Ppa[j] - (Ka0 * p0 + Ka1 * p1 + Ka2 * p4);
          Pb[j] = Ppb[j] - (Kb0 * p0 + Kb1 * p1 + Kb2 * p4);
        }

        // compact 10-plane store (16 lanes -> one 64B line per plane)
        float* __restrict__ hc = hist + ((size_t)t * NB + blk) * 160 + l;
        hc[0] = sa;
        hc[16] = sb;
#pragma unroll
        for (int j = 0; j < 6; j++) hc[(2 + j) * 16] = Pa[j];
        hc[128] = Pb[4];
        hc[144] = Pb[5];

        z0 = z0n; z1 = z1n; z2 = z2n;
      }
    }
  }

  __syncthreads();  // fwd stores -> bwd loads (block-local)

  // ================= Section B: backward =====================================
  const int c = l & (NC - 1);
  const int sl = l >> 4;          // block-local seq 0..3
  const int seq = blk * 4 + sl;
  const int lo = c * 8;
  const int hi = (c == NC - 1) ? (T - 2) : (lo + 7);
  const float* __restrict__ zs = z + (size_t)seq * T * 3;
  float* __restrict__ myop = &lops[l * OPS];
  float* __restrict__ myproj = proj + (size_t)blk * (8 * PRJ * 64) + l;

  // ---- phase 1: build chunk op; emit per-step loss projections ----
  float QG[36], Qb[6], QC[36];

#pragma unroll 1
  for (int n = hi; n >= lo; --n) {
    float s_f[6], Pf[6][6];
    load_hist(hist, n, blk, sl, s_f, Pf);

    float sp[6], X[6][6], gx, gy;
    rts_core(s_f, Pf, friction, damping, dcoef, q, sp, X, gx, gy);
    // G_n[i][j] = X[j][i]

    float Gn[36], bn[6], Cn[36];
#pragma unroll
    for (int i = 0; i < 6; i++) {
      float v = s_f[i];
#pragma unroll
      for (int j = 0; j < 6; j++) {
        Gn[i * 6 + j] = X[j][i];
        v -= X[j][i] * sp[j];
      }
      bn[i] = v;
    }
#pragma unroll
    for (int i = 0; i < 6; i++) {
      float w[6];
      w[0] = Pf[0][i] + DTc * Pf[2][i];
      w[1] = Pf[1][i] + DTc * Pf[3][i];
      w[2] = gx * Pf[2][i];
      w[3] = gy * Pf[3][i];
      w[4] = Pf[4][i] + DTc * Pf[5][i];
      w[5] = dcoef * Pf[5][i];
#pragma unroll
      for (int j = i; j < 6; j++) {
        float v = Pf[i][j];
#pragma unroll
        for (int k = 0; k < 6; k++) v -= w[k] * X[k][j];
        Cn[i * 6 + j] = v;
        Cn[j * 6 + i] = v;
      }
    }

    if (n == hi) {
#pragma unroll
      for (int k = 0; k < 36; k++) { QG[k] = Gn[k]; QC[k] = Cn[k]; }
#pragma unroll
      for (int k = 0; k < 6; k++) Qb[k] = bn[k];
    } else {
      compose_op(Gn, bn, Cn, QG, Qb, QC, QG, Qb, QC);
    }

    // emit loss projection of q_n = op_n o ... o op_hi (rows {0,1,4})
    if (n >= 2) {
      float pr[PRJ];
#pragma unroll
      for (int j = 0; j < 6; j++) {
        pr[j] = QG[j];            // G row 0
        pr[6 + j] = QG[6 + j];    // G row 1
        pr[12 + j] = QG[24 + j];  // G row 4
      }
      pr[18] = Qb[0]; pr[19] = Qb[1]; pr[20] = Qb[4];
      pr[21] = QC[0]; pr[22] = QC[1]; pr[23] = QC[4];
      pr[24] = QC[7]; pr[25] = QC[10]; pr[26] = QC[28];
      const int idx = n - lo;
#pragma unroll
      for (int k = 0; k < PRJ; k++) myproj[(size_t)(idx * PRJ + k) * 64] = pr[k];
    }
  }

  // write own chunk op to LDS
#pragma unroll
  for (int k = 0; k < 36; k++) { myop[k] = QG[k]; myop[42 + k] = QC[k]; }
#pragma unroll
  for (int k = 0; k < 6; k++) myop[36 + k] = Qb[k];
  __syncthreads();

  // ---- phase 2: Kogge-Stone inclusive suffix scan over 16 chunk ops ----
#pragma unroll 1
  for (int r = 1; r < NC; r <<= 1) {
    float PG[36], Pb2[6], PC[36];
    const bool act = (c + r) < NC;
    if (act) {
      const float* __restrict__ p = &lops[(l + r) * OPS];
#pragma unroll
      for (int k = 0; k < 36; k++) { PG[k] = p[k]; PC[k] = p[42 + k]; }
#pragma unroll
      for (int k = 0; k < 6; k++) Pb2[k] = p[36 + k];
    }
    __syncthreads();
    if (act) compose_op(QG, Qb, QC, PG, Pb2, PC, QG, Qb, QC);
#pragma unroll
    for (int k = 0; k < 36; k++) { myop[k] = QG[k]; myop[42 + k] = QC[k]; }
#pragma unroll
    for (int k = 0; k < 6; k++) myop[36 + k] = Qb[k];
    __syncthreads();
  }

  // ---- phase 3: entry state; apply stored projections + loss ----
  float st[6], Pt[6][6];
  load_hist(hist, T - 1, blk, sl, st, Pt);

  float sE[6], PE[6][6];
  float loss = 0.0f;

  if (c < NC - 1) {
    const float* __restrict__ p = &lops[(l + 1) * OPS];
    float EG[36], Eb[6], EC[36];
#pragma unroll
    for (int k = 0; k < 36; k++) { EG[k] = p[k]; EC[k] = p[42 + k]; }
#pragma unroll
    for (int k = 0; k < 6; k++) Eb[k] = p[36 + k];

#pragma unroll
    for (int i = 0; i < 6; i++) {
      float v = Eb[i];
#pragma unroll
      for (int j = 0; j < 6; j++) v += EG[i * 6 + j] * st[j];
      sE[i] = v;
    }
    float Y[6][6];
#pragma unroll
    for (int i = 0; i < 6; i++)
#pragma unroll
      for (int k = 0; k < 6; k++) {
        float v = 0.0f;
#pragma unroll
        for (int j = 0; j < 6; j++) v += EG[i * 6 + j] * Pt[j][k];
        Y[i][k] = v;
      }
#pragma unroll
    for (int i = 0; i < 6; i++)
#pragma unroll
      for (int j = i; j < 6; j++) {
        float v = EC[i * 6 + j];
#pragma unroll
        for (int k = 0; k < 6; k++) v += Y[i][k] * EG[j * 6 + k];
        PE[i][j] = v;
        PE[j][i] = v;
      }
  } else {
#pragma unroll
    for (int i = 0; i < 6; i++) {
      sE[i] = st[i];
#pragma unroll
      for (int j = 0; j < 6; j++) PE[i][j] = Pt[i][j];
    }
    loss = loss_term(Pt, st, zs[(T - 1) * 3 + 0], zs[(T - 1) * 3 + 1],
                     zs[(T - 1) * 3 + 2], r0, r1, r2);
  }

  const int lo2 = (c == 0) ? 2 : lo;

#pragma unroll 1
  for (int n = hi; n >= lo2; --n) {
    const int idx = n - lo;
    float pr[PRJ];
#pragma unroll
    for (int k = 0; k < PRJ; k++) pr[k] = myproj[(size_t)(idx * PRJ + k) * 64];
    const float zz0 = zs[n * 3 + 0];
    const float zz1 = zs[n * 3 + 1];
    const float zz2 = zs[n * 3 + 2];

    float sv0 = pr[18], sv1 = pr[19], sv4 = pr[20];
#pragma unroll
    for (int j = 0; j < 6; j++) {
      sv0 += pr[j] * sE[j];
      sv1 += pr[6 + j] * sE[j];
      sv4 += pr[12 + j] * sE[j];
    }
    float Y0[6], Y1[6], Y2[6];
#pragma unroll
    for (int k = 0; k < 6; k++) {
      float y0 = 0.f, y1 = 0.f, y2 = 0.f;
#pragma unroll
      for (int j = 0; j < 6; j++) {
        y0 += pr[j] * PE[j][k];
        y1 += pr[6 + j] * PE[j][k];
        y2 += pr[12 + j] * PE[j][k];
      }
      Y0[k] = y0; Y1[k] = y1; Y2[k] = y2;
    }
    float a = pr[21] + r0, b = pr[22], cc = pr[23];
    float d = pr[24] + r1, e = pr[25], f = pr[26] + r2;
#pragma unroll
    for (int k = 0; k < 6; k++) {
      a += Y0[k] * pr[k];
      b += Y0[k] * pr[6 + k];
      cc += Y0[k] * pr[12 + k];
      d += Y1[k] * pr[6 + k];
      e += Y1[k] * pr[12 + k];
      f += Y2[k] * pr[12 + k];
    }
    const float detv = a * (d * f - e * e) + b * (cc * e - b * f) +
                       cc * (b * e - d * cc);
    const float e0 = zz0 - sv0, e1 = zz1 - sv1;
    float aa = zz2 - sv4;
    if (aa >  PI_1_5) aa -= TWO_PIc;
    if (aa < -PI_1_5) aa += TWO_PIc;
    const float quad = a * e0 * e0 + d * e1 * e1 + f * aa * aa +
                       2.0f * (b * e0 * e1 + cc * e0 * aa + e * e1 * aa);
    loss += detv + quad;
  }

  // ---- reduce + atomic ----
#pragma unroll
  for (int off = 32; off > 0; off >>= 1) loss += __shfl_down(loss, off);
  if (l == 0) atomicAdd(out, loss);
}

}  // namespace

extern "C" void kernel_launch(void* const* d_in, const int* in_sizes, int n_in,
                              void* d_out, int out_size, void* d_ws, size_t ws_size,
                              hipStream_t stream) {
  const float* params      = (const float*)d_in[0];
  const float* covp        = (const float*)d_in[1];
  const float* init_states = (const float*)d_in[2];
  const float* z           = (const float*)d_in[3];
  float* out = (float*)d_out;

  const size_t histF = (size_t)T * NB * 160;         // 20.97M floats = 83.9 MB
  const size_t projF = (size_t)NB * 8 * PRJ * 64;    // 14.16M floats = 56.6 MB
  const size_t needBytes = (histF + projF) * sizeof(float);

  hipMemsetAsync(d_out, 0, sizeof(float), stream);

  if (ws_size >= needBytes) {
    float* hist = (float*)d_ws;
    float* prj  = hist + histF;
    fused_kernel<<<NB, 64, 0, stream>>>(params, covp, init_states, z, hist,
                                        prj, out);
  }
}

// Round 8
// 186.227 us; speedup vs baseline: 2.8517x; 1.1272x over previous
//
#include <hip/hip_runtime.h>
#include <cmath>

// Kalman_Smooth_Gradient: B=4096 seqs, T=128 steps, 6-state EKF + RTS + loss.
// Round 8: round-7 structure + software prefetch to kill latency stalls.
//   - Single fused kernel, 1024 blocks x 64 thr; block owns 4 seqs end-to-end.
//   - Section A: forward EKF via DPP quad_perm (16 active lanes); z fetched
//     with 1 load + quad-DPP broadcast; compact 10-plane hist.
//   - Section B: backward. Phase 1 (chunk-op build) prefetches the next
//     step's hist into registers while composing the current step; emits
//     27-float loss projections. Phase 2: LDS Kogge-Stone suffix scan.
//     Phase 3 applies projections with proj/z prefetch; reduce + atomicAdd.

namespace {

constexpr int B = 4096;
constexpr int T = 128;
constexpr int NC = 16;          // backward chunks per seq
constexpr int NB = B / 4;       // 1024 blocks
constexpr int OPS = 81;         // LDS floats per op (odd stride)
constexpr int PRJ = 27;         // proj floats per step
constexpr float DTc     = 1.0f / 120.0f;
constexpr float TWO_PIc = 6.28318530717958647692f;
constexpr float PI_1_5  = 4.71238898038468985769f;

__device__ __forceinline__ float frcp(float x) { return __builtin_amdgcn_rcpf(x); }

__device__ __forceinline__ float fast_tanh(float x) {
  float e = __expf(2.0f * x);
  return 1.0f - 2.0f * frcp(e + 1.0f);
}
__device__ __forceinline__ float sigmoidf(float x) {
  return frcp(1.0f + __expf(-x));
}

template <int CTRL>
__device__ __forceinline__ float qp(float x) {
  return __int_as_float(__builtin_amdgcn_update_dpp(
      __float_as_int(x), __float_as_int(x), CTRL, 0xF, 0xF, false));
}
constexpr int QP_B0 = 0;
constexpr int QP_B1 = 85;
constexpr int QP_B2 = 170;
constexpr int QP_B3 = 255;
constexpr int QP_2323 = 238;

__device__ __forceinline__ float loss_term(const float Pm[6][6], const float sv[6],
                                           float z0, float z1, float z2,
                                           float r0, float r1, float r2) {
  float a = Pm[0][0] + r0, b = Pm[0][1], c = Pm[0][4];
  float d = Pm[1][1] + r1, e = Pm[1][4], f = Pm[4][4] + r2;
  float det = a * (d * f - e * e) + b * (c * e - b * f) + c * (b * e - d * c);
  float e0 = z0 - sv[0], e1 = z1 - sv[1], aa = z2 - sv[4];
  if (aa >  PI_1_5) aa -= TWO_PIc;
  if (aa < -PI_1_5) aa += TWO_PIc;
  float quad = a * e0 * e0 + d * e1 * e1 + f * aa * aa +
               2.0f * (b * e0 * e1 + c * e0 * aa + e * e1 * aa);
  return det + quad;
}

// ---- hist prefetch: raw vector loads into registers ----
struct HistPref {
  float4 s03;
  float2 s45;
  float4 a[6];
  float2 p4, p5;
};

__device__ __forceinline__ void hist_pref(const float* __restrict__ hist, int t,
                                          int blk, int sl, HistPref& b) {
  const float* hb = hist + ((size_t)t * NB + blk) * 160 + sl * 4;
  b.s03 = *(const float4*)(hb);
  b.s45 = *(const float2*)(hb + 16);
#pragma unroll
  for (int j = 0; j < 6; j++) b.a[j] = *(const float4*)(hb + (2 + j) * 16);
  b.p4 = *(const float2*)(hb + 128);
  b.p5 = *(const float2*)(hb + 144);
}

__device__ __forceinline__ void hist_unpack(const HistPref& b, float s_f[6],
                                            float Pf[6][6]) {
  s_f[0] = b.s03.x; s_f[1] = b.s03.y; s_f[2] = b.s03.z; s_f[3] = b.s03.w;
  s_f[4] = b.s45.x; s_f[5] = b.s45.y;
#pragma unroll
  for (int j = 0; j < 6; j++) {
    Pf[0][j] = b.a[j].x; Pf[1][j] = b.a[j].y;
    Pf[2][j] = b.a[j].z; Pf[3][j] = b.a[j].w;
  }
#pragma unroll
  for (int j = 0; j < 4; j++) { Pf[4][j] = Pf[j][4]; Pf[5][j] = Pf[j][5]; }
  Pf[4][4] = b.p4.x; Pf[4][5] = b.p4.y; Pf[5][4] = b.p4.y; Pf[5][5] = b.p5.y;
}

// One backward RTS op-build core from filtered (s_f, Pf) at n.
// Returns sp, X = Pp^{-1} (F Pf) (G = X^T), gx, gy.
__device__ __forceinline__ void rts_core(
    const float s_f[6], const float Pf[6][6],
    float friction, float damping, float dcoef, const float* __restrict__ q,
    float sp[6], float W[6][6], float& gxo, float& gyo) {
  const float tx = fast_tanh(100.0f * s_f[2]);
  const float ty = fast_tanh(100.0f * s_f[3]);
  sp[0] = s_f[0] + DTc * s_f[2];
  sp[1] = s_f[1] + DTc * s_f[3];
  sp[2] = s_f[2] - DTc * (damping * s_f[2] + friction * tx);
  sp[3] = s_f[3] - DTc * (damping * s_f[3] + friction * ty);
  sp[4] = s_f[4] + DTc * s_f[5];
  sp[5] = s_f[5] * dcoef;
  const float gx = 1.0f - DTc * (damping + friction * 100.0f * (1.0f - tx * tx));
  const float gy = 1.0f - DTc * (damping + friction * 100.0f * (1.0f - ty * ty));
  gxo = gx; gyo = gy;

  float Pp[6][6];
#pragma unroll
  for (int j = 0; j < 6; j++) {
    W[0][j] = Pf[0][j] + DTc * Pf[2][j];
    W[1][j] = Pf[1][j] + DTc * Pf[3][j];
    W[2][j] = gx * Pf[2][j];
    W[3][j] = gy * Pf[3][j];
    W[4][j] = Pf[4][j] + DTc * Pf[5][j];
    W[5][j] = dcoef * Pf[5][j];
  }
#pragma unroll
  for (int i = 0; i < 6; i++) {
    Pp[i][0] = W[i][0] + DTc * W[i][2];
    Pp[i][1] = W[i][1] + DTc * W[i][3];
    Pp[i][2] = gx * W[i][2];
    Pp[i][3] = gy * W[i][3];
    Pp[i][4] = W[i][4] + DTc * W[i][5];
    Pp[i][5] = dcoef * W[i][5];
  }
#pragma unroll
  for (int i = 0; i < 6; i++) Pp[i][i] += q[i];

  float rd[6];
#pragma unroll
  for (int k = 0; k < 6; k++) {
    float dv = Pp[k][k];
#pragma unroll
    for (int m = 0; m < k; m++) dv -= Pp[k][m] * Pp[k][m];
    dv = sqrtf(fmaxf(dv, 1e-30f));
    Pp[k][k] = dv;
    rd[k] = frcp(dv);
#pragma unroll
    for (int i = k + 1; i < 6; i++) {
      float v = Pp[i][k];
#pragma unroll
      for (int m = 0; m < k; m++) v -= Pp[i][m] * Pp[k][m];
      Pp[i][k] = v * rd[k];
    }
  }
#pragma unroll
  for (int c = 0; c < 6; c++) {
    float y[6];
#pragma unroll
    for (int i = 0; i < 6; i++) {
      float v = W[i][c];
#pragma unroll
      for (int m = 0; m < i; m++) v -= Pp[i][m] * y[m];
      y[i] = v * rd[i];
    }
#pragma unroll
    for (int i = 5; i >= 0; i--) {
      float v = y[i];
#pragma unroll
      for (int m = i + 1; m < 6; m++) v -= Pp[m][i] * W[m][c];
      W[i][c] = v * rd[i];
    }
  }
}

// O = A o B (apply B first, then A). Alias-safe.
__device__ __forceinline__ void compose_op(
    const float AG[36], const float Ab[6], const float AC[36],
    const float BG[36], const float Bb[6], const float BC[36],
    float OG[36], float Ob[6], float OC[36]) {
  float tG[36], tb[6], Y[36], tC[36];
#pragma unroll
  for (int i = 0; i < 6; i++) {
    float bacc = Ab[i];
#pragma unroll
    for (int k = 0; k < 6; k++) bacc += AG[i * 6 + k] * Bb[k];
    tb[i] = bacc;
#pragma unroll
    for (int j = 0; j < 6; j++) {
      float g = 0.0f, y = 0.0f;
#pragma unroll
      for (int k = 0; k < 6; k++) {
        g += AG[i * 6 + k] * BG[k * 6 + j];
        y += AG[i * 6 + k] * BC[k * 6 + j];
      }
      tG[i * 6 + j] = g;
      Y[i * 6 + j] = y;
    }
  }
#pragma unroll
  for (int i = 0; i < 6; i++)
#pragma unroll
    for (int j = i; j < 6; j++) {
      float v = AC[i * 6 + j];
#pragma unroll
      for (int k = 0; k < 6; k++) v += Y[i * 6 + k] * AG[j * 6 + k];
      tC[i * 6 + j] = v;
      tC[j * 6 + i] = v;
    }
#pragma unroll
  for (int k = 0; k < 36; k++) { OG[k] = tG[k]; OC[k] = tC[k]; }
#pragma unroll
  for (int k = 0; k < 6; k++) Ob[k] = tb[k];
}

// ---------------------------------------------------------------------------
// Fused per-block fwd+bwd. Grid = NB = 1024 blocks x 64 threads (1 wave).
// ---------------------------------------------------------------------------
__global__ __launch_bounds__(64, 1) void fused_kernel(
    const float* __restrict__ params, const float* __restrict__ covp,
    const float* __restrict__ init_states, const float* __restrict__ z,
    float* __restrict__ hist, float* __restrict__ proj,
    float* __restrict__ out) {
  const int blk = blockIdx.x;
  const int l = threadIdx.x;

  __shared__ float lops[64 * OPS];

  // ---- shared scalars ----
  const float friction = (fast_tanh(params[0]) + 1.0f) * 0.01f;
  const float damping  = (fast_tanh(params[1]) + 1.0f) * 0.01f;
  float cp[7];
#pragma unroll
  for (int i = 0; i < 7; i++) cp[i] = sigmoidf(covp[i]);
  const float r0 = cp[0], r1 = cp[1], r2 = cp[2];
  const float q[6] = {cp[3], cp[3], cp[4], cp[4], cp[5], cp[6]};
  const float dcoef = 1.0f - DTc * damping;

  // ================= Section A: forward (lanes 0..15) =======================
  {
    const int m = l & 3;
    const int qd = l >> 2;
    if (qd < 4) {
      const int seq = blk * 4 + qd;
      const float DTf = DTc * friction;
      const float f100 = friction * 100.0f;

      const float da = (m < 2) ? DTc : 0.0f;
      const float cb = (m == 0) ? 1.0f : (m == 1) ? dcoef : 0.0f;
      const float db = (m == 0) ? DTc : 0.0f;
      const float Aspa = (m < 2) ? 1.0f : dcoef;
      const float Bspa = (m < 2) ? DTc : 0.0f;
      const float Aspb = cb, Bspb = db;
      float qma[6], qmb[6];
#pragma unroll
      for (int j = 0; j < 6; j++) {
        qma[j] = (j == m) ? q[j] : 0.0f;
        qmb[j] = (m == 0 && j == 4) ? q[4] : (m == 1 && j == 5) ? q[5] : 0.0f;
      }

      float sa = init_states[seq * 6 + m];
      float sb = (m < 2) ? init_states[seq * 6 + 4 + m] : 0.0f;
      float Pa[6], Pb[6];
#pragma unroll
      for (int j = 0; j < 6; j++) {
        Pa[j] = (j == m) ? 0.01f : 0.0f;
        Pb[j] = (m < 2 && j == m + 4) ? 0.01f : 0.0f;
      }

      const float* __restrict__ zp = z + (size_t)seq * (T * 3);
      const int mz = (m < 2) ? m : 2;  // lane m loads z[mz]; quad-DPP bcast
      float zl = zp[mz];

#pragma unroll 1
      for (int t = 0; t < T; t++) {
        float zln = 0.f;
        if (t < T - 1) zln = zp[(t + 1) * 3 + mz];

        const float z0 = qp<QP_B0>(zl);
        const float z1 = qp<QP_B1>(zl);
        const float z2 = qp<QP_B2>(zl);

        const float s2 = qp<QP_B2>(sa);
        const float s3 = qp<QP_B3>(sa);
        const float tx = fast_tanh(100.0f * s2);
        const float ty = fast_tanh(100.0f * s3);
        const float gx = 1.0f - DTc * (damping + f100 * (1.0f - tx * tx));
        const float gy = 1.0f - DTc * (damping + f100 * (1.0f - ty * ty));
        const float ca = (m == 2) ? gx : (m == 3) ? gy : 1.0f;

        const float sshf = qp<QP_2323>(sa);
        const float s5s  = qp<QP_B1>(sb);
        const float tsel = (m == 2) ? tx : (m == 3) ? ty : 0.0f;
        const float spa = fmaf(Bspa, sshf, fmaf(Aspa, sa, -DTf * tsel));
        const float spb = fmaf(Bspb, s5s, Aspb * sb);

        float Aa[6], Ab[6];
#pragma unroll
        for (int j = 0; j < 6; j++) {
          const float t1 = qp<QP_2323>(Pa[j]);
          const float t2 = qp<QP_B1>(Pb[j]);
          Aa[j] = fmaf(da, t1, ca * Pa[j]);
          Ab[j] = fmaf(db, t2, cb * Pb[j]);
        }
        float Ppa[6], Ppb[6];
        Ppa[0] = fmaf(DTc, Aa[2], Aa[0]) + qma[0];
        Ppa[1] = fmaf(DTc, Aa[3], Aa[1]) + qma[1];
        Ppa[2] = fmaf(gx, Aa[2], qma[2]);
        Ppa[3] = fmaf(gy, Aa[3], qma[3]);
        Ppa[4] = fmaf(DTc, Aa[5], Aa[4]) + qma[4];
        Ppa[5] = fmaf(dcoef, Aa[5], qma[5]);
        Ppb[0] = fmaf(DTc, Ab[2], Ab[0]) + qmb[0];
        Ppb[1] = fmaf(DTc, Ab[3], Ab[1]) + qmb[1];
        Ppb[2] = fmaf(gx, Ab[2], qmb[2]);
        Ppb[3] = fmaf(gy, Ab[3], qmb[3]);
        Ppb[4] = fmaf(DTc, Ab[5], Ab[4]) + qmb[4];
        Ppb[5] = fmaf(dcoef, Ab[5], qmb[5]);

        const float Sa = qp<QP_B0>(Ppa[0]) + r0;
        const float Sbv = qp<QP_B0>(Ppa[1]);
        const float Scv = qp<QP_B0>(Ppa[4]);
        const float Sd = qp<QP_B1>(Ppa[1]) + r1;
        const float Se = qp<QP_B1>(Ppa[4]);
        const float Sf = qp<QP_B0>(Ppb[4]) + r2;
        const float C00 = Sd * Sf - Se * Se;
        const float C01 = Scv * Se - Sbv * Sf;
        const float C02 = Sbv * Se - Sd * Scv;
        const float det = Sa * C00 + Sbv * C01 + Scv * C02;
        const float idet = frcp(det);
        const float Si00 = C00 * idet, Si01 = C01 * idet, Si02 = C02 * idet;
        const float Si11 = (Sa * Sf - Scv * Scv) * idet;
        const float Si12 = (Sbv * Scv - Sa * Se) * idet;
        const float Si22 = (Sa * Sd - Sbv * Sbv) * idet;

        const float Ka0 = Ppa[0] * Si00 + Ppa[1] * Si01 + Ppa[4] * Si02;
        const float Ka1 = Ppa[0] * Si01 + Ppa[1] * Si11 + Ppa[4] * Si12;
        const float Ka2 = Ppa[0] * Si02 + Ppa[1] * Si12 + Ppa[4] * Si22;
        const float Kb0 = Ppb[0] * Si00 + Ppb[1] * Si01 + Ppb[4] * Si02;
        const float Kb1 = Ppb[0] * Si01 + Ppb[1] * Si11 + Ppb[4] * Si12;
        const float Kb2 = Ppb[0] * Si02 + Ppb[1] * Si12 + Ppb[4] * Si22;

        const float sp0 = qp<QP_B0>(spa);
        const float sp1 = qp<QP_B1>(spa);
        const float sp4 = qp<QP_B0>(spb);
        const float i0 = z0 - sp0;
        const float i1 = z1 - sp1;
        float ia = z2 - sp4;
        ia = ia - TWO_PIc * rintf(ia * (1.0f / TWO_PIc));

        sa = spa + Ka0 * i0 + Ka1 * i1 + Ka2 * ia;
        sb = spb + Kb0 * i0 + Kb1 * i1 + Kb2 * ia;

#pragma unroll
        for (int j = 0; j < 6; j++) {
          const float p0 = qp<QP_B0>(Ppa[j]);
          const float p1 = qp<QP_B1>(Ppa[j]);
          const float p4 = qp<QP_B0>(Ppb[j]);
          Pa[j] = Ppa[j] - (Ka0 * p0 + Ka1 * p1 + Ka2 * p4);
          Pb[j] = Ppb[j] - (Kb0 * p0 + Kb1 * p1 + Kb2 * p4);
        }

        // compact 10-plane store
        float* __restrict__ hc = hist + ((size_t)t * NB + blk) * 160 + l;
        hc[0] = sa;
        hc[16] = sb;
#pragma unroll
        for (int j = 0; j < 6; j++) hc[(2 + j) * 16] = Pa[j];
        hc[128] = Pb[4];
        hc[144] = Pb[5];

        zl = zln;
      }
    }
  }

  __syncthreads();  // fwd stores -> bwd loads (block-local)

  // ================= Section B: backward =====================================
  const int c = l & (NC - 1);
  const int sl = l >> 4;
  const int seq = blk * 4 + sl;
  const int lo = c * 8;
  const int hi = (c == NC - 1) ? (T - 2) : (lo + 7);
  const float* __restrict__ zs = z + (size_t)seq * T * 3;
  float* __restrict__ myop = &lops[l * OPS];
  float* __restrict__ myproj = proj + (size_t)blk * (8 * PRJ * 64) + l;

  // ---- phase 1: build chunk op with hist prefetch; emit loss projections ----
  float QG[36], Qb[6], QC[36];
  HistPref hp;
  hist_pref(hist, hi, blk, sl, hp);

#pragma unroll 1
  for (int n = hi; n >= lo; --n) {
    float s_f[6], Pf[6][6];
    hist_unpack(hp, s_f, Pf);
    if (n > lo) hist_pref(hist, n - 1, blk, sl, hp);  // overlap with compute

    float sp[6], X[6][6], gx, gy;
    rts_core(s_f, Pf, friction, damping, dcoef, q, sp, X, gx, gy);
    // G_n[i][j] = X[j][i]

    float Gn[36], bn[6], Cn[36];
#pragma unroll
    for (int i = 0; i < 6; i++) {
      float v = s_f[i];
#pragma unroll
      for (int j = 0; j < 6; j++) {
        Gn[i * 6 + j] = X[j][i];
        v -= X[j][i] * sp[j];
      }
      bn[i] = v;
    }
#pragma unroll
    for (int i = 0; i < 6; i++) {
      float w[6];
      w[0] = Pf[0][i] + DTc * Pf[2][i];
      w[1] = Pf[1][i] + DTc * Pf[3][i];
      w[2] = gx * Pf[2][i];
      w[3] = gy * Pf[3][i];
      w[4] = Pf[4][i] + DTc * Pf[5][i];
      w[5] = dcoef * Pf[5][i];
#pragma unroll
      for (int j = i; j < 6; j++) {
        float v = Pf[i][j];
#pragma unroll
        for (int k = 0; k < 6; k++) v -= w[k] * X[k][j];
        Cn[i * 6 + j] = v;
        Cn[j * 6 + i] = v;
      }
    }

    if (n == hi) {
#pragma unroll
      for (int k = 0; k < 36; k++) { QG[k] = Gn[k]; QC[k] = Cn[k]; }
#pragma unroll
      for (int k = 0; k < 6; k++) Qb[k] = bn[k];
    } else {
      compose_op(Gn, bn, Cn, QG, Qb, QC, QG, Qb, QC);
    }

    // emit loss projection of q_n = op_n o ... o op_hi (rows {0,1,4})
    if (n >= 2) {
      float pr[PRJ];
#pragma unroll
      for (int j = 0; j < 6; j++) {
        pr[j] = QG[j];
        pr[6 + j] = QG[6 + j];
        pr[12 + j] = QG[24 + j];
      }
      pr[18] = Qb[0]; pr[19] = Qb[1]; pr[20] = Qb[4];
      pr[21] = QC[0]; pr[22] = QC[1]; pr[23] = QC[4];
      pr[24] = QC[7]; pr[25] = QC[10]; pr[26] = QC[28];
      const int idx = n - lo;
#pragma unroll
      for (int k = 0; k < PRJ; k++) myproj[(size_t)(idx * PRJ + k) * 64] = pr[k];
    }
  }

  // write own chunk op to LDS
#pragma unroll
  for (int k = 0; k < 36; k++) { myop[k] = QG[k]; myop[42 + k] = QC[k]; }
#pragma unroll
  for (int k = 0; k < 6; k++) myop[36 + k] = Qb[k];
  __syncthreads();

  // ---- phase 2: Kogge-Stone inclusive suffix scan over 16 chunk ops ----
#pragma unroll 1
  for (int r = 1; r < NC; r <<= 1) {
    float PG[36], Pb2[6], PC[36];
    const bool act = (c + r) < NC;
    if (act) {
      const float* __restrict__ p = &lops[(l + r) * OPS];
#pragma unroll
      for (int k = 0; k < 36; k++) { PG[k] = p[k]; PC[k] = p[42 + k]; }
#pragma unroll
      for (int k = 0; k < 6; k++) Pb2[k] = p[36 + k];
    }
    __syncthreads();
    if (act) compose_op(QG, Qb, QC, PG, Pb2, PC, QG, Qb, QC);
#pragma unroll
    for (int k = 0; k < 36; k++) { myop[k] = QG[k]; myop[42 + k] = QC[k]; }
#pragma unroll
    for (int k = 0; k < 6; k++) myop[36 + k] = Qb[k];
    __syncthreads();
  }

  // ---- phase 3: entry state; apply stored projections + loss ----
  float st[6], Pt[6][6];
  {
    HistPref hq;
    hist_pref(hist, T - 1, blk, sl, hq);
    hist_unpack(hq, st, Pt);
  }

  float sE[6], PE[6][6];
  float loss = 0.0f;

  if (c < NC - 1) {
    const float* __restrict__ p = &lops[(l + 1) * OPS];
    float EG[36], Eb[6], EC[36];
#pragma unroll
    for (int k = 0; k < 36; k++) { EG[k] = p[k]; EC[k] = p[42 + k]; }
#pragma unroll
    for (int k = 0; k < 6; k++) Eb[k] = p[36 + k];

#pragma unroll
    for (int i = 0; i < 6; i++) {
      float v = Eb[i];
#pragma unroll
      for (int j = 0; j < 6; j++) v += EG[i * 6 + j] * st[j];
      sE[i] = v;
    }
    float Y[6][6];
#pragma unroll
    for (int i = 0; i < 6; i++)
#pragma unroll
      for (int k = 0; k < 6; k++) {
        float v = 0.0f;
#pragma unroll
        for (int j = 0; j < 6; j++) v += EG[i * 6 + j] * Pt[j][k];
        Y[i][k] = v;
      }
#pragma unroll
    for (int i = 0; i < 6; i++)
#pragma unroll
      for (int j = i; j < 6; j++) {
        float v = EC[i * 6 + j];
#pragma unroll
        for (int k = 0; k < 6; k++) v += Y[i][k] * EG[j * 6 + k];
        PE[i][j] = v;
        PE[j][i] = v;
      }
  } else {
#pragma unroll
    for (int i = 0; i < 6; i++) {
      sE[i] = st[i];
#pragma unroll
      for (int j = 0; j < 6; j++) PE[i][j] = Pt[i][j];
    }
    loss = loss_term(Pt, st, zs[(T - 1) * 3 + 0], zs[(T - 1) * 3 + 1],
                     zs[(T - 1) * 3 + 2], r0, r1, r2);
  }

  const int lo2 = (c == 0) ? 2 : lo;

  // prefetch first projection + z
  float pr[PRJ], zz0, zz1, zz2;
  {
    const int idx = hi - lo;
#pragma unroll
    for (int k = 0; k < PRJ; k++) pr[k] = myproj[(size_t)(idx * PRJ + k) * 64];
    zz0 = zs[hi * 3 + 0];
    zz1 = zs[hi * 3 + 1];
    zz2 = zs[hi * 3 + 2];
  }

#pragma unroll 1
  for (int n = hi; n >= lo2; --n) {
    // consume current, issue next iteration's loads
    float cpr[PRJ];
#pragma unroll
    for (int k = 0; k < PRJ; k++) cpr[k] = pr[k];
    const float cz0 = zz0, cz1 = zz1, cz2 = zz2;
    if (n > lo2) {
      const int idx = n - 1 - lo;
#pragma unroll
      for (int k = 0; k < PRJ; k++) pr[k] = myproj[(size_t)(idx * PRJ + k) * 64];
      zz0 = zs[(n - 1) * 3 + 0];
      zz1 = zs[(n - 1) * 3 + 1];
      zz2 = zs[(n - 1) * 3 + 2];
    }

    float sv0 = cpr[18], sv1 = cpr[19], sv4 = cpr[20];
#pragma unroll
    for (int j = 0; j < 6; j++) {
      sv0 += cpr[j] * sE[j];
      sv1 += cpr[6 + j] * sE[j];
      sv4 += cpr[12 + j] * sE[j];
    }
    float Y0[6], Y1[6], Y2[6];
#pragma unroll
    for (int k = 0; k < 6; k++) {
      float y0 = 0.f, y1 = 0.f, y2 = 0.f;
#pragma unroll
      for (int j = 0; j < 6; j++) {
        y0 += cpr[j] * PE[j][k];
        y1 += cpr[6 + j] * PE[j][k];
        y2 += cpr[12 + j] * PE[j][k];
      }
      Y0[k] = y0; Y1[k] = y1; Y2[k] = y2;
    }
    float a = cpr[21] + r0, b = cpr[22], cc = cpr[23];
    float d = cpr[24] + r1, e = cpr[25], f = cpr[26] + r2;
#pragma unroll
    for (int k = 0; k < 6; k++) {
      a += Y0[k] * cpr[k];
      b += Y0[k] * cpr[6 + k];
      cc += Y0[k] * cpr[12 + k];
      d += Y1[k] * cpr[6 + k];
      e += Y1[k] * cpr[12 + k];
      f += Y2[k] * cpr[12 + k];
    }
    const float detv = a * (d * f - e * e) + b * (cc * e - b * f) +
                       cc * (b * e - d * cc);
    const float e0 = cz0 - sv0, e1 = cz1 - sv1;
    float aa = cz2 - sv4;
    if (aa >  PI_1_5) aa -= TWO_PIc;
    if (aa < -PI_1_5) aa += TWO_PIc;
    const float quad = a * e0 * e0 + d * e1 * e1 + f * aa * aa +
                       2.0f * (b * e0 * e1 + cc * e0 * aa + e * e1 * aa);
    loss += detv + quad;
  }

  // ---- reduce + atomic ----
#pragma unroll
  for (int off = 32; off > 0; off >>= 1) loss += __shfl_down(loss, off);
  if (l == 0) atomicAdd(out, loss);
}

}  // namespace

extern "C" void kernel_launch(void* const* d_in, const int* in_sizes, int n_in,
                              void* d_out, int out_size, void* d_ws, size_t ws_size,
                              hipStream_t stream) {
  const float* params      = (const float*)d_in[0];
  const float* covp        = (const float*)d_in[1];
  const float* init_states = (const float*)d_in[2];
  const float* z           = (const float*)d_in[3];
  float* out = (float*)d_out;

  const size_t histF = (size_t)T * NB * 160;         // 83.9 MB
  const size_t projF = (size_t)NB * 8 * PRJ * 64;    // 56.6 MB
  const size_t needBytes = (histF + projF) * sizeof(float);

  hipMemsetAsync(d_out, 0, sizeof(float), stream);

  if (ws_size >= needBytes) {
    float* hist = (float*)d_ws;
    float* prj  = hist + histF;
    fused_kernel<<<NB, 64, 0, stream>>>(params, covp, init_states, z, hist,
                                        prj, out);
  }
}

// Round 9
// 173.811 us; speedup vs baseline: 3.0554x; 1.0714x over previous
//
#include <hip/hip_runtime.h>
#include <cmath>

// Kalman_Smooth_Gradient: B=4096 seqs, T=128 steps, 6-state EKF + RTS + loss.
// Round 9: EXACT FACTORIZATION. In ordering (x,dx),(y,dy),(th,dth):
//   F block-diagonal (2x2/pair), Q,R diagonal, H one component/pair, P0=0.01I
//   => P stays block-diagonal forever; the 6x6 EKF+RTS = three independent
//   2-state Kalman smoothers. S is scalar, Pp^{-1} closed-form 2x2, loss
//   couples filters only via det(Sv)=ax*ay*at (Sv diagonal) and additive quads.
//
// One kernel: grid 64 blocks x 192 thr (3 waves: wave f = filter f, 64 seqs).
// Per thread: serial fwd (store p,v,P00,P01 float4 + P11 float, coalesced),
// serial bwd emitting (a, a*e^2) float2 per step to scratch; __syncthreads;
// block epilogue combines the 3 filters per (seq,n), reduces, one atomicAdd.

namespace {

constexpr int B = 4096;
constexpr int T = 128;
constexpr int SPB = 64;             // seqs per block
constexpr int NBLK = B / SPB;       // 64 blocks
constexpr int NTH = 3 * SPB;        // 192 threads per block
constexpr int NT = B * 3;           // 12288 filter-threads total
constexpr float DTc     = 1.0f / 120.0f;
constexpr float TWO_PIc = 6.28318530717958647692f;
constexpr float PI_1_5  = 4.71238898038468985769f;
constexpr float INV_2PI = 0.15915494309189533577f;

__device__ __forceinline__ float frcp(float x) { return __builtin_amdgcn_rcpf(x); }

__device__ __forceinline__ float fast_tanh(float x) {
  float e = __expf(2.0f * x);
  return 1.0f - 2.0f * frcp(e + 1.0f);
}
__device__ __forceinline__ float sigmoidf(float x) {
  return frcp(1.0f + __expf(-x));
}

// ---------------------------------------------------------------------------
// Fused kernel. hist4: [T][NT] float4 (p,v,P00,P01); hist1: [T][NT] float P11;
// aq: [T][NT] float2 (a, a*e^2), valid n = 2..T-1.
// ---------------------------------------------------------------------------
__global__ __launch_bounds__(NTH, 1) void fused_kernel(
    const float* __restrict__ params, const float* __restrict__ covp,
    const float* __restrict__ init_states, const float* __restrict__ z,
    float4* __restrict__ hist4, float* __restrict__ hist1,
    float2* __restrict__ aq, float* __restrict__ out) {
  const int tid = threadIdx.x;
  const int f = tid >> 6;           // filter 0=x,1=y,2=theta (wave-uniform)
  const int sb = tid & 63;          // seq within block
  const int blk = blockIdx.x;
  const int seq = blk * SPB + sb;
  const int gid = blk * NTH + tid;  // global filter-thread id

  // ---- shared scalars ----
  const float friction = (fast_tanh(params[0]) + 1.0f) * 0.01f;
  const float damping  = (fast_tanh(params[1]) + 1.0f) * 0.01f;
  float cp[7];
#pragma unroll
  for (int i = 0; i < 7; i++) cp[i] = sigmoidf(covp[i]);
  const float dcoef = 1.0f - DTc * damping;
  const bool isTH = (f == 2);                 // wave-uniform branch
  const float q0 = isTH ? cp[5] : cp[3];
  const float q1 = isTH ? cp[6] : cp[4];
  const float r  = cp[f];

  // ---- init (state pair (p,v) = (pos, vel) of this filter) ----
  const int pidx = (f == 0) ? 0 : (f == 1) ? 1 : 4;
  const int vidx = (f == 0) ? 2 : (f == 1) ? 3 : 5;
  float p = init_states[seq * 6 + pidx];
  float v = init_states[seq * 6 + vidx];
  float P00 = 0.01f, P01 = 0.0f, P11 = 0.01f;

  const float* __restrict__ zp = z + (size_t)seq * (T * 3) + f;  // stride 3

  // =========================== forward ===========================
  float zc = zp[0];
#pragma unroll 1
  for (int t = 0; t < T; t++) {
    const float zn = (t < T - 1) ? zp[(t + 1) * 3] : 0.0f;  // prefetch

    float g, tv;
    if (!isTH) {
      const float th = fast_tanh(100.0f * v);
      tv = v - DTc * (damping * v + friction * th);
      g = 1.0f - DTc * (damping + 100.0f * friction * (1.0f - th * th));
    } else {
      tv = dcoef * v;
      g = dcoef;
    }
    const float tp = p + DTc * v;
    const float u = P01 + DTc * P11;
    const float Pp00 = P00 + DTc * P01 + DTc * u + q0;
    const float Pp01 = g * u;
    const float Pp11 = g * (g * P11) + q1;
    const float iS = frcp(Pp00 + r);
    const float K0 = Pp00 * iS;
    const float K1 = Pp01 * iS;
    float e = zc - tp;
    if (isTH) e = e - TWO_PIc * rintf(e * INV_2PI);  // _wrap
    p = tp + K0 * e;
    v = tv + K1 * e;
    const float om = 1.0f - K0;
    P00 = om * Pp00;
    P01 = om * Pp01;
    P11 = Pp11 - K1 * Pp01;

    hist4[(size_t)t * NT + gid] = make_float4(p, v, P00, P01);
    hist1[(size_t)t * NT + gid] = P11;
    zc = zn;
  }

  // ---- terminal loss term n = T-1 (smoothed == filtered) ----
  {
    const float zl = zp[(T - 1) * 3];
    float e = zl - p;
    if (isTH) {
      if (e >  PI_1_5) e -= TWO_PIc;
      if (e < -PI_1_5) e += TWO_PIc;
    }
    const float a = P00 + r;
    aq[(size_t)(T - 1) * NT + gid] = make_float2(a, a * e * e);
  }

  // =========================== backward ===========================
  // carry = smoothed at n+1; init with filtered at T-1 (already in regs)
  float sp_ = p, sv_ = v, Ps00 = P00, Ps01 = P01, Ps11 = P11;

  // prefetch hist(126) + z(126)
  float4 h4 = hist4[(size_t)(T - 2) * NT + gid];
  float h1 = hist1[(size_t)(T - 2) * NT + gid];
  float zpr = zp[(T - 2) * 3];

#pragma unroll 1
  for (int n = T - 2; n >= 2; --n) {
    const float fp = h4.x, fv = h4.y, f00 = h4.z, f01 = h4.w, f11 = h1;
    const float zn_ = zpr;
    if (n > 2) {  // prefetch next (n-1) while computing
      h4 = hist4[(size_t)(n - 1) * NT + gid];
      h1 = hist1[(size_t)(n - 1) * NT + gid];
      zpr = zp[(n - 1) * 3];
    }

    // recompute prediction at n+1 from filtered(n)
    float g, tv;
    if (!isTH) {
      const float th = fast_tanh(100.0f * fv);
      tv = fv - DTc * (damping * fv + friction * th);
      g = 1.0f - DTc * (damping + 100.0f * friction * (1.0f - th * th));
    } else {
      tv = dcoef * fv;
      g = dcoef;
    }
    const float tp = fp + DTc * fv;
    const float u = f01 + DTc * f11;
    const float Pp00 = f00 + DTc * f01 + DTc * u + q0;
    const float Pp01 = g * u;
    const float Pp11 = g * (g * f11) + q1;

    // G = P_f F^T Pp^{-1} (closed-form 2x2)
    const float idet = frcp(Pp00 * Pp11 - Pp01 * Pp01);
    const float W00 = f00, W01 = DTc * f00 + g * f01;
    const float W10 = f01, W11 = DTc * f01 + g * f11;
    const float G00 = (W00 * Pp11 - W01 * Pp01) * idet;
    const float G01 = (W01 * Pp00 - W00 * Pp01) * idet;
    const float G10 = (W10 * Pp11 - W11 * Pp01) * idet;
    const float G11 = (W11 * Pp00 - W10 * Pp01) * idet;

    const float ds0 = sp_ - tp, ds1 = sv_ - tv;
    const float np = fp + G00 * ds0 + G01 * ds1;
    const float nv = fv + G10 * ds0 + G11 * ds1;

    const float M00 = Ps00 - Pp00, M01 = Ps01 - Pp01, M11 = Ps11 - Pp11;
    const float GM00 = G00 * M00 + G01 * M01, GM01 = G00 * M01 + G01 * M11;
    const float GM10 = G10 * M00 + G11 * M01, GM11 = G10 * M01 + G11 * M11;
    Ps00 = f00 + GM00 * G00 + GM01 * G01;
    Ps01 = f01 + GM00 * G10 + GM01 * G11;
    Ps11 = f11 + GM10 * G10 + GM11 * G11;
    sp_ = np;
    sv_ = nv;

    const float a = Ps00 + r;
    float e = zn_ - np;
    if (isTH) {
      if (e >  PI_1_5) e -= TWO_PIc;
      if (e < -PI_1_5) e += TWO_PIc;
    }
    aq[(size_t)n * NT + gid] = make_float2(a, a * e * e);
  }

  __syncthreads();  // aq stores -> epilogue loads (same block/CU)

  // =========================== epilogue ===========================
  // 64 seqs x 126 loss terms (n=2..127) = 8064 pairs; 42 per thread.
  float part = 0.0f;
  const int base = blk * NTH;  // gid of (this block, filter 0, sb 0)
#pragma unroll 1
  for (int k = 0; k < 42; k++) {
    const int pi = tid + k * NTH;       // 0..8063
    const int s2 = pi & 63;
    const int n2 = 2 + (pi >> 6);       // 2..127
    const size_t o = (size_t)n2 * NT + base + s2;
    const float2 x0 = aq[o];
    const float2 x1 = aq[o + 64];
    const float2 x2 = aq[o + 128];
    part += x0.x * x1.x * x2.x + (x0.y + x1.y + x2.y);
  }

  // wave reduce + cross-wave via LDS + one atomic per block
#pragma unroll
  for (int off = 32; off > 0; off >>= 1) part += __shfl_down(part, off);
  __shared__ float red[3];
  if ((tid & 63) == 0) red[tid >> 6] = part;
  __syncthreads();
  if (tid == 0) atomicAdd(out, red[0] + red[1] + red[2]);
}

}  // namespace

extern "C" void kernel_launch(void* const* d_in, const int* in_sizes, int n_in,
                              void* d_out, int out_size, void* d_ws, size_t ws_size,
                              hipStream_t stream) {
  const float* params      = (const float*)d_in[0];
  const float* covp        = (const float*)d_in[1];
  const float* init_states = (const float*)d_in[2];
  const float* z           = (const float*)d_in[3];
  float* out = (float*)d_out;

  const size_t hist4B = (size_t)T * NT * sizeof(float4);  // 25.2 MB
  const size_t hist1B = (size_t)T * NT * sizeof(float);   //  6.3 MB
  const size_t aqB    = (size_t)T * NT * sizeof(float2);  // 12.6 MB
  const size_t needBytes = hist4B + hist1B + aqB;         // 44.1 MB

  hipMemsetAsync(d_out, 0, sizeof(float), stream);

  if (ws_size >= needBytes) {
    float4* hist4 = (float4*)d_ws;
    float*  hist1 = (float*)((char*)d_ws + hist4B);
    float2* aqp   = (float2*)((char*)d_ws + hist4B + hist1B);
    fused_kernel<<<NBLK, NTH, 0, stream>>>(params, covp, init_states, z,
                                           hist4, hist1, aqp, out);
  }
}

// Round 10
// 125.624 us; speedup vs baseline: 4.2274x; 1.3836x over previous
//
#include <hip/hip_runtime.h>
#include <cmath>

// Kalman_Smooth_Gradient: B=4096 seqs, T=128 steps, 6-state EKF + RTS + loss.
// Round 10: round-9 exact factorization (three independent 2-state filters;
// P block-diagonal forever; S scalar; det(Sv)=ax*ay*at) + DEEP (distance-4)
// software prefetch pipelines in fwd/bwd/epilogue to cover L2/L3 latency at
// 1 wave/SIMD.
//
// One kernel: grid 64 blocks x 192 thr (wave f = filter f, 64 seqs).
// Per thread: serial fwd (store p,v,P00,P01 float4 + P11, coalesced), serial
// bwd (closed-form 2x2 RTS) emitting (a, a*e^2) float2 per step; __syncthreads;
// block epilogue combines the 3 filters per (seq,n), reduces, one atomicAdd.

namespace {

constexpr int B = 4096;
constexpr int T = 128;
constexpr int SPB = 64;             // seqs per block
constexpr int NBLK = B / SPB;       // 64 blocks
constexpr int NTH = 3 * SPB;        // 192 threads per block
constexpr int NT = B * 3;           // 12288 filter-threads total
constexpr float DTc     = 1.0f / 120.0f;
constexpr float TWO_PIc = 6.28318530717958647692f;
constexpr float PI_1_5  = 4.71238898038468985769f;
constexpr float INV_2PI = 0.15915494309189533577f;

__device__ __forceinline__ float frcp(float x) { return __builtin_amdgcn_rcpf(x); }

__device__ __forceinline__ float fast_tanh(float x) {
  float e = __expf(2.0f * x);
  return 1.0f - 2.0f * frcp(e + 1.0f);
}
__device__ __forceinline__ float sigmoidf(float x) {
  return frcp(1.0f + __expf(-x));
}

// ---------------------------------------------------------------------------
// Fused kernel. hist4: [T][NT] float4 (p,v,P00,P01); hist1: [T][NT] float P11;
// aq: [T][NT] float2 (a, a*e^2), valid n = 2..T-1.
// ---------------------------------------------------------------------------
__global__ __launch_bounds__(NTH, 1) void fused_kernel(
    const float* __restrict__ params, const float* __restrict__ covp,
    const float* __restrict__ init_states, const float* __restrict__ z,
    float4* __restrict__ hist4, float* __restrict__ hist1,
    float2* __restrict__ aq, float* __restrict__ out) {
  const int tid = threadIdx.x;
  const int f = tid >> 6;           // filter 0=x,1=y,2=theta (wave-uniform)
  const int sb = tid & 63;          // seq within block
  const int blk = blockIdx.x;
  const int seq = blk * SPB + sb;
  const int gid = blk * NTH + tid;  // global filter-thread id

  // ---- shared scalars ----
  const float friction = (fast_tanh(params[0]) + 1.0f) * 0.01f;
  const float damping  = (fast_tanh(params[1]) + 1.0f) * 0.01f;
  float cp[7];
#pragma unroll
  for (int i = 0; i < 7; i++) cp[i] = sigmoidf(covp[i]);
  const float dcoef = 1.0f - DTc * damping;
  const bool isTH = (f == 2);                 // wave-uniform branch
  const float q0 = isTH ? cp[5] : cp[3];
  const float q1 = isTH ? cp[6] : cp[4];
  const float r  = cp[f];

  // ---- init ----
  const int pidx = (f == 0) ? 0 : (f == 1) ? 1 : 4;
  const int vidx = (f == 0) ? 2 : (f == 1) ? 3 : 5;
  float p = init_states[seq * 6 + pidx];
  float v = init_states[seq * 6 + vidx];
  float P00 = 0.01f, P01 = 0.0f, P11 = 0.01f;

  const float* __restrict__ zp = z + (size_t)seq * (T * 3) + f;  // stride 3

  // =========================== forward ===========================
  float zb[4];
#pragma unroll
  for (int i = 0; i < 4; i++) zb[i] = zp[i * 3];

#pragma unroll 4
  for (int t = 0; t < T; t++) {
    const int sl4 = t & 3;
    const float zc = zb[sl4];
    const int tf = (t + 4 < T) ? (t + 4) : (T - 1);  // clamped prefetch
    zb[sl4] = zp[tf * 3];

    float g, tv;
    if (!isTH) {
      const float th = fast_tanh(100.0f * v);
      tv = v - DTc * (damping * v + friction * th);
      g = 1.0f - DTc * (damping + 100.0f * friction * (1.0f - th * th));
    } else {
      tv = dcoef * v;
      g = dcoef;
    }
    const float tp = p + DTc * v;
    const float u = P01 + DTc * P11;
    const float Pp00 = P00 + DTc * P01 + DTc * u + q0;
    const float Pp01 = g * u;
    const float Pp11 = g * (g * P11) + q1;
    const float iS = frcp(Pp00 + r);
    const float K0 = Pp00 * iS;
    const float K1 = Pp01 * iS;
    float e = zc - tp;
    if (isTH) e = e - TWO_PIc * rintf(e * INV_2PI);  // _wrap
    p = tp + K0 * e;
    v = tv + K1 * e;
    const float om = 1.0f - K0;
    P00 = om * Pp00;
    P01 = om * Pp01;
    P11 = Pp11 - K1 * Pp01;

    hist4[(size_t)t * NT + gid] = make_float4(p, v, P00, P01);
    hist1[(size_t)t * NT + gid] = P11;
  }

  // ---- terminal loss term n = T-1 (smoothed == filtered) ----
  {
    const float zl = zp[(T - 1) * 3];
    float e = zl - p;
    if (isTH) {
      if (e >  PI_1_5) e -= TWO_PIc;
      if (e < -PI_1_5) e += TWO_PIc;
    }
    const float a = P00 + r;
    aq[(size_t)(T - 1) * NT + gid] = make_float2(a, a * e * e);
  }

  // =========================== backward ===========================
  // carry = smoothed at n+1; init with filtered at T-1 (already in regs)
  float sp_ = p, sv_ = v, Ps00 = P00, Ps01 = P01, Ps11 = P11;

  // distance-4 rolling prefetch buffers; iteration i -> n = 126 - i (125 iters)
  float4 h4b[4];
  float h1b[4], zbb[4];
#pragma unroll
  for (int i = 0; i < 4; i++) {
    const int n2 = 126 - i;
    h4b[i] = hist4[(size_t)n2 * NT + gid];
    h1b[i] = hist1[(size_t)n2 * NT + gid];
    zbb[i] = zp[n2 * 3];
  }

#pragma unroll 4
  for (int i = 0; i < 125; i++) {
    const int n = 126 - i;
    const int sl4 = i & 3;
    const float4 h4 = h4b[sl4];
    const float h1 = h1b[sl4];
    const float zn_ = zbb[sl4];
    const int nf = (n >= 6) ? (n - 4) : 2;  // clamped prefetch target
    h4b[sl4] = hist4[(size_t)nf * NT + gid];
    h1b[sl4] = hist1[(size_t)nf * NT + gid];
    zbb[sl4] = zp[nf * 3];

    const float fp = h4.x, fv = h4.y, f00 = h4.z, f01 = h4.w, f11 = h1;

    // recompute prediction at n+1 from filtered(n)
    float g, tv;
    if (!isTH) {
      const float th = fast_tanh(100.0f * fv);
      tv = fv - DTc * (damping * fv + friction * th);
      g = 1.0f - DTc * (damping + 100.0f * friction * (1.0f - th * th));
    } else {
      tv = dcoef * fv;
      g = dcoef;
    }
    const float tp = fp + DTc * fv;
    const float u = f01 + DTc * f11;
    const float Pp00 = f00 + DTc * f01 + DTc * u + q0;
    const float Pp01 = g * u;
    const float Pp11 = g * (g * f11) + q1;

    // G = P_f F^T Pp^{-1} (closed-form 2x2)
    const float idet = frcp(Pp00 * Pp11 - Pp01 * Pp01);
    const float W00 = f00, W01 = DTc * f00 + g * f01;
    const float W10 = f01, W11 = DTc * f01 + g * f11;
    const float G00 = (W00 * Pp11 - W01 * Pp01) * idet;
    const float G01 = (W01 * Pp00 - W00 * Pp01) * idet;
    const float G10 = (W10 * Pp11 - W11 * Pp01) * idet;
    const float G11 = (W11 * Pp00 - W10 * Pp01) * idet;

    const float ds0 = sp_ - tp, ds1 = sv_ - tv;
    const float np = fp + G00 * ds0 + G01 * ds1;
    const float nv = fv + G10 * ds0 + G11 * ds1;

    const float M00 = Ps00 - Pp00, M01 = Ps01 - Pp01, M11 = Ps11 - Pp11;
    const float GM00 = G00 * M00 + G01 * M01, GM01 = G00 * M01 + G01 * M11;
    const float GM10 = G10 * M00 + G11 * M01, GM11 = G10 * M01 + G11 * M11;
    Ps00 = f00 + GM00 * G00 + GM01 * G01;
    Ps01 = f01 + GM00 * G10 + GM01 * G11;
    Ps11 = f11 + GM10 * G10 + GM11 * G11;
    sp_ = np;
    sv_ = nv;

    const float a = Ps00 + r;
    float e = zn_ - np;
    if (isTH) {
      if (e >  PI_1_5) e -= TWO_PIc;
      if (e < -PI_1_5) e += TWO_PIc;
    }
    aq[(size_t)n * NT + gid] = make_float2(a, a * e * e);
  }

  __syncthreads();  // aq stores -> epilogue loads (same block/CU)

  // =========================== epilogue ===========================
  // 64 seqs x 126 loss terms (n=2..127) = 8064 pairs; 42 per thread.
  float part = 0.0f;
  const int base = blk * NTH;

  // distance-2 rolling prefetch
  float2 b0[2], b1[2], b2[2];
#pragma unroll
  for (int k = 0; k < 2; k++) {
    const int pi = tid + k * NTH;
    const size_t o = (size_t)(2 + (pi >> 6)) * NT + base + (pi & 63);
    b0[k] = aq[o];
    b1[k] = aq[o + 64];
    b2[k] = aq[o + 128];
  }

#pragma unroll 2
  for (int k = 0; k < 42; k++) {
    const int sl2 = k & 1;
    const float2 x0 = b0[sl2];
    const float2 x1 = b1[sl2];
    const float2 x2 = b2[sl2];
    const int kf = (k + 2 < 42) ? (k + 2) : k;  // clamped prefetch
    {
      const int pi = tid + kf * NTH;
      const size_t o = (size_t)(2 + (pi >> 6)) * NT + base + (pi & 63);
      b0[sl2] = aq[o];
      b1[sl2] = aq[o + 64];
      b2[sl2] = aq[o + 128];
    }
    part += x0.x * x1.x * x2.x + (x0.y + x1.y + x2.y);
  }

  // wave reduce + cross-wave via LDS + one atomic per block
#pragma unroll
  for (int off = 32; off > 0; off >>= 1) part += __shfl_down(part, off);
  __shared__ float red[3];
  if ((tid & 63) == 0) red[tid >> 6] = part;
  __syncthreads();
  if (tid == 0) atomicAdd(out, red[0] + red[1] + red[2]);
}

}  // namespace

extern "C" void kernel_launch(void* const* d_in, const int* in_sizes, int n_in,
                              void* d_out, int out_size, void* d_ws, size_t ws_size,
                              hipStream_t stream) {
  const float* params      = (const float*)d_in[0];
  const float* covp        = (const float*)d_in[1];
  const float* init_states = (const float*)d_in[2];
  const float* z           = (const float*)d_in[3];
  float* out = (float*)d_out;

  const size_t hist4B = (size_t)T * NT * sizeof(float4);  // 25.2 MB
  const size_t hist1B = (size_t)T * NT * sizeof(float);   //  6.3 MB
  const size_t aqB    = (size_t)T * NT * sizeof(float2);  // 12.6 MB
  const size_t needBytes = hist4B + hist1B + aqB;         // 44.1 MB

  hipMemsetAsync(d_out, 0, sizeof(float), stream);

  if (ws_size >= needBytes) {
    float4* hist4 = (float4*)d_ws;
    float*  hist1 = (float*)((char*)d_ws + hist4B);
    float2* aqp   = (float2*)((char*)d_ws + hist4B + hist1B);
    fused_kernel<<<NBLK, NTH, 0, stream>>>(params, covp, init_states, z,
                                           hist4, hist1, aqp, out);
  }
}

// Round 11
// 123.029 us; speedup vs baseline: 4.3166x; 1.0211x over previous
//
#include <hip/hip_runtime.h>
#include <cmath>

// Kalman_Smooth_Gradient: B=4096 seqs, T=128 steps, 6-state EKF + RTS + loss.
// Round 11: round-9/10 exact factorization (three independent 2-state filters)
// + DEPTH-8 software prefetch pipelines (fwd z, bwd hist4/hist1/z) and depth-4
// epilogue, with unroll matched to buffer depth so rolling slots const-fold
// into registers. Covers ~1000 cy of cold-HBM latency at 1 wave/SIMD.
//
// One kernel: grid 64 blocks x 192 thr (wave f = filter f, 64 seqs).
// Per thread: serial fwd (store p,v,P00,P01 float4 + P11, coalesced), serial
// bwd (closed-form 2x2 RTS) emitting (a, a*e^2) float2 per step; __syncthreads;
// block epilogue combines the 3 filters per (seq,n), reduces, one atomicAdd.

namespace {

constexpr int B = 4096;
constexpr int T = 128;
constexpr int SPB = 64;             // seqs per block
constexpr int NBLK = B / SPB;       // 64 blocks
constexpr int NTH = 3 * SPB;        // 192 threads per block
constexpr int NT = B * 3;           // 12288 filter-threads total
constexpr float DTc     = 1.0f / 120.0f;
constexpr float TWO_PIc = 6.28318530717958647692f;
constexpr float PI_1_5  = 4.71238898038468985769f;
constexpr float INV_2PI = 0.15915494309189533577f;

__device__ __forceinline__ float frcp(float x) { return __builtin_amdgcn_rcpf(x); }

__device__ __forceinline__ float fast_tanh(float x) {
  float e = __expf(2.0f * x);
  return 1.0f - 2.0f * frcp(e + 1.0f);
}
__device__ __forceinline__ float sigmoidf(float x) {
  return frcp(1.0f + __expf(-x));
}

// ---------------------------------------------------------------------------
// Fused kernel. hist4: [T][NT] float4 (p,v,P00,P01); hist1: [T][NT] float P11;
// aq: [T][NT] float2 (a, a*e^2), valid n = 2..T-1.
// ---------------------------------------------------------------------------
__global__ __launch_bounds__(NTH, 1) void fused_kernel(
    const float* __restrict__ params, const float* __restrict__ covp,
    const float* __restrict__ init_states, const float* __restrict__ z,
    float4* __restrict__ hist4, float* __restrict__ hist1,
    float2* __restrict__ aq, float* __restrict__ out) {
  const int tid = threadIdx.x;
  const int f = tid >> 6;           // filter 0=x,1=y,2=theta (wave-uniform)
  const int sb = tid & 63;          // seq within block
  const int blk = blockIdx.x;
  const int seq = blk * SPB + sb;
  const int gid = blk * NTH + tid;  // global filter-thread id

  // ---- shared scalars ----
  const float friction = (fast_tanh(params[0]) + 1.0f) * 0.01f;
  const float damping  = (fast_tanh(params[1]) + 1.0f) * 0.01f;
  float cp[7];
#pragma unroll
  for (int i = 0; i < 7; i++) cp[i] = sigmoidf(covp[i]);
  const float dcoef = 1.0f - DTc * damping;
  const bool isTH = (f == 2);                 // wave-uniform branch
  const float q0 = isTH ? cp[5] : cp[3];
  const float q1 = isTH ? cp[6] : cp[4];
  const float r  = cp[f];

  // ---- init ----
  const int pidx = (f == 0) ? 0 : (f == 1) ? 1 : 4;
  const int vidx = (f == 0) ? 2 : (f == 1) ? 3 : 5;
  float p = init_states[seq * 6 + pidx];
  float v = init_states[seq * 6 + vidx];
  float P00 = 0.01f, P01 = 0.0f, P11 = 0.01f;

  const float* __restrict__ zp = z + (size_t)seq * (T * 3) + f;  // stride 3

  // =========================== forward ===========================
  float zb[8];
#pragma unroll
  for (int i = 0; i < 8; i++) zb[i] = zp[i * 3];

#pragma unroll 8
  for (int t = 0; t < T; t++) {
    const int sl = t & 7;
    const float zc = zb[sl];
    const int tf = (t + 8 < T) ? (t + 8) : (T - 1);  // clamped prefetch
    zb[sl] = zp[tf * 3];

    float g, tv;
    if (!isTH) {
      const float th = fast_tanh(100.0f * v);
      tv = v - DTc * (damping * v + friction * th);
      g = 1.0f - DTc * (damping + 100.0f * friction * (1.0f - th * th));
    } else {
      tv = dcoef * v;
      g = dcoef;
    }
    const float tp = p + DTc * v;
    const float u = P01 + DTc * P11;
    const float Pp00 = P00 + DTc * P01 + DTc * u + q0;
    const float Pp01 = g * u;
    const float Pp11 = g * (g * P11) + q1;
    const float iS = frcp(Pp00 + r);
    const float K0 = Pp00 * iS;
    const float K1 = Pp01 * iS;
    float e = zc - tp;
    if (isTH) e = e - TWO_PIc * rintf(e * INV_2PI);  // _wrap
    p = tp + K0 * e;
    v = tv + K1 * e;
    const float om = 1.0f - K0;
    P00 = om * Pp00;
    P01 = om * Pp01;
    P11 = Pp11 - K1 * Pp01;

    hist4[(size_t)t * NT + gid] = make_float4(p, v, P00, P01);
    hist1[(size_t)t * NT + gid] = P11;
  }

  // ---- terminal loss term n = T-1 (smoothed == filtered) ----
  {
    const float zl = zp[(T - 1) * 3];
    float e = zl - p;
    if (isTH) {
      if (e >  PI_1_5) e -= TWO_PIc;
      if (e < -PI_1_5) e += TWO_PIc;
    }
    const float a = P00 + r;
    aq[(size_t)(T - 1) * NT + gid] = make_float2(a, a * e * e);
  }

  // =========================== backward ===========================
  // carry = smoothed at n+1; init with filtered at T-1 (already in regs)
  float sp_ = p, sv_ = v, Ps00 = P00, Ps01 = P01, Ps11 = P11;

  // depth-8 rolling prefetch; iteration i -> n = 126 - i. Loop padded to 128
  // iters (n = 126..-1); n < 2 iterations compute garbage but never store.
  float4 h4b[8];
  float h1b[8], zbb[8];
#pragma unroll
  for (int i = 0; i < 8; i++) {
    const int n2 = 126 - i;
    h4b[i] = hist4[(size_t)n2 * NT + gid];
    h1b[i] = hist1[(size_t)n2 * NT + gid];
    zbb[i] = zp[n2 * 3];
  }

#pragma unroll 8
  for (int i = 0; i < 128; i++) {
    const int n = 126 - i;
    const int sl = i & 7;
    const float4 h4 = h4b[sl];
    const float h1 = h1b[sl];
    const float zn_ = zbb[sl];
    const int nf = (n >= 10) ? (n - 8) : 2;  // clamped prefetch target
    h4b[sl] = hist4[(size_t)nf * NT + gid];
    h1b[sl] = hist1[(size_t)nf * NT + gid];
    zbb[sl] = zp[nf * 3];

    const float fp = h4.x, fv = h4.y, f00 = h4.z, f01 = h4.w, f11 = h1;

    // recompute prediction at n+1 from filtered(n)
    float g, tv;
    if (!isTH) {
      const float th = fast_tanh(100.0f * fv);
      tv = fv - DTc * (damping * fv + friction * th);
      g = 1.0f - DTc * (damping + 100.0f * friction * (1.0f - th * th));
    } else {
      tv = dcoef * fv;
      g = dcoef;
    }
    const float tp = fp + DTc * fv;
    const float u = f01 + DTc * f11;
    const float Pp00 = f00 + DTc * f01 + DTc * u + q0;
    const float Pp01 = g * u;
    const float Pp11 = g * (g * f11) + q1;

    // G = P_f F^T Pp^{-1} (closed-form 2x2)
    const float idet = frcp(Pp00 * Pp11 - Pp01 * Pp01);
    const float W00 = f00, W01 = DTc * f00 + g * f01;
    const float W10 = f01, W11 = DTc * f01 + g * f11;
    const float G00 = (W00 * Pp11 - W01 * Pp01) * idet;
    const float G01 = (W01 * Pp00 - W00 * Pp01) * idet;
    const float G10 = (W10 * Pp11 - W11 * Pp01) * idet;
    const float G11 = (W11 * Pp00 - W10 * Pp01) * idet;

    const float ds0 = sp_ - tp, ds1 = sv_ - tv;
    const float np = fp + G00 * ds0 + G01 * ds1;
    const float nv = fv + G10 * ds0 + G11 * ds1;

    const float M00 = Ps00 - Pp00, M01 = Ps01 - Pp01, M11 = Ps11 - Pp11;
    const float GM00 = G00 * M00 + G01 * M01, GM01 = G00 * M01 + G01 * M11;
    const float GM10 = G10 * M00 + G11 * M01, GM11 = G10 * M01 + G11 * M11;
    Ps00 = f00 + GM00 * G00 + GM01 * G01;
    Ps01 = f01 + GM00 * G10 + GM01 * G11;
    Ps11 = f11 + GM10 * G10 + GM11 * G11;
    sp_ = np;
    sv_ = nv;

    if (n >= 2) {
      const float a = Ps00 + r;
      float e = zn_ - np;
      if (isTH) {
        if (e >  PI_1_5) e -= TWO_PIc;
        if (e < -PI_1_5) e += TWO_PIc;
      }
      aq[(size_t)n * NT + gid] = make_float2(a, a * e * e);
    }
  }

  __syncthreads();  // aq stores -> epilogue loads (same block/CU)

  // =========================== epilogue ===========================
  // 64 seqs x 126 loss terms (n=2..127) = 8064 pairs; 42 per thread.
  float part = 0.0f;
  const int base = blk * NTH;

  // depth-4 rolling prefetch; padded to 44 iters (guarded accumulate)
  float2 b0[4], b1[4], b2[4];
#pragma unroll
  for (int k = 0; k < 4; k++) {
    const int pi = tid + k * NTH;
    const size_t o = (size_t)(2 + (pi >> 6)) * NT + base + (pi & 63);
    b0[k] = aq[o];
    b1[k] = aq[o + 64];
    b2[k] = aq[o + 128];
  }

#pragma unroll 4
  for (int k = 0; k < 44; k++) {
    const int sl = k & 3;
    const float2 x0 = b0[sl];
    const float2 x1 = b1[sl];
    const float2 x2 = b2[sl];
    const int kf = (k + 4 < 42) ? (k + 4) : 41;  // clamped prefetch
    {
      const int pi = tid + kf * NTH;
      const size_t o = (size_t)(2 + (pi >> 6)) * NT + base + (pi & 63);
      b0[sl] = aq[o];
      b1[sl] = aq[o + 64];
      b2[sl] = aq[o + 128];
    }
    if (k < 42) part += x0.x * x1.x * x2.x + (x0.y + x1.y + x2.y);
  }

  // wave reduce + cross-wave via LDS + one atomic per block
#pragma unroll
  for (int off = 32; off > 0; off >>= 1) part += __shfl_down(part, off);
  __shared__ float red[3];
  if ((tid & 63) == 0) red[tid >> 6] = part;
  __syncthreads();
  if (tid == 0) atomicAdd(out, red[0] + red[1] + red[2]);
}

}  // namespace

extern "C" void kernel_launch(void* const* d_in, const int* in_sizes, int n_in,
                              void* d_out, int out_size, void* d_ws, size_t ws_size,
                              hipStream_t stream) {
  const float* params      = (const float*)d_in[0];
  const float* covp        = (const float*)d_in[1];
  const float* init_states = (const float*)d_in[2];
  const float* z           = (const float*)d_in[3];
  float* out = (float*)d_out;

  const size_t hist4B = (size_t)T * NT * sizeof(float4);  // 25.2 MB
  const size_t hist1B = (size_t)T * NT * sizeof(float);   //  6.3 MB
  const size_t aqB    = (size_t)T * NT * sizeof(float2);  // 12.6 MB
  const size_t needBytes = hist4B + hist1B + aqB;         // 44.1 MB

  hipMemsetAsync(d_out, 0, sizeof(float), stream);

  if (ws_size >= needBytes) {
    float4* hist4 = (float4*)d_ws;
    float*  hist1 = (float*)((char*)d_ws + hist4B);
    float2* aqp   = (float2*)((char*)d_ws + hist4B + hist1B);
    fused_kernel<<<NBLK, NTH, 0, stream>>>(params, covp, init_states, z,
                                           hist4, hist1, aqp, out);
  }
}

// Round 12
// 123.021 us; speedup vs baseline: 4.3169x; 1.0001x over previous
//
#include <hip/hip_runtime.h>
#include <cmath>

// Kalman_Smooth_Gradient: B=4096 seqs, T=128 steps, 6-state EKF + RTS + loss.
// Round 12: exact factorization (3 independent 2-state filters, r9) + SPREAD.
// r11 ran 64 blocks x 192 thr -> only 64/256 CUs active, per-CU store BW
// saturated. Now:
//   chains_kernel: 192 blocks x 64 thr (block = filter f x 64 seqs; one wave
//     per CU on 192 CUs). Per thread: serial fwd (hist4+hist1 stores, depth-8
//     z prefetch), serial bwd (depth-8 hist/z prefetch), local quad-sum
//     (a*e^2), store only `a` per step at aqA[n][f][B]; wave-reduce + atomic.
//   det_kernel: 504 blocks x 256 thr; sum ax*ay*at over 126*B coalesced
//     triples; block-reduce + atomic.
// Dispatch-gap data (r3..r11) shows harness overhead ~55-60us is fixed, not
// per-dispatch, so the extra small kernel is nearly free.

namespace {

constexpr int B = 4096;
constexpr int T = 128;
constexpr int NT = B * 3;           // 12288 filter chains
constexpr int NBLK1 = 192;          // chains_kernel blocks (64 per filter)
constexpr int TRIPLES = 126 * B;    // det terms, n = 2..127
constexpr float DTc     = 1.0f / 120.0f;
constexpr float TWO_PIc = 6.28318530717958647692f;
constexpr float PI_1_5  = 4.71238898038468985769f;
constexpr float INV_2PI = 0.15915494309189533577f;

__device__ __forceinline__ float frcp(float x) { return __builtin_amdgcn_rcpf(x); }

__device__ __forceinline__ float fast_tanh(float x) {
  float e = __expf(2.0f * x);
  return 1.0f - 2.0f * frcp(e + 1.0f);
}
__device__ __forceinline__ float sigmoidf(float x) {
  return frcp(1.0f + __expf(-x));
}

// ---------------------------------------------------------------------------
// chains_kernel: one wave per block; block = (filter f) x (64 seqs).
// hist4: [T][NT] float4 (p,v,P00,P01); hist1: [T][NT] float P11;
// aqA: [(n*3+f)*B + seq] float a (valid n = 2..T-1).
// ---------------------------------------------------------------------------
__global__ __launch_bounds__(64, 1) void chains_kernel(
    const float* __restrict__ params, const float* __restrict__ covp,
    const float* __restrict__ init_states, const float* __restrict__ z,
    float4* __restrict__ hist4, float* __restrict__ hist1,
    float* __restrict__ aqA, float* __restrict__ out) {
  const int lane = threadIdx.x;
  const int blk = blockIdx.x;
  const int f = blk >> 6;           // 0=x, 1=y, 2=theta (wave-uniform)
  const int g = blk & 63;
  const int seq = g * 64 + lane;
  const int fi = f * B + seq;       // chain id (lane-consecutive -> coalesced)

  // ---- shared scalars ----
  const float friction = (fast_tanh(params[0]) + 1.0f) * 0.01f;
  const float damping  = (fast_tanh(params[1]) + 1.0f) * 0.01f;
  float cp[7];
#pragma unroll
  for (int i = 0; i < 7; i++) cp[i] = sigmoidf(covp[i]);
  const float dcoef = 1.0f - DTc * damping;
  const bool isTH = (f == 2);                 // wave-uniform branch
  const float q0 = isTH ? cp[5] : cp[3];
  const float q1 = isTH ? cp[6] : cp[4];
  const float r  = cp[f];

  // ---- init ----
  const int pidx = (f == 0) ? 0 : (f == 1) ? 1 : 4;
  const int vidx = (f == 0) ? 2 : (f == 1) ? 3 : 5;
  float p = init_states[seq * 6 + pidx];
  float v = init_states[seq * 6 + vidx];
  float P00 = 0.01f, P01 = 0.0f, P11 = 0.01f;

  const float* __restrict__ zp = z + (size_t)seq * (T * 3) + f;  // stride 3

  float qacc = 0.0f;  // local quad-part accumulator (a * e^2)

  // =========================== forward ===========================
  float zb[8];
#pragma unroll
  for (int i = 0; i < 8; i++) zb[i] = zp[i * 3];

#pragma unroll 8
  for (int t = 0; t < T; t++) {
    const int sl = t & 7;
    const float zc = zb[sl];
    const int tf = (t + 8 < T) ? (t + 8) : (T - 1);  // clamped prefetch
    zb[sl] = zp[tf * 3];

    float gg, tv;
    if (!isTH) {
      const float th = fast_tanh(100.0f * v);
      tv = v - DTc * (damping * v + friction * th);
      gg = 1.0f - DTc * (damping + 100.0f * friction * (1.0f - th * th));
    } else {
      tv = dcoef * v;
      gg = dcoef;
    }
    const float tp = p + DTc * v;
    const float u = P01 + DTc * P11;
    const float Pp00 = P00 + DTc * P01 + DTc * u + q0;
    const float Pp01 = gg * u;
    const float Pp11 = gg * (gg * P11) + q1;
    const float iS = frcp(Pp00 + r);
    const float K0 = Pp00 * iS;
    const float K1 = Pp01 * iS;
    float e = zc - tp;
    if (isTH) e = e - TWO_PIc * rintf(e * INV_2PI);  // _wrap
    p = tp + K0 * e;
    v = tv + K1 * e;
    const float om = 1.0f - K0;
    P00 = om * Pp00;
    P01 = om * Pp01;
    P11 = Pp11 - K1 * Pp01;

    hist4[(size_t)t * NT + fi] = make_float4(p, v, P00, P01);
    hist1[(size_t)t * NT + fi] = P11;
  }

  // ---- terminal term n = T-1 (smoothed == filtered) ----
  {
    const float zl = zp[(T - 1) * 3];
    float e = zl - p;
    if (isTH) {
      if (e >  PI_1_5) e -= TWO_PIc;
      if (e < -PI_1_5) e += TWO_PIc;
    }
    const float a = P00 + r;
    qacc += a * e * e;
    aqA[(size_t)((T - 1) * 3 + f) * B + seq] = a;
  }

  // =========================== backward ===========================
  float sp_ = p, sv_ = v, Ps00 = P00, Ps01 = P01, Ps11 = P11;

  // depth-8 rolling prefetch; iteration i -> n = 126 - i; padded to 128 iters
  float4 h4b[8];
  float h1b[8], zbb[8];
#pragma unroll
  for (int i = 0; i < 8; i++) {
    const int n2 = 126 - i;
    h4b[i] = hist4[(size_t)n2 * NT + fi];
    h1b[i] = hist1[(size_t)n2 * NT + fi];
    zbb[i] = zp[n2 * 3];
  }

#pragma unroll 8
  for (int i = 0; i < 128; i++) {
    const int n = 126 - i;
    const int sl = i & 7;
    const float4 h4 = h4b[sl];
    const float h1 = h1b[sl];
    const float zn_ = zbb[sl];
    const int nf = (n >= 10) ? (n - 8) : 2;  // clamped prefetch target
    h4b[sl] = hist4[(size_t)nf * NT + fi];
    h1b[sl] = hist1[(size_t)nf * NT + fi];
    zbb[sl] = zp[nf * 3];

    const float fp = h4.x, fv = h4.y, f00 = h4.z, f01 = h4.w, f11 = h1;

    float gg, tv;
    if (!isTH) {
      const float th = fast_tanh(100.0f * fv);
      tv = fv - DTc * (damping * fv + friction * th);
      gg = 1.0f - DTc * (damping + 100.0f * friction * (1.0f - th * th));
    } else {
      tv = dcoef * fv;
      gg = dcoef;
    }
    const float tp = fp + DTc * fv;
    const float u = f01 + DTc * f11;
    const float Pp00 = f00 + DTc * f01 + DTc * u + q0;
    const float Pp01 = gg * u;
    const float Pp11 = gg * (gg * f11) + q1;

    // G = P_f F^T Pp^{-1} (closed-form 2x2)
    const float idet = frcp(Pp00 * Pp11 - Pp01 * Pp01);
    const float W00 = f00, W01 = DTc * f00 + gg * f01;
    const float W10 = f01, W11 = DTc * f01 + gg * f11;
    const float G00 = (W00 * Pp11 - W01 * Pp01) * idet;
    const float G01 = (W01 * Pp00 - W00 * Pp01) * idet;
    const float G10 = (W10 * Pp11 - W11 * Pp01) * idet;
    const float G11 = (W11 * Pp00 - W10 * Pp01) * idet;

    const float ds0 = sp_ - tp, ds1 = sv_ - tv;
    const float np = fp + G00 * ds0 + G01 * ds1;
    const float nv = fv + G10 * ds0 + G11 * ds1;

    const float M00 = Ps00 - Pp00, M01 = Ps01 - Pp01, M11 = Ps11 - Pp11;
    const float GM00 = G00 * M00 + G01 * M01, GM01 = G00 * M01 + G01 * M11;
    const float GM10 = G10 * M00 + G11 * M01, GM11 = G10 * M01 + G11 * M11;
    Ps00 = f00 + GM00 * G00 + GM01 * G01;
    Ps01 = f01 + GM00 * G10 + GM01 * G11;
    Ps11 = f11 + GM10 * G10 + GM11 * G11;
    sp_ = np;
    sv_ = nv;

    if (n >= 2) {
      const float a = Ps00 + r;
      float e = zn_ - np;
      if (isTH) {
        if (e >  PI_1_5) e -= TWO_PIc;
        if (e < -PI_1_5) e += TWO_PIc;
      }
      qacc += a * e * e;
      aqA[(size_t)(n * 3 + f) * B + seq] = a;
    }
  }

  // ---- wave reduce + one atomic per block ----
#pragma unroll
  for (int off = 32; off > 0; off >>= 1) qacc += __shfl_down(qacc, off);
  if (lane == 0) atomicAdd(out, qacc);
}

// ---------------------------------------------------------------------------
// det_kernel: sum over (seq, n=2..127) of ax*ay*at. Coalesced triple loads.
// ---------------------------------------------------------------------------
__global__ __launch_bounds__(256, 4) void det_kernel(
    const float* __restrict__ aqA, float* __restrict__ out) {
  const int tid0 = blockIdx.x * 256 + threadIdx.x;
  const int stride = gridDim.x * 256;
  float part = 0.0f;
  for (int idx = tid0; idx < TRIPLES; idx += stride) {
    const int n2 = 2 + (idx >> 12);       // idx / B
    const int seq = idx & (B - 1);
    const float a0 = aqA[(size_t)(n2 * 3 + 0) * B + seq];
    const float a1 = aqA[(size_t)(n2 * 3 + 1) * B + seq];
    const float a2 = aqA[(size_t)(n2 * 3 + 2) * B + seq];
    part += a0 * a1 * a2;
  }
#pragma unroll
  for (int off = 32; off > 0; off >>= 1) part += __shfl_down(part, off);
  __shared__ float red[4];
  if ((threadIdx.x & 63) == 0) red[threadIdx.x >> 6] = part;
  __syncthreads();
  if (threadIdx.x == 0) atomicAdd(out, red[0] + red[1] + red[2] + red[3]);
}

}  // namespace

extern "C" void kernel_launch(void* const* d_in, const int* in_sizes, int n_in,
                              void* d_out, int out_size, void* d_ws, size_t ws_size,
                              hipStream_t stream) {
  const float* params      = (const float*)d_in[0];
  const float* covp        = (const float*)d_in[1];
  const float* init_states = (const float*)d_in[2];
  const float* z           = (const float*)d_in[3];
  float* out = (float*)d_out;

  const size_t hist4B = (size_t)T * NT * sizeof(float4);  // 25.2 MB
  const size_t hist1B = (size_t)T * NT * sizeof(float);   //  6.3 MB
  const size_t aqB    = (size_t)T * 3 * B * sizeof(float);//  6.3 MB
  const size_t needBytes = hist4B + hist1B + aqB;         // 37.8 MB

  hipMemsetAsync(d_out, 0, sizeof(float), stream);

  if (ws_size >= needBytes) {
    float4* hist4 = (float4*)d_ws;
    float*  hist1 = (float*)((char*)d_ws + hist4B);
    float*  aqA   = (float*)((char*)d_ws + hist4B + hist1B);
    chains_kernel<<<NBLK1, 64, 0, stream>>>(params, covp, init_states, z,
                                            hist4, hist1, aqA, out);
    det_kernel<<<504, 256, 0, stream>>>(aqA, out);
  }
}